// Round 12
// baseline (1609.800 us; speedup 1.0000x reference)
//
#include <hip/hip_runtime.h>
#include <hip/hip_bf16.h>
#include <cstddef>

// GPT-small: L=8 H=8 C=256 V=128 T=1024 B=32, D=32, FF=1024
static constexpr int Lc = 8, Hc = 8, Cc = 256, Vc = 128, Tc = 1024, Bc = 32;
static constexpr int Dc = Cc / Hc;       // 32
static constexpr int FFc = 4 * Cc;       // 1024
static constexpr int Mc = Bc * Tc;       // 32768 tokens
static constexpr float EPSc = 1e-5f;
// softmax scale (1/sqrt(32)) folded together with log2(e) into Q at the
// qkv-GEMM epilogue, so attention can use a bare v_exp_f32 (exp2).
static constexpr float QSCALE_LOG2E = 0.25503486f;  // 0.176776695 * 1.44269504

typedef __bf16 bf16x8 __attribute__((ext_vector_type(8)));
typedef float f32x4 __attribute__((ext_vector_type(4)));
typedef __hip_bfloat16 bf16;

union U32x4 { uint32_t q[4]; bf16x8 v; };

#define GL2LDS16(g, l) __builtin_amdgcn_global_load_lds( \
    (const __attribute__((address_space(1))) void*)(g),  \
    (__attribute__((address_space(3))) void*)(l), 16, 0, 0)

// ------------------------------------------- embedding + LN1(layer0) fused
__global__ __launch_bounds__(256) void embed_ln_kernel(
    const int* __restrict__ idx, const float* __restrict__ tok,
    const float* __restrict__ pos, const float* __restrict__ g,
    const float* __restrict__ b, float* __restrict__ x, bf16* __restrict__ hb)
{
    int row = blockIdx.x;
    int tid = threadIdx.x;
    int t = row & (Tc - 1);
    int token = idx[row];
    float v = tok[(size_t)token * Cc + tid] + pos[(size_t)t * Cc + tid];
    x[(size_t)row * Cc + tid] = v;
    __shared__ float red[4];
    float s = v;
    #pragma unroll
    for (int off = 32; off; off >>= 1) s += __shfl_xor(s, off);
    int lane = tid & 63, wave = tid >> 6;
    if (lane == 0) red[wave] = s;
    __syncthreads();
    float mean = (red[0] + red[1] + red[2] + red[3]) * (1.0f / Cc);
    float dv = v - mean;
    float s2 = dv * dv;
    #pragma unroll
    for (int off = 32; off; off >>= 1) s2 += __shfl_xor(s2, off);
    __syncthreads();
    if (lane == 0) red[wave] = s2;
    __syncthreads();
    float var = (red[0] + red[1] + red[2] + red[3]) * (1.0f / Cc);
    hb[(size_t)row * Cc + tid] = __float2bfloat16(dv * rsqrtf(var + EPSc) * g[tid] + b[tid]);
}

// ------------------------------------------------- weight cast + transpose
// PERMK: permute the K (fast) axis within each 64-block by pos(f) so the
// fused MLP's GEMM2 B-fragments are contiguous 16B reads.
// pos(f) = (f&32) | (((f>>2)&3)<<3) | (((f>>4)&1)<<2) | (f&3):
// global chunk g*4+quad holds f = 32g+16jb+4quad+r in slot order jb*4+r.
// (Weights only: permuting vT's WRITE side broke write coalescing — R10
// lesson: +16MB partial-sector writebacks drained into later dispatches.)
template <bool PERMK>
__global__ __launch_bounds__(256) void castT_kernel(
    const float* __restrict__ W, bf16* __restrict__ Wt, int K, int N)
{
    __shared__ float tile[32][33];
    const float* Wl = W + (size_t)blockIdx.z * K * N;
    bf16* Wtl = Wt + (size_t)blockIdx.z * K * N;
    int k0 = blockIdx.y * 32, n0 = blockIdx.x * 32;
    int tid = threadIdx.x;
    for (int e = tid; e < 1024; e += 256) {
        int r = e >> 5, c = e & 31;
        tile[r][c] = Wl[(size_t)(k0 + r) * N + n0 + c];
    }
    __syncthreads();
    for (int e = tid; e < 1024; e += 256) {
        int r = e >> 5, c = e & 31;
        int kk = k0 + c;
        if (PERMK) {
            int f = kk & 63;
            kk = (kk & ~63) | (f & 32) | (((f >> 2) & 3) << 3)
                 | (((f >> 4) & 1) << 2) | (f & 3);
        }
        Wtl[(size_t)(n0 + r) * K + kk] = __float2bfloat16(tile[c][r]);
    }
}

__device__ __forceinline__ float gelu_f(float x) {
    const float k2 = 2.0f * 0.7978845608028654f;
    float u2 = k2 * (x + 0.044715f * x * x * x);
    return x / (1.0f + __expf(-u2));
}

// ---------------------------------------------------------------- MFMA GEMM
// 128x128 tile, BK=64, XOR-swizzled LDS, swapped operands, XCD-aware flat
// grid. 512 threads / 8 waves (4m x 2n, 32x64 per wave).
// K-tiles double-buffered with counted s_waitcnt vmcnt(4) + raw s_barriers.
template <bool GELU, bool OUT_BF16, bool VSPLIT>
__global__ __launch_bounds__(512) void mfma_gemm_kernel(
    const bf16* __restrict__ A,    // [M][K]
    const bf16* __restrict__ Bt,   // [N][K]
    const float* __restrict__ bias,
    const float* __restrict__ res, // fp32 [M][N] or null
    float* __restrict__ Cf,        // fp32 out (used if !OUT_BF16)
    bf16* __restrict__ Cb,         // bf16 out (used if OUT_BF16)
    bf16* __restrict__ vTout,      // V^T out (used if VSPLIT)
    int M, int N, int K, int NT)
{
    __shared__ __align__(16) bf16 Asm[2][128 * 64];   // 32 KB dbuf
    __shared__ __align__(16) bf16 Bsm[2][128 * 64];   // 32 KB dbuf
    const int id = blockIdx.x;
    const int xcd = id & 7, q = id >> 3;
    const int m0 = ((q / NT) * 8 + xcd) * 128, n0 = (q % NT) * 128;
    const int tid = threadIdx.x;
    const int wave = tid >> 6, lane = tid & 63;
    const int quad = lane >> 4, l16 = lane & 15;
    const int wm = (wave >> 1) * 32, wn = (wave & 1) * 64;
    const int srow = lane >> 3;                    // 0..7
    const int scol = ((lane & 7) ^ srow) * 8;      // swizzled source k-chunk

    f32x4 acc[2][4];
    #pragma unroll
    for (int i = 0; i < 2; ++i)
        #pragma unroll
        for (int j = 0; j < 4; ++j)
            acc[i][j] = (f32x4){0.f, 0.f, 0.f, 0.f};

    // prologue: stage K-tile 0 into buffer 0 (8 waves x 2 bands each)
    #pragma unroll
    for (int i = 0; i < 2; ++i) {
        int rband = wave * 16 + i * 8;                       // wave-uniform
        GL2LDS16(A  + (size_t)(m0 + rband + srow) * K + scol, &Asm[0][rband * 64]);
        GL2LDS16(Bt + (size_t)(n0 + rband + srow) * K + scol, &Bsm[0][rband * 64]);
    }

    const int nk = K >> 6;
    for (int kt = 0; kt < nk; ++kt) {
        const int cur = kt & 1;
        if (kt + 1 < nk) {
            const int k0 = (kt + 1) << 6;
            #pragma unroll
            for (int i = 0; i < 2; ++i) {
                int rband = wave * 16 + i * 8;
                GL2LDS16(A  + (size_t)(m0 + rband + srow) * K + k0 + scol,
                         &Asm[cur ^ 1][rband * 64]);
                GL2LDS16(Bt + (size_t)(n0 + rband + srow) * K + k0 + scol,
                         &Bsm[cur ^ 1][rband * 64]);
            }
            asm volatile("s_waitcnt vmcnt(4)" ::: "memory");
        } else {
            asm volatile("s_waitcnt vmcnt(0)" ::: "memory");
        }
        __builtin_amdgcn_s_barrier();            // tile kt ready for all waves
        __builtin_amdgcn_sched_barrier(0);

        #pragma unroll
        for (int ks = 0; ks < 2; ++ks) {
            const int phys = ((ks * 4 + quad) ^ (l16 & 7)) * 8;  // de-swizzle
            bf16x8 af[2], bfr[4];
            #pragma unroll
            for (int i = 0; i < 2; ++i)
                af[i] = *(const bf16x8*)&Asm[cur][(wm + i * 16 + l16) * 64 + phys];
            #pragma unroll
            for (int j = 0; j < 4; ++j)
                bfr[j] = *(const bf16x8*)&Bsm[cur][(wn + j * 16 + l16) * 64 + phys];
            #pragma unroll
            for (int i = 0; i < 2; ++i)
                #pragma unroll
                for (int j = 0; j < 4; ++j)
                    acc[i][j] = __builtin_amdgcn_mfma_f32_16x16x32_bf16(
                        bfr[j], af[i], acc[i][j], 0, 0, 0);
        }
        __builtin_amdgcn_s_barrier();
    }

    #pragma unroll
    for (int i = 0; i < 2; ++i) {
        const int m = m0 + wm + i * 16 + l16;
        #pragma unroll
        for (int j = 0; j < 4; ++j) {
            const int nb = n0 + wn + j * 16 + quad * 4;
            f32x4 v = acc[i][j];
            if (bias) {
                float4 b4 = *(const float4*)(bias + nb);
                v[0] += b4.x; v[1] += b4.y; v[2] += b4.z; v[3] += b4.w;
            }
            if (GELU) {
                #pragma unroll
                for (int r = 0; r < 4; ++r) v[r] = gelu_f(v[r]);
            }
            if (res) {
                float4 r4 = *(const float4*)(res + (size_t)m * N + nb);
                v[0] += r4.x; v[1] += r4.y; v[2] += r4.z; v[3] += r4.w;
            }
            if (VSPLIT && nb < Cc) {
                #pragma unroll
                for (int r = 0; r < 4; ++r) v[r] *= QSCALE_LOG2E;
            }
            if (VSPLIT && nb >= 2 * Cc) {
                int hv = (nb - 2 * Cc) >> 5, dv = (nb - 2 * Cc) & 31;
                int bq = m >> 10, t = m & 1023;
                bf16* vp = vTout + ((size_t)(bq * Hc + hv) * Dc + dv) * Tc + t;
                #pragma unroll
                for (int r = 0; r < 4; ++r)
                    vp[(size_t)r * Tc] = __float2bfloat16(v[r]);
            } else if (OUT_BF16) {
                union { bf16 h[4]; uint2 u; } p;
                #pragma unroll
                for (int r = 0; r < 4; ++r) p.h[r] = __float2bfloat16(v[r]);
                *(uint2*)(Cb + (size_t)m * N + nb) = p.u;
            } else {
                *(float4*)(Cf + (size_t)m * N + nb) = (float4){v[0], v[1], v[2], v[3]};
            }
        }
    }
}

// --------------------------------------------- MFMA GEMM + residual + LN
// 512 threads / 8 waves (4m x 2n). K-tiles double-buffered, counted vmcnt(6).
__global__ __launch_bounds__(512) void mfma_gemm_ln_kernel(
    const bf16* __restrict__ A,    // [M][K]
    const bf16* __restrict__ Bt,   // [256][K]
    const float* __restrict__ bias,
    const float* __restrict__ res, // fp32 [M][256]
    const float* __restrict__ g, const float* __restrict__ b,
    float* __restrict__ xout, bf16* __restrict__ hbout, int K)
{
    __shared__ __align__(16) bf16 Asm[2][128 * 64];   // 32 KB dbuf
    __shared__ __align__(16) bf16 Bsm[2][256 * 64];   // 64 KB dbuf
    __shared__ float red[128][2][2];                  // 2 KB
    const int m0 = blockIdx.x * 128;
    const int tid = threadIdx.x;
    const int wave = tid >> 6, lane = tid & 63;
    const int quad = lane >> 4, l16 = lane & 15;
    const int wm = (wave >> 1) * 32, wn = (wave & 1) * 128;
    const int wnIdx = wave & 1;
    const int srow = lane >> 3;
    const int scol = ((lane & 7) ^ srow) * 8;

    f32x4 acc[2][8];
    #pragma unroll
    for (int i = 0; i < 2; ++i)
        #pragma unroll
        for (int j = 0; j < 8; ++j)
            acc[i][j] = (f32x4){0.f, 0.f, 0.f, 0.f};

    #pragma unroll
    for (int i = 0; i < 2; ++i) {
        int rband = wave * 16 + i * 8;
        GL2LDS16(A + (size_t)(m0 + rband + srow) * K + scol, &Asm[0][rband * 64]);
    }
    #pragma unroll
    for (int i = 0; i < 4; ++i) {
        int rband = wave * 32 + i * 8;
        GL2LDS16(Bt + (size_t)(rband + srow) * K + scol, &Bsm[0][rband * 64]);
    }

    const int nk = K >> 6;
    for (int kt = 0; kt < nk; ++kt) {
        const int cur = kt & 1;
        if (kt + 1 < nk) {
            const int k0 = (kt + 1) << 6;
            #pragma unroll
            for (int i = 0; i < 2; ++i) {
                int rband = wave * 16 + i * 8;
                GL2LDS16(A + (size_t)(m0 + rband + srow) * K + k0 + scol,
                         &Asm[cur ^ 1][rband * 64]);
            }
            #pragma unroll
            for (int i = 0; i < 4; ++i) {
                int rband = wave * 32 + i * 8;
                GL2LDS16(Bt + (size_t)(rband + srow) * K + k0 + scol,
                         &Bsm[cur ^ 1][rband * 64]);
            }
            asm volatile("s_waitcnt vmcnt(6)" ::: "memory");
        } else {
            asm volatile("s_waitcnt vmcnt(0)" ::: "memory");
        }
        __builtin_amdgcn_s_barrier();
        __builtin_amdgcn_sched_barrier(0);

        #pragma unroll
        for (int ks = 0; ks < 2; ++ks) {
            const int phys = ((ks * 4 + quad) ^ (l16 & 7)) * 8;
            bf16x8 af[2], bfr[8];
            #pragma unroll
            for (int i = 0; i < 2; ++i)
                af[i] = *(const bf16x8*)&Asm[cur][(wm + i * 16 + l16) * 64 + phys];
            #pragma unroll
            for (int j = 0; j < 8; ++j)
                bfr[j] = *(const bf16x8*)&Bsm[cur][(wn + j * 16 + l16) * 64 + phys];
            #pragma unroll
            for (int i = 0; i < 2; ++i)
                #pragma unroll
                for (int j = 0; j < 8; ++j)
                    acc[i][j] = __builtin_amdgcn_mfma_f32_16x16x32_bf16(
                        bfr[j], af[i], acc[i][j], 0, 0, 0);
        }
        __builtin_amdgcn_s_barrier();
    }

    #pragma unroll
    for (int i = 0; i < 2; ++i) {
        const int rl = wm + i * 16 + l16;
        const int m = m0 + rl;
        float s = 0.f, s2 = 0.f;
        #pragma unroll
        for (int j = 0; j < 8; ++j) {
            const int nb = wn + j * 16 + quad * 4;
            float4 b4 = *(const float4*)(bias + nb);
            float4 r4 = *(const float4*)(res + (size_t)m * Cc + nb);
            acc[i][j][0] += b4.x + r4.x; acc[i][j][1] += b4.y + r4.y;
            acc[i][j][2] += b4.z + r4.z; acc[i][j][3] += b4.w + r4.w;
            #pragma unroll
            for (int r = 0; r < 4; ++r) {
                s += acc[i][j][r];
                s2 += acc[i][j][r] * acc[i][j][r];
            }
        }
        s  += __shfl_xor(s, 16);  s  += __shfl_xor(s, 32);
        s2 += __shfl_xor(s2, 16); s2 += __shfl_xor(s2, 32);
        if (quad == 0) { red[rl][wnIdx][0] = s; red[rl][wnIdx][1] = s2; }
    }
    __syncthreads();

    #pragma unroll
    for (int i = 0; i < 2; ++i) {
        const int rl = wm + i * 16 + l16;
        const int m = m0 + rl;
        float s  = red[rl][0][0] + red[rl][1][0];
        float s2 = red[rl][0][1] + red[rl][1][1];
        float mean = s * (1.0f / Cc);
        float rstd = rsqrtf(s2 * (1.0f / Cc) - mean * mean + EPSc);
        #pragma unroll
        for (int j = 0; j < 8; ++j) {
            const int nb = wn + j * 16 + quad * 4;
            f32x4 v = acc[i][j];
            *(float4*)(xout + (size_t)m * Cc + nb) = (float4){v[0], v[1], v[2], v[3]};
            float4 g4 = *(const float4*)(g + nb);
            float4 bb4 = *(const float4*)(b + nb);
            union { bf16 h[4]; uint2 u; } p;
            p.h[0] = __float2bfloat16((v[0] - mean) * rstd * g4.x + bb4.x);
            p.h[1] = __float2bfloat16((v[1] - mean) * rstd * g4.y + bb4.y);
            p.h[2] = __float2bfloat16((v[2] - mean) * rstd * g4.z + bb4.z);
            p.h[3] = __float2bfloat16((v[3] - mean) * rstd * g4.w + bb4.w);
            *(uint2*)(hbout + (size_t)m * Cc + nb) = p.u;
        }
    }
}

// ------------------------------------------- fused MLP: gelu(hb@Wf+b1)@Wp
//                                             + b2 + residual + LN
// R8 version. Wp pre-permuted in global (castT<true>) so GEMM2 B-frags are
// contiguous ds_read_b128.
__global__ __launch_bounds__(512) void fused_ff_ln_kernel(
    const bf16* __restrict__ A,     // hb [M][256]
    const bf16* __restrict__ Wf,    // WfT [1024 f][256 c]
    const float* __restrict__ b1,   // [1024]
    const bf16* __restrict__ Wp,    // wpT [256 outc][1024 f], f pi-permuted
    const float* __restrict__ b2,   // [256]
    const float* __restrict__ g, const float* __restrict__ bb,
    float* __restrict__ x,          // residual in / out, fp32 [M][256]
    bf16* __restrict__ hbout)       // LN output [M][256]
{
    // 2 bufs x (Wf slice 64x256 + Wp slice 256x64) = 2 x 32768 elems = 128 KB
    __shared__ __align__(16) bf16 lds[2 * 32768];
    const int m0 = blockIdx.x * 128;
    const int tid = threadIdx.x;
    const int wave = tid >> 6, lane = tid & 63;
    const int quad = lane >> 4, l16 = lane & 15;

    // ---- prologue: stage hb tile [128][256] into lds[0..32768)
    #pragma unroll
    for (int it = 0; it < 8; ++it) {
        const int row = wave * 16 + it * 2 + (lane >> 5);
        const int clog = (lane & 31) ^ (row & 7);
        GL2LDS16(A + (size_t)(m0 + row) * Cc + clog * 8,
                 &lds[(wave * 16 + it * 2) * Cc]);
    }
    __syncthreads();
    // extract this wave's 16 rows as B-operand frags: for mfma kk, lane
    // (quad,l16) supplies hb[row = wave*16+l16][c = (kk*4+quad)*8 + e]
    bf16x8 ahb[8];
    #pragma unroll
    for (int kk = 0; kk < 8; ++kk)
        ahb[kk] = *(const bf16x8*)&lds[(wave * 16 + l16) * Cc
                                       + (((kk * 4 + quad) ^ (l16 & 7)) * 8)];
    asm volatile("s_waitcnt lgkmcnt(0)" ::: "memory");
    __builtin_amdgcn_sched_barrier(0);
    __builtin_amdgcn_s_barrier();   // all reads done before staging overwrites

    // stage one f-slice (Wf rows f0..f0+63 x 256c; Wp rows 0..255 x 64f)
    #define FF_STAGE(buf, sl) do {                                             \
        const int f0s = (sl) * 64;                                             \
        _Pragma("unroll")                                                      \
        for (int it = 0; it < 4; ++it) {                                       \
            const int row = it * 16 + wave * 2 + (lane >> 5);                  \
            const int clog = (lane & 31) ^ (row & 7);                          \
            GL2LDS16(Wf + (size_t)(f0s + row) * Cc + clog * 8,                 \
                     &lds[(buf) * 32768 + (it * 16 + wave * 2) * Cc]);         \
        }                                                                      \
        _Pragma("unroll")                                                      \
        for (int it = 0; it < 4; ++it) {                                       \
            const int row = it * 64 + wave * 8 + (lane >> 3);                  \
            const int clog = (lane & 7) ^ (row & 7);                           \
            GL2LDS16(Wp + (size_t)row * FFc + f0s + clog * 8,                  \
                     &lds[(buf) * 32768 + 16384 + (it * 64 + wave * 8) * 64]); \
        }                                                                      \
    } while (0)

    FF_STAGE(0, 0);

    f32x4 o[16];
    #pragma unroll
    for (int nt = 0; nt < 16; ++nt) o[nt] = (f32x4){0.f, 0.f, 0.f, 0.f};

    for (int kt = 0; kt < 16; ++kt) {
        const int cur = kt & 1;
        if (kt < 15) {
            FF_STAGE(cur ^ 1, kt + 1);
            asm volatile("s_waitcnt vmcnt(8)" ::: "memory");
        } else {
            asm volatile("s_waitcnt vmcnt(0)" ::: "memory");
        }
        __builtin_amdgcn_s_barrier();
        __builtin_amdgcn_sched_barrier(0);

        const bf16* Wfb = &lds[cur * 32768];
        const bf16* Wpb = &lds[cur * 32768 + 16384];

        // GEMM1 (swapped): sj[j] holds S[f=kt*64+j*16+quad*4+r][m=wave*16+l16]
        f32x4 sj[4];
        #pragma unroll
        for (int j = 0; j < 4; ++j) sj[j] = (f32x4){0.f, 0.f, 0.f, 0.f};
        #pragma unroll
        for (int kk = 0; kk < 8; ++kk) {
            const int ph = ((kk * 4 + quad) ^ (l16 & 7)) * 8;
            #pragma unroll
            for (int j = 0; j < 4; ++j) {
                bf16x8 wfr = *(const bf16x8*)&Wfb[(j * 16 + l16) * Cc + ph];
                sj[j] = __builtin_amdgcn_mfma_f32_16x16x32_bf16(
                    wfr, ahb[kk], sj[j], 0, 0, 0);
            }
        }

        // bias1 + gelu
        float p[4][4];
        #pragma unroll
        for (int j = 0; j < 4; ++j) {
            float4 b4 = *(const float4*)(b1 + kt * 64 + j * 16 + quad * 4);
            p[j][0] = gelu_f(sj[j][0] + b4.x);
            p[j][1] = gelu_f(sj[j][1] + b4.y);
            p[j][2] = gelu_f(sj[j][2] + b4.z);
            p[j][3] = gelu_f(sj[j][3] + b4.w);
        }

        // pi-order PV A-frags: lane's own values, no shuffles
        U32x4 pa0, pa1;
        asm("v_cvt_pk_bf16_f32 %0, %1, %2" : "=v"(pa0.q[0]) : "v"(p[0][0]), "v"(p[0][1]));
        asm("v_cvt_pk_bf16_f32 %0, %1, %2" : "=v"(pa0.q[1]) : "v"(p[0][2]), "v"(p[0][3]));
        asm("v_cvt_pk_bf16_f32 %0, %1, %2" : "=v"(pa0.q[2]) : "v"(p[1][0]), "v"(p[1][1]));
        asm("v_cvt_pk_bf16_f32 %0, %1, %2" : "=v"(pa0.q[3]) : "v"(p[1][2]), "v"(p[1][3]));
        asm("v_cvt_pk_bf16_f32 %0, %1, %2" : "=v"(pa1.q[0]) : "v"(p[2][0]), "v"(p[2][1]));
        asm("v_cvt_pk_bf16_f32 %0, %1, %2" : "=v"(pa1.q[1]) : "v"(p[2][2]), "v"(p[2][3]));
        asm("v_cvt_pk_bf16_f32 %0, %1, %2" : "=v"(pa1.q[2]) : "v"(p[3][0]), "v"(p[3][1]));
        asm("v_cvt_pk_bf16_f32 %0, %1, %2" : "=v"(pa1.q[3]) : "v"(p[3][2]), "v"(p[3][3]));

        // GEMM2: o[nt] += P @ Wp-slice. Wp pre-permuted: frag g is one
        // contiguous b128 at chunk (g*4+quad), staged-XOR de-swizzled.
        #pragma unroll
        for (int nt = 0; nt < 16; ++nt) {
            const int d = nt * 16 + l16;
            bf16x8 w0 = *(const bf16x8*)&Wpb[d * 64 + (((0 + quad) ^ (l16 & 7)) * 8)];
            bf16x8 w1 = *(const bf16x8*)&Wpb[d * 64 + (((4 + quad) ^ (l16 & 7)) * 8)];
            o[nt] = __builtin_amdgcn_mfma_f32_16x16x32_bf16(pa0.v, w0, o[nt], 0, 0, 0);
            o[nt] = __builtin_amdgcn_mfma_f32_16x16x32_bf16(pa1.v, w1, o[nt], 0, 0, 0);
        }
        __builtin_amdgcn_s_barrier();   // buf cur reads done before overwrite
    }
    #undef FF_STAGE

    // ---- epilogue: bias2 + residual; LN stats per row (pure shfl: each
    // quad owns distinct rows, reduce across the 16 l16 lanes only)
    const int row0 = m0 + wave * 16 + quad * 4;
    float s[4] = {0.f, 0.f, 0.f, 0.f}, s2[4] = {0.f, 0.f, 0.f, 0.f};
    #pragma unroll
    for (int nt = 0; nt < 16; ++nt) {
        const int col = nt * 16 + l16;
        const float bpv = b2[col];
        #pragma unroll
        for (int r = 0; r < 4; ++r) {
            float v = o[nt][r] + bpv + x[(size_t)(row0 + r) * Cc + col];
            o[nt][r] = v;
            s[r] += v; s2[r] += v * v;
        }
    }
    #pragma unroll
    for (int r = 0; r < 4; ++r) {
        #pragma unroll
        for (int off = 1; off < 16; off <<= 1) {
            s[r]  += __shfl_xor(s[r], off);
            s2[r] += __shfl_xor(s2[r], off);
        }
    }
    float mean[4], rstd[4];
    #pragma unroll
    for (int r = 0; r < 4; ++r) {
        mean[r] = s[r] * (1.0f / Cc);
        rstd[r] = rsqrtf(s2[r] * (1.0f / Cc) - mean[r] * mean[r] + EPSc);
    }
    #pragma unroll
    for (int nt = 0; nt < 16; ++nt) {
        const int col = nt * 16 + l16;
        const float gv = g[col], bv = bb[col];
        #pragma unroll
        for (int r = 0; r < 4; ++r) {
            x[(size_t)(row0 + r) * Cc + col] = o[nt][r];
            hbout[(size_t)(row0 + r) * Cc + col] =
                __float2bfloat16((o[nt][r] - mean[r]) * rstd[r] * gv + bv);
        }
    }
}

// ---------------------------------------------------------------- attention
// MFMA flash attention, K/V double-buffered with counted vmcnt. SWAPPED
// QK^T + pi key-permutation: P never touches LDS (V read in pi order via
// 2x ds_read_b64 per fragment). q-tiles paired {2i,2i+1} (heavy pair
// first): total staged rounds 52 -> 40 (R10, kept).
__global__ __launch_bounds__(256) void attn_mfma_kernel(
    const bf16* __restrict__ qkv, const bf16* __restrict__ vT,
    bf16* __restrict__ y)
{
    const int id = blockIdx.x;              // 1024 = 32 g * 4 pair * 8 xcd
    const int xcd = id & 7;
    const int pr  = (id >> 3) & 3;          // pair 0 (heaviest: tiles 6,7)
    const int bh  = ((id >> 5) << 3) + xcd;
    const int qa = 6 - 2 * pr, qb = qa + 1; // 128-row q-tile indices
    const int b = bh >> 3, h = bh & 7;
    const int tid = threadIdx.x;
    const int wave = tid >> 6, lane = tid & 63;
    const int quad = lane >> 4, l16 = lane & 15;

    __shared__ __align__(16) bf16 Ks[2][64 * 32];    // 8 KB, dbuf, swizzled
    __shared__ __align__(16) bf16 Vs[2][32 * 64];    // 8 KB, dbuf, swizzled
    __shared__ __align__(16) bf16 Qs[256 * 32];      // 16 KB Q staging

    const size_t rstride = 3 * Cc;
    const bf16* base  = qkv + (size_t)(b * Tc) * rstride + h * Dc;
    const bf16* vbase = vT + (size_t)bh * Dc * Tc;

    const int srow4  = lane >> 2;
    const int schunk = ((lane & 3) ^ ((lane >> 3) & 3)) * 8;
    const int vchunk = ((lane & 7) ^ (lane >> 3)) * 8;

    #pragma unroll
    for (int u = 0; u < 4; ++u) {
        const int qt = (u >> 1) ? qb : qa;
        const bf16* gq = base
            + (size_t)(qt * 128 + (u & 1) * 64 + wave * 16 + srow4) * rstride + schunk;
        GL2LDS16(gq, &Qs[(u * 64 + wave * 16) * 32]);
    }
    {
        const bf16* gk = base + (size_t)(wave * 16 + srow4) * rstride + 256 + schunk;
        GL2LDS16(gk, &Ks[0][(wave * 16) * 32]);
        const bf16* gv = vbase + (size_t)(wave * 8 + (lane >> 3)) * Tc + vchunk;
        GL2LDS16(gv, &Vs[0][(wave * 8) * 64]);
    }
    __syncthreads();
    const int qkphys = (quad ^ ((l16 >> 1) & 3)) * 8;
    bf16x8 afq[4];
    #pragma unroll
    for (int u = 0; u < 4; ++u)
        afq[u] = *(const bf16x8*)&Qs[(u * 64 + wave * 16 + l16) * 32 + qkphys];

    float l_acc[4] = {};
    f32x4 o[4][2];
    #pragma unroll
    for (int u = 0; u < 4; ++u)
        #pragma unroll
        for (int nt = 0; nt < 2; ++nt)
            o[u][nt] = (f32x4){0.f, 0.f, 0.f, 0.f};

    const int rloc = wave * 16 + quad * 4;     // output q rows (epilogue)
    const int qloc = wave * 16 + l16;          // this lane's P column (q row)
    // V read offsets in pi order: frag g, half jb -> 4 keys
    // 32g+16jb+4*quad+(0..3) at phys element offset
    // ((4g+2jb+(quad>>1)) ^ (l16&7))*8 + (quad&1)*4 within the row.
    const int vsw = l16 & 7;
    const int vq  = (quad >> 1);
    const int vo  = (quad & 1) * 4;

    const int ktmax = 2 * qb + 1;
    for (int kt = 0; kt <= ktmax; ++kt) {
        const int cur = kt & 1;

        if (kt < ktmax) {
            const int nxt = cur ^ 1;
            const bf16* gk = base
                + (size_t)((kt + 1) * 64 + wave * 16 + srow4) * rstride + 256 + schunk;
            GL2LDS16(gk, &Ks[nxt][(wave * 16) * 32]);
            const bf16* gv = vbase
                + (size_t)(wave * 8 + (lane >> 3)) * Tc + (kt + 1) * 64 + vchunk;
            GL2LDS16(gv, &Vs[nxt][(wave * 8) * 64]);
            asm volatile("s_waitcnt vmcnt(2)" ::: "memory");
        } else {
            asm volatile("s_waitcnt vmcnt(0)" ::: "memory");
        }
        __builtin_amdgcn_s_barrier();
        __builtin_amdgcn_sched_barrier(0);

        bf16x8 bk[4];
        #pragma unroll
        for (int j = 0; j < 4; ++j)
            bk[j] = *(const bf16x8*)&Ks[cur][(j * 16 + l16) * 32 + qkphys];

        // V fragments in pi order: bvx[g][nt], words {jb=0: q0,q1}{jb=1: q2,q3}
        U32x4 bvx[2][2];
        #pragma unroll
        for (int g = 0; g < 2; ++g)
            #pragma unroll
            for (int nt = 0; nt < 2; ++nt) {
                const int d = nt * 16 + l16;
                uint2 lo = *(const uint2*)&Vs[cur][d * 64 + (((4 * g + 0 + vq) ^ vsw) * 8 + vo)];
                uint2 hi = *(const uint2*)&Vs[cur][d * 64 + (((4 * g + 2 + vq) ^ vsw) * 8 + vo)];
                bvx[g][nt].q[0] = lo.x; bvx[g][nt].q[1] = lo.y;
                bvx[g][nt].q[2] = hi.x; bvx[g][nt].q[3] = hi.y;
            }

        #pragma unroll
        for (int t = 1; t >= 0; --t) {
            const int qt = t ? qb : qa;
            if (kt > 2 * qt + 1) continue;      // whole tile done (uniform)

            #pragma unroll
            for (int s = 0; s < 2; ++s) {
                const int u = t * 2 + s;
                if (kt > 2 * qt + s) continue;  // subtile masked (uniform)

                f32x4 sj[4];
                #pragma unroll
                for (int j = 0; j < 4; ++j)
                    sj[j] = __builtin_amdgcn_mfma_f32_16x16x32_bf16(
                        bk[j], afq[u], (f32x4){0.f,0.f,0.f,0.f}, 0, 0, 0);
                if (kt == 2 * qt + s) {         // diagonal: causal mask
                    #pragma unroll
                    for (int j = 0; j < 4; ++j)
                        #pragma unroll
                        for (int r = 0; r < 4; ++r)
                            if (j * 16 + quad * 4 + r > qloc) sj[j][r] = -INFINITY;
                }

                float p[4][4];
                float ls = 0.f;
                #pragma unroll
                for (int j = 0; j < 4; ++j) {
                    #pragma unroll
                    for (int r = 0; r < 4; ++r) {
                        p[j][r] = __builtin_amdgcn_exp2f(sj[j][r]);
                    }
                    ls += (p[j][0] + p[j][1]) + (p[j][2] + p[j][3]);
                }
                l_acc[u] += ls;

                U32x4 pa0, pa1;
                asm("v_cvt_pk_bf16_f32 %0, %1, %2" : "=v"(pa0.q[0]) : "v"(p[0][0]), "v"(p[0][1]));
                asm("v_cvt_pk_bf16_f32 %0, %1, %2" : "=v"(pa0.q[1]) : "v"(p[0][2]), "v"(p[0][3]));
                asm("v_cvt_pk_bf16_f32 %0, %1, %2" : "=v"(pa0.q[2]) : "v"(p[1][0]), "v"(p[1][1]));
                asm("v_cvt_pk_bf16_f32 %0, %1, %2" : "=v"(pa0.q[3]) : "v"(p[1][2]), "v"(p[1][3]));
                asm("v_cvt_pk_bf16_f32 %0, %1, %2" : "=v"(pa1.q[0]) : "v"(p[2][0]), "v"(p[2][1]));
                asm("v_cvt_pk_bf16_f32 %0, %1, %2" : "=v"(pa1.q[1]) : "v"(p[2][2]), "v"(p[2][3]));
                asm("v_cvt_pk_bf16_f32 %0, %1, %2" : "=v"(pa1.q[2]) : "v"(p[3][0]), "v"(p[3][1]));
                asm("v_cvt_pk_bf16_f32 %0, %1, %2" : "=v"(pa1.q[3]) : "v"(p[3][2]), "v"(p[3][3]));

                o[u][0] = __builtin_amdgcn_mfma_f32_16x16x32_bf16(pa0.v, bvx[0][0].v, o[u][0], 0, 0, 0);
                o[u][0] = __builtin_amdgcn_mfma_f32_16x16x32_bf16(pa1.v, bvx[1][0].v, o[u][0], 0, 0, 0);
                o[u][1] = __builtin_amdgcn_mfma_f32_16x16x32_bf16(pa0.v, bvx[0][1].v, o[u][1], 0, 0, 0);
                o[u][1] = __builtin_amdgcn_mfma_f32_16x16x32_bf16(pa1.v, bvx[1][1].v, o[u][1], 0, 0, 0);
            }
        }

        __builtin_amdgcn_s_barrier();
    }

    #pragma unroll
    for (int u = 0; u < 4; ++u) {
        const int qt = (u >> 1) ? qb : qa;
        float l = l_acc[u];
        l += __shfl_xor(l, 16);
        l += __shfl_xor(l, 32);
        float linv[4];
        #pragma unroll
        for (int r = 0; r < 4; ++r)
            linv[r] = 1.0f / __shfl(l, quad * 20 + r);
        #pragma unroll
        for (int nt = 0; nt < 2; ++nt)
            #pragma unroll
            for (int r = 0; r < 4; ++r)
                y[(size_t)(b * Tc + qt * 128 + (u & 1) * 64 + rloc + r) * Cc
                  + h * Dc + nt * 16 + l16]
                    = __float2bfloat16(o[u][nt][r] * linv[r]);
    }
}

// ---------------------------------------------------------------- launch
extern "C" void kernel_launch(void* const* d_in, const int* in_sizes, int n_in,
                              void* d_out, int out_size, void* d_ws, size_t ws_size,
                              hipStream_t stream)
{
    const int*   idx     = (const int*)  d_in[0];
    const float* tok_emb = (const float*)d_in[1];
    const float* pos_emb = (const float*)d_in[2];
    const float* ln1_g   = (const float*)d_in[3];
    const float* ln1_b   = (const float*)d_in[4];
    const float* wqkv    = (const float*)d_in[5];
    const float* bqkv    = (const float*)d_in[6];
    const float* wo      = (const float*)d_in[7];
    const float* bo      = (const float*)d_in[8];
    const float* ln2_g   = (const float*)d_in[9];
    const float* ln2_b   = (const float*)d_in[10];
    const float* wfc     = (const float*)d_in[11];
    const float* bfc     = (const float*)d_in[12];
    const float* wpr     = (const float*)d_in[13];
    const float* bpr     = (const float*)d_in[14];
    const float* lnf_g   = (const float*)d_in[15];
    const float* lnf_b   = (const float*)d_in[16];
    const float* w_lm    = (const float*)d_in[17];
    float* out = (float*)d_out;

    float* ws = (float*)d_ws;
    float* x  = ws;                                        // Mc*Cc fp32
    bf16* hb  = (bf16*)(x + (size_t)Mc * Cc);              // Mc*Cc bf16
    bf16* yb  = hb + (size_t)Mc * Cc;                      // Mc*Cc bf16
    float* big = (float*)(yb + (size_t)Mc * Cc);           // scratch region
    bf16* bigb = (bf16*)big;                               // qkv bf16
    bf16* wqT = (bf16*)(big + (size_t)Mc * 3 * Cc);        // [L][3C][C]
    bf16* woT = wqT + (size_t)Lc * 3 * Cc * Cc;            // [L][C][C]
    bf16* wfT = woT + (size_t)Lc * Cc * Cc;                // [L][FF][C]
    bf16* wpT = wfT + (size_t)Lc * Cc * FFc;               // [L][C][FF] (f permuted)
    bf16* wlT = wpT + (size_t)Lc * FFc * Cc;               // [V][C]
    bf16* vT  = wlT + (size_t)Vc * Cc;                     // [B][H][D][T]

    dim3 blk(256);
    dim3 blkG(512);

    castT_kernel<false><<<dim3(3 * Cc / 32, Cc / 32, Lc), blk, 0, stream>>>(wqkv, wqT, Cc, 3 * Cc);
    castT_kernel<false><<<dim3(Cc / 32, Cc / 32, Lc),     blk, 0, stream>>>(wo,   woT, Cc, Cc);
    castT_kernel<false><<<dim3(FFc / 32, Cc / 32, Lc),    blk, 0, stream>>>(wfc,  wfT, Cc, FFc);
    castT_kernel<true><<<dim3(Cc / 32, FFc / 32, Lc),     blk, 0, stream>>>(wpr,  wpT, FFc, Cc);
    castT_kernel<false><<<dim3(Vc / 32, Cc / 32, 1),      blk, 0, stream>>>(w_lm, wlT, Cc, Vc);

    embed_ln_kernel<<<dim3(Mc), blk, 0, stream>>>(idx, tok_emb, pos_emb,
                                                  ln1_g, ln1_b, x, hb);

    for (int l = 0; l < Lc; ++l) {
        const bf16* WqT = wqT + (size_t)l * 3 * Cc * Cc;
        const bf16* WoT = woT + (size_t)l * Cc * Cc;
        const bf16* WfT = wfT + (size_t)l * Cc * FFc;
        const bf16* WpT = wpT + (size_t)l * FFc * Cc;
        const float* bq = bqkv + (size_t)l * 3 * Cc;
        const float* bo_ = bo  + (size_t)l * Cc;
        const float* bf_ = bfc + (size_t)l * FFc;
        const float* bp = bpr  + (size_t)l * Cc;
        const float* gn = (l < Lc - 1) ? ln1_g + (size_t)(l + 1) * Cc : lnf_g;
        const float* bn = (l < Lc - 1) ? ln1_b + (size_t)(l + 1) * Cc : lnf_b;

        // qkv: q,k -> bigb [M,3C]; v -> vT[B][H][D][T]   (NT=6, XCD-swizzled)
        mfma_gemm_kernel<false, true, true><<<dim3(Mc / 128 * 6), blkG, 0, stream>>>(
            hb, WqT, bq, nullptr, nullptr, bigb, vT, Mc, 3 * Cc, Cc, 6);
        attn_mfma_kernel<<<dim3(1024), blk, 0, stream>>>(bigb, vT, yb);
        // x = x + yb @ Wo + bo;  hb = LN2(x)
        mfma_gemm_ln_kernel<<<dim3(Mc / 128), blkG, 0, stream>>>(
            yb, WoT, bo_, x, ln2_g + (size_t)l * Cc, ln2_b + (size_t)l * Cc,
            x, hb, Cc);
        // fused MLP: x = x + gelu(hb@Wf+bf)@Wp + bp;  hb = LN_next(x)
        fused_ff_ln_kernel<<<dim3(Mc / 128), blkG, 0, stream>>>(
            hb, WfT, bf_, WpT, bp, gn, bn, x, hb);
    }

    // logits = hb @ w_lm   (NT=1)
    mfma_gemm_kernel<false, false, false><<<dim3(Mc / 128), blkG, 0, stream>>>(
        hb, wlT, nullptr, nullptr, out, nullptr, nullptr, Mc, Vc, Cc, 1);
}

// Round 13
// 1537.983 us; speedup vs baseline: 1.0467x; 1.0467x over previous
//
#include <hip/hip_runtime.h>
#include <hip/hip_bf16.h>
#include <cstddef>

// GPT-small: L=8 H=8 C=256 V=128 T=1024 B=32, D=32, FF=1024
static constexpr int Lc = 8, Hc = 8, Cc = 256, Vc = 128, Tc = 1024, Bc = 32;
static constexpr int Dc = Cc / Hc;       // 32
static constexpr int FFc = 4 * Cc;       // 1024
static constexpr int Mc = Bc * Tc;       // 32768 tokens
static constexpr float EPSc = 1e-5f;
// softmax scale (1/sqrt(32)) folded together with log2(e) into Q at the
// qkv-GEMM epilogue, so attention can use a bare v_exp_f32 (exp2).
static constexpr float QSCALE_LOG2E = 0.25503486f;  // 0.176776695 * 1.44269504

typedef __bf16 bf16x8 __attribute__((ext_vector_type(8)));
typedef float f32x4 __attribute__((ext_vector_type(4)));
typedef __hip_bfloat16 bf16;

union U32x4 { uint32_t q[4]; bf16x8 v; };

#define GL2LDS16(g, l) __builtin_amdgcn_global_load_lds( \
    (const __attribute__((address_space(1))) void*)(g),  \
    (__attribute__((address_space(3))) void*)(l), 16, 0, 0)

// ------------------------------------------- embedding + LN1(layer0) fused
__global__ __launch_bounds__(256) void embed_ln_kernel(
    const int* __restrict__ idx, const float* __restrict__ tok,
    const float* __restrict__ pos, const float* __restrict__ g,
    const float* __restrict__ b, float* __restrict__ x, bf16* __restrict__ hb)
{
    int row = blockIdx.x;
    int tid = threadIdx.x;
    int t = row & (Tc - 1);
    int token = idx[row];
    float v = tok[(size_t)token * Cc + tid] + pos[(size_t)t * Cc + tid];
    x[(size_t)row * Cc + tid] = v;
    __shared__ float red[4];
    float s = v;
    #pragma unroll
    for (int off = 32; off; off >>= 1) s += __shfl_xor(s, off);
    int lane = tid & 63, wave = tid >> 6;
    if (lane == 0) red[wave] = s;
    __syncthreads();
    float mean = (red[0] + red[1] + red[2] + red[3]) * (1.0f / Cc);
    float dv = v - mean;
    float s2 = dv * dv;
    #pragma unroll
    for (int off = 32; off; off >>= 1) s2 += __shfl_xor(s2, off);
    __syncthreads();
    if (lane == 0) red[wave] = s2;
    __syncthreads();
    float var = (red[0] + red[1] + red[2] + red[3]) * (1.0f / Cc);
    hb[(size_t)row * Cc + tid] = __float2bfloat16(dv * rsqrtf(var + EPSc) * g[tid] + b[tid]);
}

// ------------------------------------------------- weight cast + transpose
// PERMK: permute the K (fast) axis within each 64-block by pos(f) so the
// fused MLP's GEMM2 B-fragments are contiguous 16B reads.
// pos(f) = (f&32) | (((f>>2)&3)<<3) | (((f>>4)&1)<<2) | (f&3):
// global chunk g*4+quad holds f = 32g+16jb+4quad+r in slot order jb*4+r.
// (Weights only — permuting vT's write side or re-pairing attention's
// q-tiles both regressed downstream dispatches; R10-R12 lessons.)
template <bool PERMK>
__global__ __launch_bounds__(256) void castT_kernel(
    const float* __restrict__ W, bf16* __restrict__ Wt, int K, int N)
{
    __shared__ float tile[32][33];
    const float* Wl = W + (size_t)blockIdx.z * K * N;
    bf16* Wtl = Wt + (size_t)blockIdx.z * K * N;
    int k0 = blockIdx.y * 32, n0 = blockIdx.x * 32;
    int tid = threadIdx.x;
    for (int e = tid; e < 1024; e += 256) {
        int r = e >> 5, c = e & 31;
        tile[r][c] = Wl[(size_t)(k0 + r) * N + n0 + c];
    }
    __syncthreads();
    for (int e = tid; e < 1024; e += 256) {
        int r = e >> 5, c = e & 31;
        int kk = k0 + c;
        if (PERMK) {
            int f = kk & 63;
            kk = (kk & ~63) | (f & 32) | (((f >> 2) & 3) << 3)
                 | (((f >> 4) & 1) << 2) | (f & 3);
        }
        Wtl[(size_t)(n0 + r) * K + kk] = __float2bfloat16(tile[c][r]);
    }
}

__device__ __forceinline__ float gelu_f(float x) {
    const float k2 = 2.0f * 0.7978845608028654f;
    float u2 = k2 * (x + 0.044715f * x * x * x);
    return x / (1.0f + __expf(-u2));
}

// ---------------------------------------------------------------- MFMA GEMM
// 128x128 tile, BK=64, XOR-swizzled LDS, swapped operands, XCD-aware flat
// grid. 512 threads / 8 waves (4m x 2n, 32x64 per wave).
// K-tiles double-buffered with counted s_waitcnt vmcnt(4) + raw s_barriers.
template <bool GELU, bool OUT_BF16, bool VSPLIT>
__global__ __launch_bounds__(512) void mfma_gemm_kernel(
    const bf16* __restrict__ A,    // [M][K]
    const bf16* __restrict__ Bt,   // [N][K]
    const float* __restrict__ bias,
    const float* __restrict__ res, // fp32 [M][N] or null
    float* __restrict__ Cf,        // fp32 out (used if !OUT_BF16)
    bf16* __restrict__ Cb,         // bf16 out (used if OUT_BF16)
    bf16* __restrict__ vTout,      // V^T out (used if VSPLIT)
    int M, int N, int K, int NT)
{
    __shared__ __align__(16) bf16 Asm[2][128 * 64];   // 32 KB dbuf
    __shared__ __align__(16) bf16 Bsm[2][128 * 64];   // 32 KB dbuf
    const int id = blockIdx.x;
    const int xcd = id & 7, q = id >> 3;
    const int m0 = ((q / NT) * 8 + xcd) * 128, n0 = (q % NT) * 128;
    const int tid = threadIdx.x;
    const int wave = tid >> 6, lane = tid & 63;
    const int quad = lane >> 4, l16 = lane & 15;
    const int wm = (wave >> 1) * 32, wn = (wave & 1) * 64;
    const int srow = lane >> 3;                    // 0..7
    const int scol = ((lane & 7) ^ srow) * 8;      // swizzled source k-chunk

    f32x4 acc[2][4];
    #pragma unroll
    for (int i = 0; i < 2; ++i)
        #pragma unroll
        for (int j = 0; j < 4; ++j)
            acc[i][j] = (f32x4){0.f, 0.f, 0.f, 0.f};

    // prologue: stage K-tile 0 into buffer 0 (8 waves x 2 bands each)
    #pragma unroll
    for (int i = 0; i < 2; ++i) {
        int rband = wave * 16 + i * 8;                       // wave-uniform
        GL2LDS16(A  + (size_t)(m0 + rband + srow) * K + scol, &Asm[0][rband * 64]);
        GL2LDS16(Bt + (size_t)(n0 + rband + srow) * K + scol, &Bsm[0][rband * 64]);
    }

    const int nk = K >> 6;
    for (int kt = 0; kt < nk; ++kt) {
        const int cur = kt & 1;
        if (kt + 1 < nk) {
            const int k0 = (kt + 1) << 6;
            #pragma unroll
            for (int i = 0; i < 2; ++i) {
                int rband = wave * 16 + i * 8;
                GL2LDS16(A  + (size_t)(m0 + rband + srow) * K + k0 + scol,
                         &Asm[cur ^ 1][rband * 64]);
                GL2LDS16(Bt + (size_t)(n0 + rband + srow) * K + k0 + scol,
                         &Bsm[cur ^ 1][rband * 64]);
            }
            asm volatile("s_waitcnt vmcnt(4)" ::: "memory");
        } else {
            asm volatile("s_waitcnt vmcnt(0)" ::: "memory");
        }
        __builtin_amdgcn_s_barrier();            // tile kt ready for all waves
        __builtin_amdgcn_sched_barrier(0);

        #pragma unroll
        for (int ks = 0; ks < 2; ++ks) {
            const int phys = ((ks * 4 + quad) ^ (l16 & 7)) * 8;  // de-swizzle
            bf16x8 af[2], bfr[4];
            #pragma unroll
            for (int i = 0; i < 2; ++i)
                af[i] = *(const bf16x8*)&Asm[cur][(wm + i * 16 + l16) * 64 + phys];
            #pragma unroll
            for (int j = 0; j < 4; ++j)
                bfr[j] = *(const bf16x8*)&Bsm[cur][(wn + j * 16 + l16) * 64 + phys];
            #pragma unroll
            for (int i = 0; i < 2; ++i)
                #pragma unroll
                for (int j = 0; j < 4; ++j)
                    acc[i][j] = __builtin_amdgcn_mfma_f32_16x16x32_bf16(
                        bfr[j], af[i], acc[i][j], 0, 0, 0);
        }
        __builtin_amdgcn_s_barrier();
    }

    #pragma unroll
    for (int i = 0; i < 2; ++i) {
        const int m = m0 + wm + i * 16 + l16;
        #pragma unroll
        for (int j = 0; j < 4; ++j) {
            const int nb = n0 + wn + j * 16 + quad * 4;
            f32x4 v = acc[i][j];
            if (bias) {
                float4 b4 = *(const float4*)(bias + nb);
                v[0] += b4.x; v[1] += b4.y; v[2] += b4.z; v[3] += b4.w;
            }
            if (GELU) {
                #pragma unroll
                for (int r = 0; r < 4; ++r) v[r] = gelu_f(v[r]);
            }
            if (res) {
                float4 r4 = *(const float4*)(res + (size_t)m * N + nb);
                v[0] += r4.x; v[1] += r4.y; v[2] += r4.z; v[3] += r4.w;
            }
            if (VSPLIT && nb < Cc) {
                #pragma unroll
                for (int r = 0; r < 4; ++r) v[r] *= QSCALE_LOG2E;
            }
            if (VSPLIT && nb >= 2 * Cc) {
                int hv = (nb - 2 * Cc) >> 5, dv = (nb - 2 * Cc) & 31;
                int bq = m >> 10, t = m & 1023;
                bf16* vp = vTout + ((size_t)(bq * Hc + hv) * Dc + dv) * Tc + t;
                #pragma unroll
                for (int r = 0; r < 4; ++r)
                    vp[(size_t)r * Tc] = __float2bfloat16(v[r]);
            } else if (OUT_BF16) {
                union { bf16 h[4]; uint2 u; } p;
                #pragma unroll
                for (int r = 0; r < 4; ++r) p.h[r] = __float2bfloat16(v[r]);
                *(uint2*)(Cb + (size_t)m * N + nb) = p.u;
            } else {
                *(float4*)(Cf + (size_t)m * N + nb) = (float4){v[0], v[1], v[2], v[3]};
            }
        }
    }
}

// --------------------------------------------- MFMA GEMM + residual + LN
// 512 threads / 8 waves (4m x 2n). K-tiles double-buffered, counted vmcnt(6).
__global__ __launch_bounds__(512) void mfma_gemm_ln_kernel(
    const bf16* __restrict__ A,    // [M][K]
    const bf16* __restrict__ Bt,   // [256][K]
    const float* __restrict__ bias,
    const float* __restrict__ res, // fp32 [M][256]
    const float* __restrict__ g, const float* __restrict__ b,
    float* __restrict__ xout, bf16* __restrict__ hbout, int K)
{
    __shared__ __align__(16) bf16 Asm[2][128 * 64];   // 32 KB dbuf
    __shared__ __align__(16) bf16 Bsm[2][256 * 64];   // 64 KB dbuf
    __shared__ float red[128][2][2];                  // 2 KB
    const int m0 = blockIdx.x * 128;
    const int tid = threadIdx.x;
    const int wave = tid >> 6, lane = tid & 63;
    const int quad = lane >> 4, l16 = lane & 15;
    const int wm = (wave >> 1) * 32, wn = (wave & 1) * 128;
    const int wnIdx = wave & 1;
    const int srow = lane >> 3;
    const int scol = ((lane & 7) ^ srow) * 8;

    f32x4 acc[2][8];
    #pragma unroll
    for (int i = 0; i < 2; ++i)
        #pragma unroll
        for (int j = 0; j < 8; ++j)
            acc[i][j] = (f32x4){0.f, 0.f, 0.f, 0.f};

    #pragma unroll
    for (int i = 0; i < 2; ++i) {
        int rband = wave * 16 + i * 8;
        GL2LDS16(A + (size_t)(m0 + rband + srow) * K + scol, &Asm[0][rband * 64]);
    }
    #pragma unroll
    for (int i = 0; i < 4; ++i) {
        int rband = wave * 32 + i * 8;
        GL2LDS16(Bt + (size_t)(rband + srow) * K + scol, &Bsm[0][rband * 64]);
    }

    const int nk = K >> 6;
    for (int kt = 0; kt < nk; ++kt) {
        const int cur = kt & 1;
        if (kt + 1 < nk) {
            const int k0 = (kt + 1) << 6;
            #pragma unroll
            for (int i = 0; i < 2; ++i) {
                int rband = wave * 16 + i * 8;
                GL2LDS16(A + (size_t)(m0 + rband + srow) * K + k0 + scol,
                         &Asm[cur ^ 1][rband * 64]);
            }
            #pragma unroll
            for (int i = 0; i < 4; ++i) {
                int rband = wave * 32 + i * 8;
                GL2LDS16(Bt + (size_t)(rband + srow) * K + k0 + scol,
                         &Bsm[cur ^ 1][rband * 64]);
            }
            asm volatile("s_waitcnt vmcnt(6)" ::: "memory");
        } else {
            asm volatile("s_waitcnt vmcnt(0)" ::: "memory");
        }
        __builtin_amdgcn_s_barrier();
        __builtin_amdgcn_sched_barrier(0);

        #pragma unroll
        for (int ks = 0; ks < 2; ++ks) {
            const int phys = ((ks * 4 + quad) ^ (l16 & 7)) * 8;
            bf16x8 af[2], bfr[8];
            #pragma unroll
            for (int i = 0; i < 2; ++i)
                af[i] = *(const bf16x8*)&Asm[cur][(wm + i * 16 + l16) * 64 + phys];
            #pragma unroll
            for (int j = 0; j < 8; ++j)
                bfr[j] = *(const bf16x8*)&Bsm[cur][(wn + j * 16 + l16) * 64 + phys];
            #pragma unroll
            for (int i = 0; i < 2; ++i)
                #pragma unroll
                for (int j = 0; j < 8; ++j)
                    acc[i][j] = __builtin_amdgcn_mfma_f32_16x16x32_bf16(
                        bfr[j], af[i], acc[i][j], 0, 0, 0);
        }
        __builtin_amdgcn_s_barrier();
    }

    #pragma unroll
    for (int i = 0; i < 2; ++i) {
        const int rl = wm + i * 16 + l16;
        const int m = m0 + rl;
        float s = 0.f, s2 = 0.f;
        #pragma unroll
        for (int j = 0; j < 8; ++j) {
            const int nb = wn + j * 16 + quad * 4;
            float4 b4 = *(const float4*)(bias + nb);
            float4 r4 = *(const float4*)(res + (size_t)m * Cc + nb);
            acc[i][j][0] += b4.x + r4.x; acc[i][j][1] += b4.y + r4.y;
            acc[i][j][2] += b4.z + r4.z; acc[i][j][3] += b4.w + r4.w;
            #pragma unroll
            for (int r = 0; r < 4; ++r) {
                s += acc[i][j][r];
                s2 += acc[i][j][r] * acc[i][j][r];
            }
        }
        s  += __shfl_xor(s, 16);  s  += __shfl_xor(s, 32);
        s2 += __shfl_xor(s2, 16); s2 += __shfl_xor(s2, 32);
        if (quad == 0) { red[rl][wnIdx][0] = s; red[rl][wnIdx][1] = s2; }
    }
    __syncthreads();

    #pragma unroll
    for (int i = 0; i < 2; ++i) {
        const int rl = wm + i * 16 + l16;
        const int m = m0 + rl;
        float s  = red[rl][0][0] + red[rl][1][0];
        float s2 = red[rl][0][1] + red[rl][1][1];
        float mean = s * (1.0f / Cc);
        float rstd = rsqrtf(s2 * (1.0f / Cc) - mean * mean + EPSc);
        #pragma unroll
        for (int j = 0; j < 8; ++j) {
            const int nb = wn + j * 16 + quad * 4;
            f32x4 v = acc[i][j];
            *(float4*)(xout + (size_t)m * Cc + nb) = (float4){v[0], v[1], v[2], v[3]};
            float4 g4 = *(const float4*)(g + nb);
            float4 bb4 = *(const float4*)(b + nb);
            union { bf16 h[4]; uint2 u; } p;
            p.h[0] = __float2bfloat16((v[0] - mean) * rstd * g4.x + bb4.x);
            p.h[1] = __float2bfloat16((v[1] - mean) * rstd * g4.y + bb4.y);
            p.h[2] = __float2bfloat16((v[2] - mean) * rstd * g4.z + bb4.z);
            p.h[3] = __float2bfloat16((v[3] - mean) * rstd * g4.w + bb4.w);
            *(uint2*)(hbout + (size_t)m * Cc + nb) = p.u;
        }
    }
}

// ------------------------------------------- fused MLP: gelu(hb@Wf+b1)@Wp
//                                             + b2 + residual + LN
// Attention-structure port (R7 k-chunk fix). Wp pre-permuted in global
// (castT_kernel<true>) so GEMM2 B-fragments are contiguous ds_read_b128.
__global__ __launch_bounds__(512) void fused_ff_ln_kernel(
    const bf16* __restrict__ A,     // hb [M][256]
    const bf16* __restrict__ Wf,    // WfT [1024 f][256 c]
    const float* __restrict__ b1,   // [1024]
    const bf16* __restrict__ Wp,    // wpT [256 outc][1024 f], f pi-permuted
    const float* __restrict__ b2,   // [256]
    const float* __restrict__ g, const float* __restrict__ bb,
    float* __restrict__ x,          // residual in / out, fp32 [M][256]
    bf16* __restrict__ hbout)       // LN output [M][256]
{
    // 2 bufs x (Wf slice 64x256 + Wp slice 256x64) = 2 x 32768 elems = 128 KB
    __shared__ __align__(16) bf16 lds[2 * 32768];
    const int m0 = blockIdx.x * 128;
    const int tid = threadIdx.x;
    const int wave = tid >> 6, lane = tid & 63;
    const int quad = lane >> 4, l16 = lane & 15;

    // ---- prologue: stage hb tile [128][256] into lds[0..32768)
    #pragma unroll
    for (int it = 0; it < 8; ++it) {
        const int row = wave * 16 + it * 2 + (lane >> 5);
        const int clog = (lane & 31) ^ (row & 7);
        GL2LDS16(A + (size_t)(m0 + row) * Cc + clog * 8,
                 &lds[(wave * 16 + it * 2) * Cc]);
    }
    __syncthreads();
    // extract this wave's 16 rows as B-operand frags: for mfma kk, lane
    // (quad,l16) supplies hb[row = wave*16+l16][c = (kk*4+quad)*8 + e]
    bf16x8 ahb[8];
    #pragma unroll
    for (int kk = 0; kk < 8; ++kk)
        ahb[kk] = *(const bf16x8*)&lds[(wave * 16 + l16) * Cc
                                       + (((kk * 4 + quad) ^ (l16 & 7)) * 8)];
    asm volatile("s_waitcnt lgkmcnt(0)" ::: "memory");
    __builtin_amdgcn_sched_barrier(0);
    __builtin_amdgcn_s_barrier();   // all reads done before staging overwrites

    // stage one f-slice (Wf rows f0..f0+63 x 256c; Wp rows 0..255 x 64f)
    #define FF_STAGE(buf, sl) do {                                             \
        const int f0s = (sl) * 64;                                             \
        _Pragma("unroll")                                                      \
        for (int it = 0; it < 4; ++it) {                                       \
            const int row = it * 16 + wave * 2 + (lane >> 5);                  \
            const int clog = (lane & 31) ^ (row & 7);                          \
            GL2LDS16(Wf + (size_t)(f0s + row) * Cc + clog * 8,                 \
                     &lds[(buf) * 32768 + (it * 16 + wave * 2) * Cc]);         \
        }                                                                      \
        _Pragma("unroll")                                                      \
        for (int it = 0; it < 4; ++it) {                                       \
            const int row = it * 64 + wave * 8 + (lane >> 3);                  \
            const int clog = (lane & 7) ^ (row & 7);                           \
            GL2LDS16(Wp + (size_t)row * FFc + f0s + clog * 8,                  \
                     &lds[(buf) * 32768 + 16384 + (it * 64 + wave * 8) * 64]); \
        }                                                                      \
    } while (0)

    FF_STAGE(0, 0);

    f32x4 o[16];
    #pragma unroll
    for (int nt = 0; nt < 16; ++nt) o[nt] = (f32x4){0.f, 0.f, 0.f, 0.f};

    for (int kt = 0; kt < 16; ++kt) {
        const int cur = kt & 1;
        if (kt < 15) {
            FF_STAGE(cur ^ 1, kt + 1);
            asm volatile("s_waitcnt vmcnt(8)" ::: "memory");
        } else {
            asm volatile("s_waitcnt vmcnt(0)" ::: "memory");
        }
        __builtin_amdgcn_s_barrier();
        __builtin_amdgcn_sched_barrier(0);

        const bf16* Wfb = &lds[cur * 32768];
        const bf16* Wpb = &lds[cur * 32768 + 16384];

        // GEMM1 (swapped): sj[j] holds S[f=kt*64+j*16+quad*4+r][m=wave*16+l16]
        // mfma kk covers c-chunks kk*4..kk*4+3; lane supplies chunk kk*4+quad.
        f32x4 sj[4];
        #pragma unroll
        for (int j = 0; j < 4; ++j) sj[j] = (f32x4){0.f, 0.f, 0.f, 0.f};
        #pragma unroll
        for (int kk = 0; kk < 8; ++kk) {
            const int ph = ((kk * 4 + quad) ^ (l16 & 7)) * 8;
            #pragma unroll
            for (int j = 0; j < 4; ++j) {
                bf16x8 wfr = *(const bf16x8*)&Wfb[(j * 16 + l16) * Cc + ph];
                sj[j] = __builtin_amdgcn_mfma_f32_16x16x32_bf16(
                    wfr, ahb[kk], sj[j], 0, 0, 0);
            }
        }

        // bias1 + gelu
        float p[4][4];
        #pragma unroll
        for (int j = 0; j < 4; ++j) {
            float4 b4 = *(const float4*)(b1 + kt * 64 + j * 16 + quad * 4);
            p[j][0] = gelu_f(sj[j][0] + b4.x);
            p[j][1] = gelu_f(sj[j][1] + b4.y);
            p[j][2] = gelu_f(sj[j][2] + b4.z);
            p[j][3] = gelu_f(sj[j][3] + b4.w);
        }

        // pi-order PV A-frags: lane's own values, no shuffles
        U32x4 pa0, pa1;
        asm("v_cvt_pk_bf16_f32 %0, %1, %2" : "=v"(pa0.q[0]) : "v"(p[0][0]), "v"(p[0][1]));
        asm("v_cvt_pk_bf16_f32 %0, %1, %2" : "=v"(pa0.q[1]) : "v"(p[0][2]), "v"(p[0][3]));
        asm("v_cvt_pk_bf16_f32 %0, %1, %2" : "=v"(pa0.q[2]) : "v"(p[1][0]), "v"(p[1][1]));
        asm("v_cvt_pk_bf16_f32 %0, %1, %2" : "=v"(pa0.q[3]) : "v"(p[1][2]), "v"(p[1][3]));
        asm("v_cvt_pk_bf16_f32 %0, %1, %2" : "=v"(pa1.q[0]) : "v"(p[2][0]), "v"(p[2][1]));
        asm("v_cvt_pk_bf16_f32 %0, %1, %2" : "=v"(pa1.q[1]) : "v"(p[2][2]), "v"(p[2][3]));
        asm("v_cvt_pk_bf16_f32 %0, %1, %2" : "=v"(pa1.q[2]) : "v"(p[3][0]), "v"(p[3][1]));
        asm("v_cvt_pk_bf16_f32 %0, %1, %2" : "=v"(pa1.q[3]) : "v"(p[3][2]), "v"(p[3][3]));

        // GEMM2: o[nt] += P @ Wp-slice. Wp pre-permuted: frag g is one
        // contiguous b128 at chunk (g*4+quad), staged-XOR de-swizzled.
        #pragma unroll
        for (int nt = 0; nt < 16; ++nt) {
            const int d = nt * 16 + l16;
            bf16x8 w0 = *(const bf16x8*)&Wpb[d * 64 + (((0 + quad) ^ (l16 & 7)) * 8)];
            bf16x8 w1 = *(const bf16x8*)&Wpb[d * 64 + (((4 + quad) ^ (l16 & 7)) * 8)];
            o[nt] = __builtin_amdgcn_mfma_f32_16x16x32_bf16(pa0.v, w0, o[nt], 0, 0, 0);
            o[nt] = __builtin_amdgcn_mfma_f32_16x16x32_bf16(pa1.v, w1, o[nt], 0, 0, 0);
        }
        __builtin_amdgcn_s_barrier();   // buf cur reads done before overwrite
    }
    #undef FF_STAGE

    // ---- epilogue: bias2 + residual; LN stats per row (pure shfl: each
    // quad owns distinct rows, reduce across the 16 l16 lanes only)
    const int row0 = m0 + wave * 16 + quad * 4;
    float s[4] = {0.f, 0.f, 0.f, 0.f}, s2[4] = {0.f, 0.f, 0.f, 0.f};
    #pragma unroll
    for (int nt = 0; nt < 16; ++nt) {
        const int col = nt * 16 + l16;
        const float bpv = b2[col];
        #pragma unroll
        for (int r = 0; r < 4; ++r) {
            float v = o[nt][r] + bpv + x[(size_t)(row0 + r) * Cc + col];
            o[nt][r] = v;
            s[r] += v; s2[r] += v * v;
        }
    }
    #pragma unroll
    for (int r = 0; r < 4; ++r) {
        #pragma unroll
        for (int off = 1; off < 16; off <<= 1) {
            s[r]  += __shfl_xor(s[r], off);
            s2[r] += __shfl_xor(s2[r], off);
        }
    }
    float mean[4], rstd[4];
    #pragma unroll
    for (int r = 0; r < 4; ++r) {
        mean[r] = s[r] * (1.0f / Cc);
        rstd[r] = rsqrtf(s2[r] * (1.0f / Cc) - mean[r] * mean[r] + EPSc);
    }
    #pragma unroll
    for (int nt = 0; nt < 16; ++nt) {
        const int col = nt * 16 + l16;
        const float gv = g[col], bv = bb[col];
        #pragma unroll
        for (int r = 0; r < 4; ++r) {
            x[(size_t)(row0 + r) * Cc + col] = o[nt][r];
            hbout[(size_t)(row0 + r) * Cc + col] =
                __float2bfloat16((o[nt][r] - mean[r]) * rstd[r] * gv + bv);
        }
    }
}

// ---------------------------------------------------------------- attention
// MFMA flash attention, PAIRED q-tiles {pi, 7-pi} (R12: re-pairing to
// {2i,2i+1} regressed downstream dispatches twice — keep this pairing).
// K/V double-buffered with counted vmcnt. SWAPPED QK^T + pi key-
// permutation: P never touches LDS; V read in pi order (2x ds_read_b64).
__global__ __launch_bounds__(256) void attn_mfma_kernel(
    const bf16* __restrict__ qkv, const bf16* __restrict__ vT,
    bf16* __restrict__ y)
{
    const int id = blockIdx.x;              // 1024 = 32 g * 4 pair * 8 xcd
    const int xcd = id & 7;
    const int pi  = (id >> 3) & 3;          // pair 0 (heaviest) first
    const int bh  = ((id >> 5) << 3) + xcd;
    const int qa = pi, qb = 7 - pi;         // 128-row q-tile indices
    const int b = bh >> 3, h = bh & 7;
    const int tid = threadIdx.x;
    const int wave = tid >> 6, lane = tid & 63;
    const int quad = lane >> 4, l16 = lane & 15;

    __shared__ __align__(16) bf16 Ks[2][64 * 32];    // 8 KB, dbuf, swizzled
    __shared__ __align__(16) bf16 Vs[2][32 * 64];    // 8 KB, dbuf, swizzled
    __shared__ __align__(16) bf16 Qs[256 * 32];      // 16 KB Q staging

    const size_t rstride = 3 * Cc;
    const bf16* base  = qkv + (size_t)(b * Tc) * rstride + h * Dc;
    const bf16* vbase = vT + (size_t)bh * Dc * Tc;

    const int srow4  = lane >> 2;
    const int schunk = ((lane & 3) ^ ((lane >> 3) & 3)) * 8;
    const int vchunk = ((lane & 7) ^ (lane >> 3)) * 8;

    #pragma unroll
    for (int u = 0; u < 4; ++u) {
        const int qt = (u >> 1) ? qb : qa;
        const bf16* gq = base
            + (size_t)(qt * 128 + (u & 1) * 64 + wave * 16 + srow4) * rstride + schunk;
        GL2LDS16(gq, &Qs[(u * 64 + wave * 16) * 32]);
    }
    {
        const bf16* gk = base + (size_t)(wave * 16 + srow4) * rstride + 256 + schunk;
        GL2LDS16(gk, &Ks[0][(wave * 16) * 32]);
        const bf16* gv = vbase + (size_t)(wave * 8 + (lane >> 3)) * Tc + vchunk;
        GL2LDS16(gv, &Vs[0][(wave * 8) * 64]);
    }
    __syncthreads();
    const int qkphys = (quad ^ ((l16 >> 1) & 3)) * 8;
    bf16x8 afq[4];
    #pragma unroll
    for (int u = 0; u < 4; ++u)
        afq[u] = *(const bf16x8*)&Qs[(u * 64 + wave * 16 + l16) * 32 + qkphys];

    float l_acc[4] = {};
    f32x4 o[4][2];
    #pragma unroll
    for (int u = 0; u < 4; ++u)
        #pragma unroll
        for (int nt = 0; nt < 2; ++nt)
            o[u][nt] = (f32x4){0.f, 0.f, 0.f, 0.f};

    const int rloc = wave * 16 + quad * 4;     // output q rows (epilogue)
    const int qloc = wave * 16 + l16;          // this lane's P column (q row)
    // V read offsets in pi order: frag g, half jb -> 4 keys
    // 32g+16jb+4*quad+(0..3) at phys element offset
    // ((4g+2jb+(quad>>1)) ^ (l16&7))*8 + (quad&1)*4 within the row.
    const int vsw = l16 & 7;
    const int vq  = (quad >> 1);
    const int vo  = (quad & 1) * 4;

    const int ktmax = 2 * qb + 1;
    for (int kt = 0; kt <= ktmax; ++kt) {
        const int cur = kt & 1;

        if (kt < ktmax) {
            const int nxt = cur ^ 1;
            const bf16* gk = base
                + (size_t)((kt + 1) * 64 + wave * 16 + srow4) * rstride + 256 + schunk;
            GL2LDS16(gk, &Ks[nxt][(wave * 16) * 32]);
            const bf16* gv = vbase
                + (size_t)(wave * 8 + (lane >> 3)) * Tc + (kt + 1) * 64 + vchunk;
            GL2LDS16(gv, &Vs[nxt][(wave * 8) * 64]);
            asm volatile("s_waitcnt vmcnt(2)" ::: "memory");
        } else {
            asm volatile("s_waitcnt vmcnt(0)" ::: "memory");
        }
        __builtin_amdgcn_s_barrier();
        __builtin_amdgcn_sched_barrier(0);

        bf16x8 bk[4];
        #pragma unroll
        for (int j = 0; j < 4; ++j)
            bk[j] = *(const bf16x8*)&Ks[cur][(j * 16 + l16) * 32 + qkphys];

        // V fragments in pi order: bvx[g][nt], words {jb=0: q0,q1}{jb=1: q2,q3}
        U32x4 bvx[2][2];
        #pragma unroll
        for (int g = 0; g < 2; ++g)
            #pragma unroll
            for (int nt = 0; nt < 2; ++nt) {
                const int d = nt * 16 + l16;
                uint2 lo = *(const uint2*)&Vs[cur][d * 64 + (((4 * g + 0 + vq) ^ vsw) * 8 + vo)];
                uint2 hi = *(const uint2*)&Vs[cur][d * 64 + (((4 * g + 2 + vq) ^ vsw) * 8 + vo)];
                bvx[g][nt].q[0] = lo.x; bvx[g][nt].q[1] = lo.y;
                bvx[g][nt].q[2] = hi.x; bvx[g][nt].q[3] = hi.y;
            }

        #pragma unroll
        for (int t = 1; t >= 0; --t) {
            const int qt = t ? qb : qa;
            if (kt > 2 * qt + 1) continue;      // whole tile done (uniform)

            #pragma unroll
            for (int s = 0; s < 2; ++s) {
                const int u = t * 2 + s;
                if (kt > 2 * qt + s) continue;  // subtile masked (uniform)

                f32x4 sj[4];
                #pragma unroll
                for (int j = 0; j < 4; ++j)
                    sj[j] = __builtin_amdgcn_mfma_f32_16x16x32_bf16(
                        bk[j], afq[u], (f32x4){0.f,0.f,0.f,0.f}, 0, 0, 0);
                if (kt == 2 * qt + s) {         // diagonal: causal mask
                    #pragma unroll
                    for (int j = 0; j < 4; ++j)
                        #pragma unroll
                        for (int r = 0; r < 4; ++r)
                            if (j * 16 + quad * 4 + r > qloc) sj[j][r] = -INFINITY;
                }

                float p[4][4];
                float ls = 0.f;
                #pragma unroll
                for (int j = 0; j < 4; ++j) {
                    #pragma unroll
                    for (int r = 0; r < 4; ++r) {
                        p[j][r] = __builtin_amdgcn_exp2f(sj[j][r]);
                    }
                    ls += (p[j][0] + p[j][1]) + (p[j][2] + p[j][3]);
                }
                l_acc[u] += ls;

                U32x4 pa0, pa1;
                asm("v_cvt_pk_bf16_f32 %0, %1, %2" : "=v"(pa0.q[0]) : "v"(p[0][0]), "v"(p[0][1]));
                asm("v_cvt_pk_bf16_f32 %0, %1, %2" : "=v"(pa0.q[1]) : "v"(p[0][2]), "v"(p[0][3]));
                asm("v_cvt_pk_bf16_f32 %0, %1, %2" : "=v"(pa0.q[2]) : "v"(p[1][0]), "v"(p[1][1]));
                asm("v_cvt_pk_bf16_f32 %0, %1, %2" : "=v"(pa0.q[3]) : "v"(p[1][2]), "v"(p[1][3]));
                asm("v_cvt_pk_bf16_f32 %0, %1, %2" : "=v"(pa1.q[0]) : "v"(p[2][0]), "v"(p[2][1]));
                asm("v_cvt_pk_bf16_f32 %0, %1, %2" : "=v"(pa1.q[1]) : "v"(p[2][2]), "v"(p[2][3]));
                asm("v_cvt_pk_bf16_f32 %0, %1, %2" : "=v"(pa1.q[2]) : "v"(p[3][0]), "v"(p[3][1]));
                asm("v_cvt_pk_bf16_f32 %0, %1, %2" : "=v"(pa1.q[3]) : "v"(p[3][2]), "v"(p[3][3]));

                o[u][0] = __builtin_amdgcn_mfma_f32_16x16x32_bf16(pa0.v, bvx[0][0].v, o[u][0], 0, 0, 0);
                o[u][0] = __builtin_amdgcn_mfma_f32_16x16x32_bf16(pa1.v, bvx[1][0].v, o[u][0], 0, 0, 0);
                o[u][1] = __builtin_amdgcn_mfma_f32_16x16x32_bf16(pa0.v, bvx[0][1].v, o[u][1], 0, 0, 0);
                o[u][1] = __builtin_amdgcn_mfma_f32_16x16x32_bf16(pa1.v, bvx[1][1].v, o[u][1], 0, 0, 0);
            }
        }

        __builtin_amdgcn_s_barrier();
    }

    #pragma unroll
    for (int u = 0; u < 4; ++u) {
        const int qt = (u >> 1) ? qb : qa;
        float l = l_acc[u];
        l += __shfl_xor(l, 16);
        l += __shfl_xor(l, 32);
        float linv[4];
        #pragma unroll
        for (int r = 0; r < 4; ++r)
            linv[r] = 1.0f / __shfl(l, quad * 20 + r);
        #pragma unroll
        for (int nt = 0; nt < 2; ++nt)
            #pragma unroll
            for (int r = 0; r < 4; ++r)
                y[(size_t)(b * Tc + qt * 128 + (u & 1) * 64 + rloc + r) * Cc
                  + h * Dc + nt * 16 + l16]
                    = __float2bfloat16(o[u][nt][r] * linv[r]);
    }
}

// ---------------------------------------------------------------- launch
extern "C" void kernel_launch(void* const* d_in, const int* in_sizes, int n_in,
                              void* d_out, int out_size, void* d_ws, size_t ws_size,
                              hipStream_t stream)
{
    const int*   idx     = (const int*)  d_in[0];
    const float* tok_emb = (const float*)d_in[1];
    const float* pos_emb = (const float*)d_in[2];
    const float* ln1_g   = (const float*)d_in[3];
    const float* ln1_b   = (const float*)d_in[4];
    const float* wqkv    = (const float*)d_in[5];
    const float* bqkv    = (const float*)d_in[6];
    const float* wo      = (const float*)d_in[7];
    const float* bo      = (const float*)d_in[8];
    const float* ln2_g   = (const float*)d_in[9];
    const float* ln2_b   = (const float*)d_in[10];
    const float* wfc     = (const float*)d_in[11];
    const float* bfc     = (const float*)d_in[12];
    const float* wpr     = (const float*)d_in[13];
    const float* bpr     = (const float*)d_in[14];
    const float* lnf_g   = (const float*)d_in[15];
    const float* lnf_b   = (const float*)d_in[16];
    const float* w_lm    = (const float*)d_in[17];
    float* out = (float*)d_out;

    float* ws = (float*)d_ws;
    float* x  = ws;                                        // Mc*Cc fp32
    bf16* hb  = (bf16*)(x + (size_t)Mc * Cc);              // Mc*Cc bf16
    bf16* yb  = hb + (size_t)Mc * Cc;                      // Mc*Cc bf16
    float* big = (float*)(yb + (size_t)Mc * Cc);           // scratch region
    bf16* bigb = (bf16*)big;                               // qkv bf16
    bf16* wqT = (bf16*)(big + (size_t)Mc * 3 * Cc);        // [L][3C][C]
    bf16* woT = wqT + (size_t)Lc * 3 * Cc * Cc;            // [L][C][C]
    bf16* wfT = woT + (size_t)Lc * Cc * Cc;                // [L][FF][C]
    bf16* wpT = wfT + (size_t)Lc * Cc * FFc;               // [L][C][FF] (f permuted)
    bf16* wlT = wpT + (size_t)Lc * FFc * Cc;               // [V][C]
    bf16* vT  = wlT + (size_t)Vc * Cc;                     // [B][H][D][T]

    dim3 blk(256);
    dim3 blkG(512);

    castT_kernel<false><<<dim3(3 * Cc / 32, Cc / 32, Lc), blk, 0, stream>>>(wqkv, wqT, Cc, 3 * Cc);
    castT_kernel<false><<<dim3(Cc / 32, Cc / 32, Lc),     blk, 0, stream>>>(wo,   woT, Cc, Cc);
    castT_kernel<false><<<dim3(FFc / 32, Cc / 32, Lc),    blk, 0, stream>>>(wfc,  wfT, Cc, FFc);
    castT_kernel<true><<<dim3(Cc / 32, FFc / 32, Lc),     blk, 0, stream>>>(wpr,  wpT, FFc, Cc);
    castT_kernel<false><<<dim3(Vc / 32, Cc / 32, 1),      blk, 0, stream>>>(w_lm, wlT, Cc, Vc);

    embed_ln_kernel<<<dim3(Mc), blk, 0, stream>>>(idx, tok_emb, pos_emb,
                                                  ln1_g, ln1_b, x, hb);

    for (int l = 0; l < Lc; ++l) {
        const bf16* WqT = wqT + (size_t)l * 3 * Cc * Cc;
        const bf16* WoT = woT + (size_t)l * Cc * Cc;
        const bf16* WfT = wfT + (size_t)l * Cc * FFc;
        const bf16* WpT = wpT + (size_t)l * FFc * Cc;
        const float* bq = bqkv + (size_t)l * 3 * Cc;
        const float* bo_ = bo  + (size_t)l * Cc;
        const float* bf_ = bfc + (size_t)l * FFc;
        const float* bp = bpr  + (size_t)l * Cc;
        const float* gn = (l < Lc - 1) ? ln1_g + (size_t)(l + 1) * Cc : lnf_g;
        const float* bn = (l < Lc - 1) ? ln1_b + (size_t)(l + 1) * Cc : lnf_b;

        // qkv: q,k -> bigb [M,3C]; v -> vT[B][H][D][T]   (NT=6, XCD-swizzled)
        mfma_gemm_kernel<false, true, true><<<dim3(Mc / 128 * 6), blkG, 0, stream>>>(
            hb, WqT, bq, nullptr, nullptr, bigb, vT, Mc, 3 * Cc, Cc, 6);
        attn_mfma_kernel<<<dim3(1024), blk, 0, stream>>>(bigb, vT, yb);
        // x = x + yb @ Wo + bo;  hb = LN2(x)
        mfma_gemm_ln_kernel<<<dim3(Mc / 128), blkG, 0, stream>>>(
            yb, WoT, bo_, x, ln2_g + (size_t)l * Cc, ln2_b + (size_t)l * Cc,
            x, hb, Cc);
        // fused MLP: x = x + gelu(hb@Wf+bf)@Wp + bp;  hb = LN_next(x)
        fused_ff_ln_kernel<<<dim3(Mc / 128), blkG, 0, stream>>>(
            hb, WfT, bf_, WpT, bp, gn, bn, x, hb);
    }

    // logits = hb @ w_lm   (NT=1)
    mfma_gemm_kernel<false, false, false><<<dim3(Mc / 128), blkG, 0, stream>>>(
        hb, wlT, nullptr, nullptr, out, nullptr, nullptr, Mc, Vc, Cc, 1);
}

// Round 14
// 1525.880 us; speedup vs baseline: 1.0550x; 1.0079x over previous
//
#include <hip/hip_runtime.h>
#include <hip/hip_bf16.h>
#include <cstddef>

// GPT-small: L=8 H=8 C=256 V=128 T=1024 B=32, D=32, FF=1024
static constexpr int Lc = 8, Hc = 8, Cc = 256, Vc = 128, Tc = 1024, Bc = 32;
static constexpr int Dc = Cc / Hc;       // 32
static constexpr int FFc = 4 * Cc;       // 1024
static constexpr int Mc = Bc * Tc;       // 32768 tokens
static constexpr float EPSc = 1e-5f;
// softmax scale (1/sqrt(32)) folded together with log2(e) into Q at the
// qkv-GEMM epilogue, so attention can use a bare v_exp_f32 (exp2).
static constexpr float QSCALE_LOG2E = 0.25503486f;  // 0.176776695 * 1.44269504

typedef __bf16 bf16x8 __attribute__((ext_vector_type(8)));
typedef float f32x4 __attribute__((ext_vector_type(4)));
typedef __hip_bfloat16 bf16;

union U32x4 { uint32_t q[4]; bf16x8 v; };

#define GL2LDS16(g, l) __builtin_amdgcn_global_load_lds( \
    (const __attribute__((address_space(1))) void*)(g),  \
    (__attribute__((address_space(3))) void*)(l), 16, 0, 0)

// ------------------------------------------- embedding + LN1(layer0) fused
__global__ __launch_bounds__(256) void embed_ln_kernel(
    const int* __restrict__ idx, const float* __restrict__ tok,
    const float* __restrict__ pos, const float* __restrict__ g,
    const float* __restrict__ b, float* __restrict__ x, bf16* __restrict__ hb)
{
    int row = blockIdx.x;
    int tid = threadIdx.x;
    int t = row & (Tc - 1);
    int token = idx[row];
    float v = tok[(size_t)token * Cc + tid] + pos[(size_t)t * Cc + tid];
    x[(size_t)row * Cc + tid] = v;
    __shared__ float red[4];
    float s = v;
    #pragma unroll
    for (int off = 32; off; off >>= 1) s += __shfl_xor(s, off);
    int lane = tid & 63, wave = tid >> 6;
    if (lane == 0) red[wave] = s;
    __syncthreads();
    float mean = (red[0] + red[1] + red[2] + red[3]) * (1.0f / Cc);
    float dv = v - mean;
    float s2 = dv * dv;
    #pragma unroll
    for (int off = 32; off; off >>= 1) s2 += __shfl_xor(s2, off);
    __syncthreads();
    if (lane == 0) red[wave] = s2;
    __syncthreads();
    float var = (red[0] + red[1] + red[2] + red[3]) * (1.0f / Cc);
    hb[(size_t)row * Cc + tid] = __float2bfloat16(dv * rsqrtf(var + EPSc) * g[tid] + b[tid]);
}

// ------------------------------------------------- weight cast + transpose
// PERMK: permute the K (fast) axis within each 64-block by pos(f) so the
// fused MLP's GEMM2 B-fragments are contiguous 16B reads.
// pos(f) = (f&32) | (((f>>2)&3)<<3) | (((f>>4)&1)<<2) | (f&3):
// global chunk g*4+quad holds f = 32g+16jb+4quad+r in slot order jb*4+r.
// (Weights only — permuting vT's write side or re-pairing attention's
// q-tiles both regressed downstream dispatches; R10-R12 lessons.)
template <bool PERMK>
__global__ __launch_bounds__(256) void castT_kernel(
    const float* __restrict__ W, bf16* __restrict__ Wt, int K, int N)
{
    __shared__ float tile[32][33];
    const float* Wl = W + (size_t)blockIdx.z * K * N;
    bf16* Wtl = Wt + (size_t)blockIdx.z * K * N;
    int k0 = blockIdx.y * 32, n0 = blockIdx.x * 32;
    int tid = threadIdx.x;
    for (int e = tid; e < 1024; e += 256) {
        int r = e >> 5, c = e & 31;
        tile[r][c] = Wl[(size_t)(k0 + r) * N + n0 + c];
    }
    __syncthreads();
    for (int e = tid; e < 1024; e += 256) {
        int r = e >> 5, c = e & 31;
        int kk = k0 + c;
        if (PERMK) {
            int f = kk & 63;
            kk = (kk & ~63) | (f & 32) | (((f >> 2) & 3) << 3)
                 | (((f >> 4) & 1) << 2) | (f & 3);
        }
        Wtl[(size_t)(n0 + r) * K + kk] = __float2bfloat16(tile[c][r]);
    }
}

__device__ __forceinline__ float gelu_f(float x) {
    const float k2 = 2.0f * 0.7978845608028654f;
    float u2 = k2 * (x + 0.044715f * x * x * x);
    return x / (1.0f + __expf(-u2));
}

// ---------------------------------------------------------------- MFMA GEMM
// 128x128 tile, BK=64, XOR-swizzled LDS, swapped operands, XCD-aware flat
// grid. 512 threads / 8 waves (4m x 2n, 32x64 per wave).
// K-tiles double-buffered with counted s_waitcnt vmcnt(4) + raw s_barriers.
template <bool GELU, bool OUT_BF16, bool VSPLIT>
__global__ __launch_bounds__(512) void mfma_gemm_kernel(
    const bf16* __restrict__ A,    // [M][K]
    const bf16* __restrict__ Bt,   // [N][K]
    const float* __restrict__ bias,
    const float* __restrict__ res, // fp32 [M][N] or null
    float* __restrict__ Cf,        // fp32 out (used if !OUT_BF16)
    bf16* __restrict__ Cb,         // bf16 out (used if OUT_BF16)
    bf16* __restrict__ vTout,      // V^T out (used if VSPLIT)
    int M, int N, int K, int NT)
{
    __shared__ __align__(16) bf16 Asm[2][128 * 64];   // 32 KB dbuf
    __shared__ __align__(16) bf16 Bsm[2][128 * 64];   // 32 KB dbuf
    const int id = blockIdx.x;
    const int xcd = id & 7, q = id >> 3;
    const int m0 = ((q / NT) * 8 + xcd) * 128, n0 = (q % NT) * 128;
    const int tid = threadIdx.x;
    const int wave = tid >> 6, lane = tid & 63;
    const int quad = lane >> 4, l16 = lane & 15;
    const int wm = (wave >> 1) * 32, wn = (wave & 1) * 64;
    const int srow = lane >> 3;                    // 0..7
    const int scol = ((lane & 7) ^ srow) * 8;      // swizzled source k-chunk

    f32x4 acc[2][4];
    #pragma unroll
    for (int i = 0; i < 2; ++i)
        #pragma unroll
        for (int j = 0; j < 4; ++j)
            acc[i][j] = (f32x4){0.f, 0.f, 0.f, 0.f};

    // prologue: stage K-tile 0 into buffer 0 (8 waves x 2 bands each)
    #pragma unroll
    for (int i = 0; i < 2; ++i) {
        int rband = wave * 16 + i * 8;                       // wave-uniform
        GL2LDS16(A  + (size_t)(m0 + rband + srow) * K + scol, &Asm[0][rband * 64]);
        GL2LDS16(Bt + (size_t)(n0 + rband + srow) * K + scol, &Bsm[0][rband * 64]);
    }

    const int nk = K >> 6;
    for (int kt = 0; kt < nk; ++kt) {
        const int cur = kt & 1;
        if (kt + 1 < nk) {
            const int k0 = (kt + 1) << 6;
            #pragma unroll
            for (int i = 0; i < 2; ++i) {
                int rband = wave * 16 + i * 8;
                GL2LDS16(A  + (size_t)(m0 + rband + srow) * K + k0 + scol,
                         &Asm[cur ^ 1][rband * 64]);
                GL2LDS16(Bt + (size_t)(n0 + rband + srow) * K + k0 + scol,
                         &Bsm[cur ^ 1][rband * 64]);
            }
            asm volatile("s_waitcnt vmcnt(4)" ::: "memory");
        } else {
            asm volatile("s_waitcnt vmcnt(0)" ::: "memory");
        }
        __builtin_amdgcn_s_barrier();            // tile kt ready for all waves
        __builtin_amdgcn_sched_barrier(0);

        #pragma unroll
        for (int ks = 0; ks < 2; ++ks) {
            const int phys = ((ks * 4 + quad) ^ (l16 & 7)) * 8;  // de-swizzle
            bf16x8 af[2], bfr[4];
            #pragma unroll
            for (int i = 0; i < 2; ++i)
                af[i] = *(const bf16x8*)&Asm[cur][(wm + i * 16 + l16) * 64 + phys];
            #pragma unroll
            for (int j = 0; j < 4; ++j)
                bfr[j] = *(const bf16x8*)&Bsm[cur][(wn + j * 16 + l16) * 64 + phys];
            #pragma unroll
            for (int i = 0; i < 2; ++i)
                #pragma unroll
                for (int j = 0; j < 4; ++j)
                    acc[i][j] = __builtin_amdgcn_mfma_f32_16x16x32_bf16(
                        bfr[j], af[i], acc[i][j], 0, 0, 0);
        }
        __builtin_amdgcn_s_barrier();
    }

    #pragma unroll
    for (int i = 0; i < 2; ++i) {
        const int m = m0 + wm + i * 16 + l16;
        #pragma unroll
        for (int j = 0; j < 4; ++j) {
            const int nb = n0 + wn + j * 16 + quad * 4;
            f32x4 v = acc[i][j];
            if (bias) {
                float4 b4 = *(const float4*)(bias + nb);
                v[0] += b4.x; v[1] += b4.y; v[2] += b4.z; v[3] += b4.w;
            }
            if (GELU) {
                #pragma unroll
                for (int r = 0; r < 4; ++r) v[r] = gelu_f(v[r]);
            }
            if (res) {
                float4 r4 = *(const float4*)(res + (size_t)m * N + nb);
                v[0] += r4.x; v[1] += r4.y; v[2] += r4.z; v[3] += r4.w;
            }
            if (VSPLIT && nb < Cc) {
                #pragma unroll
                for (int r = 0; r < 4; ++r) v[r] *= QSCALE_LOG2E;
            }
            if (VSPLIT && nb >= 2 * Cc) {
                int hv = (nb - 2 * Cc) >> 5, dv = (nb - 2 * Cc) & 31;
                int bq = m >> 10, t = m & 1023;
                bf16* vp = vTout + ((size_t)(bq * Hc + hv) * Dc + dv) * Tc + t;
                #pragma unroll
                for (int r = 0; r < 4; ++r)
                    vp[(size_t)r * Tc] = __float2bfloat16(v[r]);
            } else if (OUT_BF16) {
                union { bf16 h[4]; uint2 u; } p;
                #pragma unroll
                for (int r = 0; r < 4; ++r) p.h[r] = __float2bfloat16(v[r]);
                *(uint2*)(Cb + (size_t)m * N + nb) = p.u;
            } else {
                *(float4*)(Cf + (size_t)m * N + nb) = (float4){v[0], v[1], v[2], v[3]};
            }
        }
    }
}

// --------------------------------------------- MFMA GEMM + residual + LN
// 512 threads / 8 waves (4m x 2n). K-tiles double-buffered, counted vmcnt(6).
__global__ __launch_bounds__(512) void mfma_gemm_ln_kernel(
    const bf16* __restrict__ A,    // [M][K]
    const bf16* __restrict__ Bt,   // [256][K]
    const float* __restrict__ bias,
    const float* __restrict__ res, // fp32 [M][256]
    const float* __restrict__ g, const float* __restrict__ b,
    float* __restrict__ xout, bf16* __restrict__ hbout, int K)
{
    __shared__ __align__(16) bf16 Asm[2][128 * 64];   // 32 KB dbuf
    __shared__ __align__(16) bf16 Bsm[2][256 * 64];   // 64 KB dbuf
    __shared__ float red[128][2][2];                  // 2 KB
    const int m0 = blockIdx.x * 128;
    const int tid = threadIdx.x;
    const int wave = tid >> 6, lane = tid & 63;
    const int quad = lane >> 4, l16 = lane & 15;
    const int wm = (wave >> 1) * 32, wn = (wave & 1) * 128;
    const int wnIdx = wave & 1;
    const int srow = lane >> 3;
    const int scol = ((lane & 7) ^ srow) * 8;

    f32x4 acc[2][8];
    #pragma unroll
    for (int i = 0; i < 2; ++i)
        #pragma unroll
        for (int j = 0; j < 8; ++j)
            acc[i][j] = (f32x4){0.f, 0.f, 0.f, 0.f};

    #pragma unroll
    for (int i = 0; i < 2; ++i) {
        int rband = wave * 16 + i * 8;
        GL2LDS16(A + (size_t)(m0 + rband + srow) * K + scol, &Asm[0][rband * 64]);
    }
    #pragma unroll
    for (int i = 0; i < 4; ++i) {
        int rband = wave * 32 + i * 8;
        GL2LDS16(Bt + (size_t)(rband + srow) * K + scol, &Bsm[0][rband * 64]);
    }

    const int nk = K >> 6;
    for (int kt = 0; kt < nk; ++kt) {
        const int cur = kt & 1;
        if (kt + 1 < nk) {
            const int k0 = (kt + 1) << 6;
            #pragma unroll
            for (int i = 0; i < 2; ++i) {
                int rband = wave * 16 + i * 8;
                GL2LDS16(A + (size_t)(m0 + rband + srow) * K + k0 + scol,
                         &Asm[cur ^ 1][rband * 64]);
            }
            #pragma unroll
            for (int i = 0; i < 4; ++i) {
                int rband = wave * 32 + i * 8;
                GL2LDS16(Bt + (size_t)(rband + srow) * K + k0 + scol,
                         &Bsm[cur ^ 1][rband * 64]);
            }
            asm volatile("s_waitcnt vmcnt(6)" ::: "memory");
        } else {
            asm volatile("s_waitcnt vmcnt(0)" ::: "memory");
        }
        __builtin_amdgcn_s_barrier();
        __builtin_amdgcn_sched_barrier(0);

        #pragma unroll
        for (int ks = 0; ks < 2; ++ks) {
            const int phys = ((ks * 4 + quad) ^ (l16 & 7)) * 8;
            bf16x8 af[2], bfr[8];
            #pragma unroll
            for (int i = 0; i < 2; ++i)
                af[i] = *(const bf16x8*)&Asm[cur][(wm + i * 16 + l16) * 64 + phys];
            #pragma unroll
            for (int j = 0; j < 8; ++j)
                bfr[j] = *(const bf16x8*)&Bsm[cur][(wn + j * 16 + l16) * 64 + phys];
            #pragma unroll
            for (int i = 0; i < 2; ++i)
                #pragma unroll
                for (int j = 0; j < 8; ++j)
                    acc[i][j] = __builtin_amdgcn_mfma_f32_16x16x32_bf16(
                        bfr[j], af[i], acc[i][j], 0, 0, 0);
        }
        __builtin_amdgcn_s_barrier();
    }

    #pragma unroll
    for (int i = 0; i < 2; ++i) {
        const int rl = wm + i * 16 + l16;
        const int m = m0 + rl;
        float s = 0.f, s2 = 0.f;
        #pragma unroll
        for (int j = 0; j < 8; ++j) {
            const int nb = wn + j * 16 + quad * 4;
            float4 b4 = *(const float4*)(bias + nb);
            float4 r4 = *(const float4*)(res + (size_t)m * Cc + nb);
            acc[i][j][0] += b4.x + r4.x; acc[i][j][1] += b4.y + r4.y;
            acc[i][j][2] += b4.z + r4.z; acc[i][j][3] += b4.w + r4.w;
            #pragma unroll
            for (int r = 0; r < 4; ++r) {
                s += acc[i][j][r];
                s2 += acc[i][j][r] * acc[i][j][r];
            }
        }
        s  += __shfl_xor(s, 16);  s  += __shfl_xor(s, 32);
        s2 += __shfl_xor(s2, 16); s2 += __shfl_xor(s2, 32);
        if (quad == 0) { red[rl][wnIdx][0] = s; red[rl][wnIdx][1] = s2; }
    }
    __syncthreads();

    #pragma unroll
    for (int i = 0; i < 2; ++i) {
        const int rl = wm + i * 16 + l16;
        const int m = m0 + rl;
        float s  = red[rl][0][0] + red[rl][1][0];
        float s2 = red[rl][0][1] + red[rl][1][1];
        float mean = s * (1.0f / Cc);
        float rstd = rsqrtf(s2 * (1.0f / Cc) - mean * mean + EPSc);
        #pragma unroll
        for (int j = 0; j < 8; ++j) {
            const int nb = wn + j * 16 + quad * 4;
            f32x4 v = acc[i][j];
            *(float4*)(xout + (size_t)m * Cc + nb) = (float4){v[0], v[1], v[2], v[3]};
            float4 g4 = *(const float4*)(g + nb);
            float4 bb4 = *(const float4*)(b + nb);
            union { bf16 h[4]; uint2 u; } p;
            p.h[0] = __float2bfloat16((v[0] - mean) * rstd * g4.x + bb4.x);
            p.h[1] = __float2bfloat16((v[1] - mean) * rstd * g4.y + bb4.y);
            p.h[2] = __float2bfloat16((v[2] - mean) * rstd * g4.z + bb4.z);
            p.h[3] = __float2bfloat16((v[3] - mean) * rstd * g4.w + bb4.w);
            *(uint2*)(hbout + (size_t)m * Cc + nb) = p.u;
        }
    }
}

// ------------------------------------------- fused MLP: gelu(hb@Wf+b1)@Wp
//                                             + b2 + residual + LN
// Attention-structure port (R7 k-chunk fix). Wp pre-permuted in global
// (castT_kernel<true>) so GEMM2 B-fragments are contiguous ds_read_b128.
__global__ __launch_bounds__(512) void fused_ff_ln_kernel(
    const bf16* __restrict__ A,     // hb [M][256]
    const bf16* __restrict__ Wf,    // WfT [1024 f][256 c]
    const float* __restrict__ b1,   // [1024]
    const bf16* __restrict__ Wp,    // wpT [256 outc][1024 f], f pi-permuted
    const float* __restrict__ b2,   // [256]
    const float* __restrict__ g, const float* __restrict__ bb,
    float* __restrict__ x,          // residual in / out, fp32 [M][256]
    bf16* __restrict__ hbout)       // LN output [M][256]
{
    // 2 bufs x (Wf slice 64x256 + Wp slice 256x64) = 2 x 32768 elems = 128 KB
    __shared__ __align__(16) bf16 lds[2 * 32768];
    const int m0 = blockIdx.x * 128;
    const int tid = threadIdx.x;
    const int wave = tid >> 6, lane = tid & 63;
    const int quad = lane >> 4, l16 = lane & 15;

    // ---- prologue: stage hb tile [128][256] into lds[0..32768)
    #pragma unroll
    for (int it = 0; it < 8; ++it) {
        const int row = wave * 16 + it * 2 + (lane >> 5);
        const int clog = (lane & 31) ^ (row & 7);
        GL2LDS16(A + (size_t)(m0 + row) * Cc + clog * 8,
                 &lds[(wave * 16 + it * 2) * Cc]);
    }
    __syncthreads();
    // extract this wave's 16 rows as B-operand frags: for mfma kk, lane
    // (quad,l16) supplies hb[row = wave*16+l16][c = (kk*4+quad)*8 + e]
    bf16x8 ahb[8];
    #pragma unroll
    for (int kk = 0; kk < 8; ++kk)
        ahb[kk] = *(const bf16x8*)&lds[(wave * 16 + l16) * Cc
                                       + (((kk * 4 + quad) ^ (l16 & 7)) * 8)];
    asm volatile("s_waitcnt lgkmcnt(0)" ::: "memory");
    __builtin_amdgcn_sched_barrier(0);
    __builtin_amdgcn_s_barrier();   // all reads done before staging overwrites

    // stage one f-slice (Wf rows f0..f0+63 x 256c; Wp rows 0..255 x 64f)
    #define FF_STAGE(buf, sl) do {                                             \
        const int f0s = (sl) * 64;                                             \
        _Pragma("unroll")                                                      \
        for (int it = 0; it < 4; ++it) {                                       \
            const int row = it * 16 + wave * 2 + (lane >> 5);                  \
            const int clog = (lane & 31) ^ (row & 7);                          \
            GL2LDS16(Wf + (size_t)(f0s + row) * Cc + clog * 8,                 \
                     &lds[(buf) * 32768 + (it * 16 + wave * 2) * Cc]);         \
        }                                                                      \
        _Pragma("unroll")                                                      \
        for (int it = 0; it < 4; ++it) {                                       \
            const int row = it * 64 + wave * 8 + (lane >> 3);                  \
            const int clog = (lane & 7) ^ (row & 7);                           \
            GL2LDS16(Wp + (size_t)row * FFc + f0s + clog * 8,                  \
                     &lds[(buf) * 32768 + 16384 + (it * 64 + wave * 8) * 64]); \
        }                                                                      \
    } while (0)

    FF_STAGE(0, 0);

    f32x4 o[16];
    #pragma unroll
    for (int nt = 0; nt < 16; ++nt) o[nt] = (f32x4){0.f, 0.f, 0.f, 0.f};

    for (int kt = 0; kt < 16; ++kt) {
        const int cur = kt & 1;
        if (kt < 15) {
            FF_STAGE(cur ^ 1, kt + 1);
            asm volatile("s_waitcnt vmcnt(8)" ::: "memory");
        } else {
            asm volatile("s_waitcnt vmcnt(0)" ::: "memory");
        }
        __builtin_amdgcn_s_barrier();
        __builtin_amdgcn_sched_barrier(0);

        const bf16* Wfb = &lds[cur * 32768];
        const bf16* Wpb = &lds[cur * 32768 + 16384];

        // GEMM1 (swapped): sj[j] holds S[f=kt*64+j*16+quad*4+r][m=wave*16+l16]
        // mfma kk covers c-chunks kk*4..kk*4+3; lane supplies chunk kk*4+quad.
        f32x4 sj[4];
        #pragma unroll
        for (int j = 0; j < 4; ++j) sj[j] = (f32x4){0.f, 0.f, 0.f, 0.f};
        #pragma unroll
        for (int kk = 0; kk < 8; ++kk) {
            const int ph = ((kk * 4 + quad) ^ (l16 & 7)) * 8;
            #pragma unroll
            for (int j = 0; j < 4; ++j) {
                bf16x8 wfr = *(const bf16x8*)&Wfb[(j * 16 + l16) * Cc + ph];
                sj[j] = __builtin_amdgcn_mfma_f32_16x16x32_bf16(
                    wfr, ahb[kk], sj[j], 0, 0, 0);
            }
        }

        // bias1 + gelu
        float p[4][4];
        #pragma unroll
        for (int j = 0; j < 4; ++j) {
            float4 b4 = *(const float4*)(b1 + kt * 64 + j * 16 + quad * 4);
            p[j][0] = gelu_f(sj[j][0] + b4.x);
            p[j][1] = gelu_f(sj[j][1] + b4.y);
            p[j][2] = gelu_f(sj[j][2] + b4.z);
            p[j][3] = gelu_f(sj[j][3] + b4.w);
        }

        // pi-order PV A-frags: lane's own values, no shuffles
        U32x4 pa0, pa1;
        asm("v_cvt_pk_bf16_f32 %0, %1, %2" : "=v"(pa0.q[0]) : "v"(p[0][0]), "v"(p[0][1]));
        asm("v_cvt_pk_bf16_f32 %0, %1, %2" : "=v"(pa0.q[1]) : "v"(p[0][2]), "v"(p[0][3]));
        asm("v_cvt_pk_bf16_f32 %0, %1, %2" : "=v"(pa0.q[2]) : "v"(p[1][0]), "v"(p[1][1]));
        asm("v_cvt_pk_bf16_f32 %0, %1, %2" : "=v"(pa0.q[3]) : "v"(p[1][2]), "v"(p[1][3]));
        asm("v_cvt_pk_bf16_f32 %0, %1, %2" : "=v"(pa1.q[0]) : "v"(p[2][0]), "v"(p[2][1]));
        asm("v_cvt_pk_bf16_f32 %0, %1, %2" : "=v"(pa1.q[1]) : "v"(p[2][2]), "v"(p[2][3]));
        asm("v_cvt_pk_bf16_f32 %0, %1, %2" : "=v"(pa1.q[2]) : "v"(p[3][0]), "v"(p[3][1]));
        asm("v_cvt_pk_bf16_f32 %0, %1, %2" : "=v"(pa1.q[3]) : "v"(p[3][2]), "v"(p[3][3]));

        // GEMM2: o[nt] += P @ Wp-slice. Wp pre-permuted: frag g is one
        // contiguous b128 at chunk (g*4+quad), staged-XOR de-swizzled.
        #pragma unroll
        for (int nt = 0; nt < 16; ++nt) {
            const int d = nt * 16 + l16;
            bf16x8 w0 = *(const bf16x8*)&Wpb[d * 64 + (((0 + quad) ^ (l16 & 7)) * 8)];
            bf16x8 w1 = *(const bf16x8*)&Wpb[d * 64 + (((4 + quad) ^ (l16 & 7)) * 8)];
            o[nt] = __builtin_amdgcn_mfma_f32_16x16x32_bf16(pa0.v, w0, o[nt], 0, 0, 0);
            o[nt] = __builtin_amdgcn_mfma_f32_16x16x32_bf16(pa1.v, w1, o[nt], 0, 0, 0);
        }
        __builtin_amdgcn_s_barrier();   // buf cur reads done before overwrite
    }
    #undef FF_STAGE

    // ---- epilogue: bias2 + residual; LN stats per row (pure shfl: each
    // quad owns distinct rows, reduce across the 16 l16 lanes only)
    const int row0 = m0 + wave * 16 + quad * 4;
    float s[4] = {0.f, 0.f, 0.f, 0.f}, s2[4] = {0.f, 0.f, 0.f, 0.f};
    #pragma unroll
    for (int nt = 0; nt < 16; ++nt) {
        const int col = nt * 16 + l16;
        const float bpv = b2[col];
        #pragma unroll
        for (int r = 0; r < 4; ++r) {
            float v = o[nt][r] + bpv + x[(size_t)(row0 + r) * Cc + col];
            o[nt][r] = v;
            s[r] += v; s2[r] += v * v;
        }
    }
    #pragma unroll
    for (int r = 0; r < 4; ++r) {
        #pragma unroll
        for (int off = 1; off < 16; off <<= 1) {
            s[r]  += __shfl_xor(s[r], off);
            s2[r] += __shfl_xor(s2[r], off);
        }
    }
    float mean[4], rstd[4];
    #pragma unroll
    for (int r = 0; r < 4; ++r) {
        mean[r] = s[r] * (1.0f / Cc);
        rstd[r] = rsqrtf(s2[r] * (1.0f / Cc) - mean[r] * mean[r] + EPSc);
    }
    #pragma unroll
    for (int nt = 0; nt < 16; ++nt) {
        const int col = nt * 16 + l16;
        const float gv = g[col], bv = bb[col];
        #pragma unroll
        for (int r = 0; r < 4; ++r) {
            x[(size_t)(row0 + r) * Cc + col] = o[nt][r];
            hbout[(size_t)(row0 + r) * Cc + col] =
                __float2bfloat16((o[nt][r] - mean[r]) * rstd[r] * gv + bv);
        }
    }
}

// ---------------------------------------------------------------- attention
// MFMA flash attention, PAIRED q-tiles {pi, 7-pi} (R12-verified pairing).
// R13: K/V TRIPLE-buffered, prefetch 2 tiles ahead with counted vmcnt(4)
// (steady state) — tile kt's DMA now has TWO rounds of compute to land
// instead of one, removing the residual first-use stall. Buffer safety:
// buf[(kt+2)%3] was last read in round kt-1, protected by its end-barrier;
// vmcnt retires oldest-first so vmcnt(4) guarantees tile kt complete.
// SWAPPED QK^T + pi key-permutation: P never touches LDS.
__global__ __launch_bounds__(256) void attn_mfma_kernel(
    const bf16* __restrict__ qkv, const bf16* __restrict__ vT,
    bf16* __restrict__ y)
{
    const int id = blockIdx.x;              // 1024 = 32 g * 4 pair * 8 xcd
    const int xcd = id & 7;
    const int pi  = (id >> 3) & 3;          // pair 0 (heaviest) first
    const int bh  = ((id >> 5) << 3) + xcd;
    const int qa = pi, qb = 7 - pi;         // 128-row q-tile indices
    const int b = bh >> 3, h = bh & 7;
    const int tid = threadIdx.x;
    const int wave = tid >> 6, lane = tid & 63;
    const int quad = lane >> 4, l16 = lane & 15;

    __shared__ __align__(16) bf16 Ks[3][64 * 32];    // 12 KB, 3-buf, swizzled
    __shared__ __align__(16) bf16 Vs[3][32 * 64];    // 12 KB, 3-buf, swizzled
    __shared__ __align__(16) bf16 Qs[256 * 32];      // 16 KB Q staging

    const size_t rstride = 3 * Cc;
    const bf16* base  = qkv + (size_t)(b * Tc) * rstride + h * Dc;
    const bf16* vbase = vT + (size_t)bh * Dc * Tc;

    const int srow4  = lane >> 2;
    const int schunk = ((lane & 3) ^ ((lane >> 3) & 3)) * 8;
    const int vchunk = ((lane & 7) ^ (lane >> 3)) * 8;

    #pragma unroll
    for (int u = 0; u < 4; ++u) {
        const int qt = (u >> 1) ? qb : qa;
        const bf16* gq = base
            + (size_t)(qt * 128 + (u & 1) * 64 + wave * 16 + srow4) * rstride + schunk;
        GL2LDS16(gq, &Qs[(u * 64 + wave * 16) * 32]);
    }
    // prologue: stage K/V tiles 0 and 1 (ktmax >= 9 so tile 1 exists);
    // the syncthreads below drains all (vmcnt 0) — both tiles ready.
    #pragma unroll
    for (int t0 = 0; t0 < 2; ++t0) {
        const bf16* gk = base
            + (size_t)(t0 * 64 + wave * 16 + srow4) * rstride + 256 + schunk;
        GL2LDS16(gk, &Ks[t0][(wave * 16) * 32]);
        const bf16* gv = vbase + (size_t)(wave * 8 + (lane >> 3)) * Tc + t0 * 64 + vchunk;
        GL2LDS16(gv, &Vs[t0][(wave * 8) * 64]);
    }
    __syncthreads();
    const int qkphys = (quad ^ ((l16 >> 1) & 3)) * 8;
    bf16x8 afq[4];
    #pragma unroll
    for (int u = 0; u < 4; ++u)
        afq[u] = *(const bf16x8*)&Qs[(u * 64 + wave * 16 + l16) * 32 + qkphys];

    float l_acc[4] = {};
    f32x4 o[4][2];
    #pragma unroll
    for (int u = 0; u < 4; ++u)
        #pragma unroll
        for (int nt = 0; nt < 2; ++nt)
            o[u][nt] = (f32x4){0.f, 0.f, 0.f, 0.f};

    const int rloc = wave * 16 + quad * 4;     // output q rows (epilogue)
    const int qloc = wave * 16 + l16;          // this lane's P column (q row)
    // V read offsets in pi order: frag g, half jb -> 4 keys
    // 32g+16jb+4*quad+(0..3) at phys element offset
    // ((4g+2jb+(quad>>1)) ^ (l16&7))*8 + (quad&1)*4 within the row.
    const int vsw = l16 & 7;
    const int vq  = (quad >> 1);
    const int vo  = (quad & 1) * 4;

    const int ktmax = 2 * qb + 1;
    for (int kt = 0; kt <= ktmax; ++kt) {
        const int cur = kt % 3;

        if (kt + 2 <= ktmax) {
            // issue DMA for tile kt+2 into buf (kt+2)%3; safe: that buffer
            // (tile kt-1) was last read in round kt-1, whose end-barrier
            // precedes this point.
            const int nxt = (kt + 2) % 3;
            const bf16* gk = base
                + (size_t)((kt + 2) * 64 + wave * 16 + srow4) * rstride + 256 + schunk;
            GL2LDS16(gk, &Ks[nxt][(wave * 16) * 32]);
            const bf16* gv = vbase
                + (size_t)(wave * 8 + (lane >> 3)) * Tc + (kt + 2) * 64 + vchunk;
            GL2LDS16(gv, &Vs[nxt][(wave * 8) * 64]);
            // wait until only kt+1's and kt+2's 4 loads remain -> kt done.
            asm volatile("s_waitcnt vmcnt(4)" ::: "memory");
        } else if (kt + 1 <= ktmax) {
            // only kt+1's 2 loads may remain in flight.
            asm volatile("s_waitcnt vmcnt(2)" ::: "memory");
        } else {
            asm volatile("s_waitcnt vmcnt(0)" ::: "memory");
        }
        __builtin_amdgcn_s_barrier();            // tile kt ready for all waves
        __builtin_amdgcn_sched_barrier(0);

        bf16x8 bk[4];
        #pragma unroll
        for (int j = 0; j < 4; ++j)
            bk[j] = *(const bf16x8*)&Ks[cur][(j * 16 + l16) * 32 + qkphys];

        // V fragments in pi order: bvx[g][nt], words {jb=0: q0,q1}{jb=1: q2,q3}
        U32x4 bvx[2][2];
        #pragma unroll
        for (int g = 0; g < 2; ++g)
            #pragma unroll
            for (int nt = 0; nt < 2; ++nt) {
                const int d = nt * 16 + l16;
                uint2 lo = *(const uint2*)&Vs[cur][d * 64 + (((4 * g + 0 + vq) ^ vsw) * 8 + vo)];
                uint2 hi = *(const uint2*)&Vs[cur][d * 64 + (((4 * g + 2 + vq) ^ vsw) * 8 + vo)];
                bvx[g][nt].q[0] = lo.x; bvx[g][nt].q[1] = lo.y;
                bvx[g][nt].q[2] = hi.x; bvx[g][nt].q[3] = hi.y;
            }

        #pragma unroll
        for (int t = 1; t >= 0; --t) {
            const int qt = t ? qb : qa;
            if (kt > 2 * qt + 1) continue;      // whole tile done (uniform)

            #pragma unroll
            for (int s = 0; s < 2; ++s) {
                const int u = t * 2 + s;
                if (kt > 2 * qt + s) continue;  // subtile masked (uniform)

                f32x4 sj[4];
                #pragma unroll
                for (int j = 0; j < 4; ++j)
                    sj[j] = __builtin_amdgcn_mfma_f32_16x16x32_bf16(
                        bk[j], afq[u], (f32x4){0.f,0.f,0.f,0.f}, 0, 0, 0);
                if (kt == 2 * qt + s) {         // diagonal: causal mask
                    #pragma unroll
                    for (int j = 0; j < 4; ++j)
                        #pragma unroll
                        for (int r = 0; r < 4; ++r)
                            if (j * 16 + quad * 4 + r > qloc) sj[j][r] = -INFINITY;
                }

                float p[4][4];
                float ls = 0.f;
                #pragma unroll
                for (int j = 0; j < 4; ++j) {
                    #pragma unroll
                    for (int r = 0; r < 4; ++r) {
                        p[j][r] = __builtin_amdgcn_exp2f(sj[j][r]);
                    }
                    ls += (p[j][0] + p[j][1]) + (p[j][2] + p[j][3]);
                }
                l_acc[u] += ls;

                U32x4 pa0, pa1;
                asm("v_cvt_pk_bf16_f32 %0, %1, %2" : "=v"(pa0.q[0]) : "v"(p[0][0]), "v"(p[0][1]));
                asm("v_cvt_pk_bf16_f32 %0, %1, %2" : "=v"(pa0.q[1]) : "v"(p[0][2]), "v"(p[0][3]));
                asm("v_cvt_pk_bf16_f32 %0, %1, %2" : "=v"(pa0.q[2]) : "v"(p[1][0]), "v"(p[1][1]));
                asm("v_cvt_pk_bf16_f32 %0, %1, %2" : "=v"(pa0.q[3]) : "v"(p[1][2]), "v"(p[1][3]));
                asm("v_cvt_pk_bf16_f32 %0, %1, %2" : "=v"(pa1.q[0]) : "v"(p[2][0]), "v"(p[2][1]));
                asm("v_cvt_pk_bf16_f32 %0, %1, %2" : "=v"(pa1.q[1]) : "v"(p[2][2]), "v"(p[2][3]));
                asm("v_cvt_pk_bf16_f32 %0, %1, %2" : "=v"(pa1.q[2]) : "v"(p[3][0]), "v"(p[3][1]));
                asm("v_cvt_pk_bf16_f32 %0, %1, %2" : "=v"(pa1.q[3]) : "v"(p[3][2]), "v"(p[3][3]));

                o[u][0] = __builtin_amdgcn_mfma_f32_16x16x32_bf16(pa0.v, bvx[0][0].v, o[u][0], 0, 0, 0);
                o[u][0] = __builtin_amdgcn_mfma_f32_16x16x32_bf16(pa1.v, bvx[1][0].v, o[u][0], 0, 0, 0);
                o[u][1] = __builtin_amdgcn_mfma_f32_16x16x32_bf16(pa0.v, bvx[0][1].v, o[u][1], 0, 0, 0);
                o[u][1] = __builtin_amdgcn_mfma_f32_16x16x32_bf16(pa1.v, bvx[1][1].v, o[u][1], 0, 0, 0);
            }
        }

        // end of round: all waves done reading buf cur before it is
        // overwritten (tile kt+3 issues at round kt+1).
        __builtin_amdgcn_s_barrier();
    }

    #pragma unroll
    for (int u = 0; u < 4; ++u) {
        const int qt = (u >> 1) ? qb : qa;
        float l = l_acc[u];
        l += __shfl_xor(l, 16);
        l += __shfl_xor(l, 32);
        float linv[4];
        #pragma unroll
        for (int r = 0; r < 4; ++r)
            linv[r] = 1.0f / __shfl(l, quad * 20 + r);
        #pragma unroll
        for (int nt = 0; nt < 2; ++nt)
            #pragma unroll
            for (int r = 0; r < 4; ++r)
                y[(size_t)(b * Tc + qt * 128 + (u & 1) * 64 + rloc + r) * Cc
                  + h * Dc + nt * 16 + l16]
                    = __float2bfloat16(o[u][nt][r] * linv[r]);
    }
}

// ---------------------------------------------------------------- launch
extern "C" void kernel_launch(void* const* d_in, const int* in_sizes, int n_in,
                              void* d_out, int out_size, void* d_ws, size_t ws_size,
                              hipStream_t stream)
{
    const int*   idx     = (const int*)  d_in[0];
    const float* tok_emb = (const float*)d_in[1];
    const float* pos_emb = (const float*)d_in[2];
    const float* ln1_g   = (const float*)d_in[3];
    const float* ln1_b   = (const float*)d_in[4];
    const float* wqkv    = (const float*)d_in[5];
    const float* bqkv    = (const float*)d_in[6];
    const float* wo      = (const float*)d_in[7];
    const float* bo      = (const float*)d_in[8];
    const float* ln2_g   = (const float*)d_in[9];
    const float* ln2_b   = (const float*)d_in[10];
    const float* wfc     = (const float*)d_in[11];
    const float* bfc     = (const float*)d_in[12];
    const float* wpr     = (const float*)d_in[13];
    const float* bpr     = (const float*)d_in[14];
    const float* lnf_g   = (const float*)d_in[15];
    const float* lnf_b   = (const float*)d_in[16];
    const float* w_lm    = (const float*)d_in[17];
    float* out = (float*)d_out;

    float* ws = (float*)d_ws;
    float* x  = ws;                                        // Mc*Cc fp32
    bf16* hb  = (bf16*)(x + (size_t)Mc * Cc);              // Mc*Cc bf16
    bf16* yb  = hb + (size_t)Mc * Cc;                      // Mc*Cc bf16
    float* big = (float*)(yb + (size_t)Mc * Cc);           // scratch region
    bf16* bigb = (bf16*)big;                               // qkv bf16
    bf16* wqT = (bf16*)(big + (size_t)Mc * 3 * Cc);        // [L][3C][C]
    bf16* woT = wqT + (size_t)Lc * 3 * Cc * Cc;            // [L][C][C]
    bf16* wfT = woT + (size_t)Lc * Cc * Cc;                // [L][FF][C]
    bf16* wpT = wfT + (size_t)Lc * Cc * FFc;               // [L][C][FF] (f permuted)
    bf16* wlT = wpT + (size_t)Lc * FFc * Cc;               // [V][C]
    bf16* vT  = wlT + (size_t)Vc * Cc;                     // [B][H][D][T]

    dim3 blk(256);
    dim3 blkG(512);

    castT_kernel<false><<<dim3(3 * Cc / 32, Cc / 32, Lc), blk, 0, stream>>>(wqkv, wqT, Cc, 3 * Cc);
    castT_kernel<false><<<dim3(Cc / 32, Cc / 32, Lc),     blk, 0, stream>>>(wo,   woT, Cc, Cc);
    castT_kernel<false><<<dim3(FFc / 32, Cc / 32, Lc),    blk, 0, stream>>>(wfc,  wfT, Cc, FFc);
    castT_kernel<true><<<dim3(Cc / 32, FFc / 32, Lc),     blk, 0, stream>>>(wpr,  wpT, FFc, Cc);
    castT_kernel<false><<<dim3(Vc / 32, Cc / 32, 1),      blk, 0, stream>>>(w_lm, wlT, Cc, Vc);

    embed_ln_kernel<<<dim3(Mc), blk, 0, stream>>>(idx, tok_emb, pos_emb,
                                                  ln1_g, ln1_b, x, hb);

    for (int l = 0; l < Lc; ++l) {
        const bf16* WqT = wqT + (size_t)l * 3 * Cc * Cc;
        const bf16* WoT = woT + (size_t)l * Cc * Cc;
        const bf16* WfT = wfT + (size_t)l * Cc * FFc;
        const bf16* WpT = wpT + (size_t)l * FFc * Cc;
        const float* bq = bqkv + (size_t)l * 3 * Cc;
        const float* bo_ = bo  + (size_t)l * Cc;
        const float* bf_ = bfc + (size_t)l * FFc;
        const float* bp = bpr  + (size_t)l * Cc;
        const float* gn = (l < Lc - 1) ? ln1_g + (size_t)(l + 1) * Cc : lnf_g;
        const float* bn = (l < Lc - 1) ? ln1_b + (size_t)(l + 1) * Cc : lnf_b;

        // qkv: q,k -> bigb [M,3C]; v -> vT[B][H][D][T]   (NT=6, XCD-swizzled)
        mfma_gemm_kernel<false, true, true><<<dim3(Mc / 128 * 6), blkG, 0, stream>>>(
            hb, WqT, bq, nullptr, nullptr, bigb, vT, Mc, 3 * Cc, Cc, 6);
        attn_mfma_kernel<<<dim3(1024), blk, 0, stream>>>(bigb, vT, yb);
        // x = x + yb @ Wo + bo;  hb = LN2(x)
        mfma_gemm_ln_kernel<<<dim3(Mc / 128), blkG, 0, stream>>>(
            yb, WoT, bo_, x, ln2_g + (size_t)l * Cc, ln2_b + (size_t)l * Cc,
            x, hb, Cc);
        // fused MLP: x = x + gelu(hb@Wf+bf)@Wp + bp;  hb = LN_next(x)
        fused_ff_ln_kernel<<<dim3(Mc / 128), blkG, 0, stream>>>(
            hb, WfT, bf_, WpT, bp, gn, bn, x, hb);
    }

    // logits = hb @ w_lm   (NT=1)
    mfma_gemm_kernel<false, false, false><<<dim3(Mc / 128), blkG, 0, stream>>>(
        hb, wlT, nullptr, nullptr, out, nullptr, nullptr, Mc, Vc, Cc, 1);
}

// Round 16
// 1516.896 us; speedup vs baseline: 1.0612x; 1.0059x over previous
//
#include <hip/hip_runtime.h>
#include <hip/hip_bf16.h>
#include <cstddef>

// GPT-small: L=8 H=8 C=256 V=128 T=1024 B=32, D=32, FF=1024
static constexpr int Lc = 8, Hc = 8, Cc = 256, Vc = 128, Tc = 1024, Bc = 32;
static constexpr int Dc = Cc / Hc;       // 32
static constexpr int FFc = 4 * Cc;       // 1024
static constexpr int Mc = Bc * Tc;       // 32768 tokens
static constexpr float EPSc = 1e-5f;
// softmax scale (1/sqrt(32)) folded together with log2(e) into Q at the
// qkv-GEMM epilogue, so attention can use a bare v_exp_f32 (exp2).
static constexpr float QSCALE_LOG2E = 0.25503486f;  // 0.176776695 * 1.44269504

typedef __bf16 bf16x8 __attribute__((ext_vector_type(8)));
typedef float f32x4 __attribute__((ext_vector_type(4)));
typedef __hip_bfloat16 bf16;

union U32x4 { uint32_t q[4]; bf16x8 v; };

#define GL2LDS16(g, l) __builtin_amdgcn_global_load_lds( \
    (const __attribute__((address_space(1))) void*)(g),  \
    (__attribute__((address_space(3))) void*)(l), 16, 0, 0)

// ------------------------------------------- embedding + LN1(layer0) fused
__global__ __launch_bounds__(256) void embed_ln_kernel(
    const int* __restrict__ idx, const float* __restrict__ tok,
    const float* __restrict__ pos, const float* __restrict__ g,
    const float* __restrict__ b, float* __restrict__ x, bf16* __restrict__ hb)
{
    int row = blockIdx.x;
    int tid = threadIdx.x;
    int t = row & (Tc - 1);
    int token = idx[row];
    float v = tok[(size_t)token * Cc + tid] + pos[(size_t)t * Cc + tid];
    x[(size_t)row * Cc + tid] = v;
    __shared__ float red[4];
    float s = v;
    #pragma unroll
    for (int off = 32; off; off >>= 1) s += __shfl_xor(s, off);
    int lane = tid & 63, wave = tid >> 6;
    if (lane == 0) red[wave] = s;
    __syncthreads();
    float mean = (red[0] + red[1] + red[2] + red[3]) * (1.0f / Cc);
    float dv = v - mean;
    float s2 = dv * dv;
    #pragma unroll
    for (int off = 32; off; off >>= 1) s2 += __shfl_xor(s2, off);
    __syncthreads();
    if (lane == 0) red[wave] = s2;
    __syncthreads();
    float var = (red[0] + red[1] + red[2] + red[3]) * (1.0f / Cc);
    hb[(size_t)row * Cc + tid] = __float2bfloat16(dv * rsqrtf(var + EPSc) * g[tid] + b[tid]);
}

// ------------------------------------------------- weight cast + transpose
// PERMK: permute the K (fast) axis within each 64-block by pos(f) so the
// fused MLP's GEMM2 B-fragments are contiguous 16B reads.
// pos(f) = (f&32) | (((f>>2)&3)<<3) | (((f>>4)&1)<<2) | (f&3):
// global chunk g*4+quad holds f = 32g+16jb+4quad+r in slot order jb*4+r.
// (Weights only — permuting vT's write side or re-pairing attention's
// q-tiles both regressed downstream dispatches; R10-R12 lessons.)
template <bool PERMK>
__global__ __launch_bounds__(256) void castT_kernel(
    const float* __restrict__ W, bf16* __restrict__ Wt, int K, int N)
{
    __shared__ float tile[32][33];
    const float* Wl = W + (size_t)blockIdx.z * K * N;
    bf16* Wtl = Wt + (size_t)blockIdx.z * K * N;
    int k0 = blockIdx.y * 32, n0 = blockIdx.x * 32;
    int tid = threadIdx.x;
    for (int e = tid; e < 1024; e += 256) {
        int r = e >> 5, c = e & 31;
        tile[r][c] = Wl[(size_t)(k0 + r) * N + n0 + c];
    }
    __syncthreads();
    for (int e = tid; e < 1024; e += 256) {
        int r = e >> 5, c = e & 31;
        int kk = k0 + c;
        if (PERMK) {
            int f = kk & 63;
            kk = (kk & ~63) | (f & 32) | (((f >> 2) & 3) << 3)
                 | (((f >> 4) & 1) << 2) | (f & 3);
        }
        Wtl[(size_t)(n0 + r) * K + kk] = __float2bfloat16(tile[c][r]);
    }
}

__device__ __forceinline__ float gelu_f(float x) {
    const float k2 = 2.0f * 0.7978845608028654f;
    float u2 = k2 * (x + 0.044715f * x * x * x);
    return x / (1.0f + __expf(-u2));
}

// ---------------------------------------------------------------- MFMA GEMM
// 128x128 tile, BK=64, XOR-swizzled LDS, swapped operands, XCD-aware flat
// grid. 512 threads / 8 waves (4m x 2n, 32x64 per wave).
// K-tiles double-buffered with counted s_waitcnt vmcnt(4) + raw s_barriers.
template <bool GELU, bool OUT_BF16, bool VSPLIT>
__global__ __launch_bounds__(512) void mfma_gemm_kernel(
    const bf16* __restrict__ A,    // [M][K]
    const bf16* __restrict__ Bt,   // [N][K]
    const float* __restrict__ bias,
    const float* __restrict__ res, // fp32 [M][N] or null
    float* __restrict__ Cf,        // fp32 out (used if !OUT_BF16)
    bf16* __restrict__ Cb,         // bf16 out (used if OUT_BF16)
    bf16* __restrict__ vTout,      // V^T out (used if VSPLIT)
    int M, int N, int K, int NT)
{
    __shared__ __align__(16) bf16 Asm[2][128 * 64];   // 32 KB dbuf
    __shared__ __align__(16) bf16 Bsm[2][128 * 64];   // 32 KB dbuf
    const int id = blockIdx.x;
    const int xcd = id & 7, q = id >> 3;
    const int m0 = ((q / NT) * 8 + xcd) * 128, n0 = (q % NT) * 128;
    const int tid = threadIdx.x;
    const int wave = tid >> 6, lane = tid & 63;
    const int quad = lane >> 4, l16 = lane & 15;
    const int wm = (wave >> 1) * 32, wn = (wave & 1) * 64;
    const int srow = lane >> 3;                    // 0..7
    const int scol = ((lane & 7) ^ srow) * 8;      // swizzled source k-chunk

    f32x4 acc[2][4];
    #pragma unroll
    for (int i = 0; i < 2; ++i)
        #pragma unroll
        for (int j = 0; j < 4; ++j)
            acc[i][j] = (f32x4){0.f, 0.f, 0.f, 0.f};

    // prologue: stage K-tile 0 into buffer 0 (8 waves x 2 bands each)
    #pragma unroll
    for (int i = 0; i < 2; ++i) {
        int rband = wave * 16 + i * 8;                       // wave-uniform
        GL2LDS16(A  + (size_t)(m0 + rband + srow) * K + scol, &Asm[0][rband * 64]);
        GL2LDS16(Bt + (size_t)(n0 + rband + srow) * K + scol, &Bsm[0][rband * 64]);
    }

    const int nk = K >> 6;
    for (int kt = 0; kt < nk; ++kt) {
        const int cur = kt & 1;
        if (kt + 1 < nk) {
            const int k0 = (kt + 1) << 6;
            #pragma unroll
            for (int i = 0; i < 2; ++i) {
                int rband = wave * 16 + i * 8;
                GL2LDS16(A  + (size_t)(m0 + rband + srow) * K + k0 + scol,
                         &Asm[cur ^ 1][rband * 64]);
                GL2LDS16(Bt + (size_t)(n0 + rband + srow) * K + k0 + scol,
                         &Bsm[cur ^ 1][rband * 64]);
            }
            asm volatile("s_waitcnt vmcnt(4)" ::: "memory");
        } else {
            asm volatile("s_waitcnt vmcnt(0)" ::: "memory");
        }
        __builtin_amdgcn_s_barrier();            // tile kt ready for all waves
        __builtin_amdgcn_sched_barrier(0);

        #pragma unroll
        for (int ks = 0; ks < 2; ++ks) {
            const int phys = ((ks * 4 + quad) ^ (l16 & 7)) * 8;  // de-swizzle
            bf16x8 af[2], bfr[4];
            #pragma unroll
            for (int i = 0; i < 2; ++i)
                af[i] = *(const bf16x8*)&Asm[cur][(wm + i * 16 + l16) * 64 + phys];
            #pragma unroll
            for (int j = 0; j < 4; ++j)
                bfr[j] = *(const bf16x8*)&Bsm[cur][(wn + j * 16 + l16) * 64 + phys];
            #pragma unroll
            for (int i = 0; i < 2; ++i)
                #pragma unroll
                for (int j = 0; j < 4; ++j)
                    acc[i][j] = __builtin_amdgcn_mfma_f32_16x16x32_bf16(
                        bfr[j], af[i], acc[i][j], 0, 0, 0);
        }
        __builtin_amdgcn_s_barrier();
    }

    #pragma unroll
    for (int i = 0; i < 2; ++i) {
        const int m = m0 + wm + i * 16 + l16;
        #pragma unroll
        for (int j = 0; j < 4; ++j) {
            const int nb = n0 + wn + j * 16 + quad * 4;
            f32x4 v = acc[i][j];
            if (bias) {
                float4 b4 = *(const float4*)(bias + nb);
                v[0] += b4.x; v[1] += b4.y; v[2] += b4.z; v[3] += b4.w;
            }
            if (GELU) {
                #pragma unroll
                for (int r = 0; r < 4; ++r) v[r] = gelu_f(v[r]);
            }
            if (res) {
                float4 r4 = *(const float4*)(res + (size_t)m * N + nb);
                v[0] += r4.x; v[1] += r4.y; v[2] += r4.z; v[3] += r4.w;
            }
            if (VSPLIT && nb < Cc) {
                #pragma unroll
                for (int r = 0; r < 4; ++r) v[r] *= QSCALE_LOG2E;
            }
            if (VSPLIT && nb >= 2 * Cc) {
                int hv = (nb - 2 * Cc) >> 5, dv = (nb - 2 * Cc) & 31;
                int bq = m >> 10, t = m & 1023;
                bf16* vp = vTout + ((size_t)(bq * Hc + hv) * Dc + dv) * Tc + t;
                #pragma unroll
                for (int r = 0; r < 4; ++r)
                    vp[(size_t)r * Tc] = __float2bfloat16(v[r]);
            } else if (OUT_BF16) {
                union { bf16 h[4]; uint2 u; } p;
                #pragma unroll
                for (int r = 0; r < 4; ++r) p.h[r] = __float2bfloat16(v[r]);
                *(uint2*)(Cb + (size_t)m * N + nb) = p.u;
            } else {
                *(float4*)(Cf + (size_t)m * N + nb) = (float4){v[0], v[1], v[2], v[3]};
            }
        }
    }
}

// --------------------------------------------- MFMA GEMM + residual + LN
// 512 threads / 8 waves (4m x 2n). K-tiles double-buffered, counted vmcnt(6).
__global__ __launch_bounds__(512) void mfma_gemm_ln_kernel(
    const bf16* __restrict__ A,    // [M][K]
    const bf16* __restrict__ Bt,   // [256][K]
    const float* __restrict__ bias,
    const float* __restrict__ res, // fp32 [M][256]
    const float* __restrict__ g, const float* __restrict__ b,
    float* __restrict__ xout, bf16* __restrict__ hbout, int K)
{
    __shared__ __align__(16) bf16 Asm[2][128 * 64];   // 32 KB dbuf
    __shared__ __align__(16) bf16 Bsm[2][256 * 64];   // 64 KB dbuf
    __shared__ float red[128][2][2];                  // 2 KB
    const int m0 = blockIdx.x * 128;
    const int tid = threadIdx.x;
    const int wave = tid >> 6, lane = tid & 63;
    const int quad = lane >> 4, l16 = lane & 15;
    const int wm = (wave >> 1) * 32, wn = (wave & 1) * 128;
    const int wnIdx = wave & 1;
    const int srow = lane >> 3;
    const int scol = ((lane & 7) ^ srow) * 8;

    f32x4 acc[2][8];
    #pragma unroll
    for (int i = 0; i < 2; ++i)
        #pragma unroll
        for (int j = 0; j < 8; ++j)
            acc[i][j] = (f32x4){0.f, 0.f, 0.f, 0.f};

    #pragma unroll
    for (int i = 0; i < 2; ++i) {
        int rband = wave * 16 + i * 8;
        GL2LDS16(A + (size_t)(m0 + rband + srow) * K + scol, &Asm[0][rband * 64]);
    }
    #pragma unroll
    for (int i = 0; i < 4; ++i) {
        int rband = wave * 32 + i * 8;
        GL2LDS16(Bt + (size_t)(rband + srow) * K + scol, &Bsm[0][rband * 64]);
    }

    const int nk = K >> 6;
    for (int kt = 0; kt < nk; ++kt) {
        const int cur = kt & 1;
        if (kt + 1 < nk) {
            const int k0 = (kt + 1) << 6;
            #pragma unroll
            for (int i = 0; i < 2; ++i) {
                int rband = wave * 16 + i * 8;
                GL2LDS16(A + (size_t)(m0 + rband + srow) * K + k0 + scol,
                         &Asm[cur ^ 1][rband * 64]);
            }
            #pragma unroll
            for (int i = 0; i < 4; ++i) {
                int rband = wave * 32 + i * 8;
                GL2LDS16(Bt + (size_t)(rband + srow) * K + k0 + scol,
                         &Bsm[cur ^ 1][rband * 64]);
            }
            asm volatile("s_waitcnt vmcnt(6)" ::: "memory");
        } else {
            asm volatile("s_waitcnt vmcnt(0)" ::: "memory");
        }
        __builtin_amdgcn_s_barrier();
        __builtin_amdgcn_sched_barrier(0);

        #pragma unroll
        for (int ks = 0; ks < 2; ++ks) {
            const int phys = ((ks * 4 + quad) ^ (l16 & 7)) * 8;
            bf16x8 af[2], bfr[8];
            #pragma unroll
            for (int i = 0; i < 2; ++i)
                af[i] = *(const bf16x8*)&Asm[cur][(wm + i * 16 + l16) * 64 + phys];
            #pragma unroll
            for (int j = 0; j < 8; ++j)
                bfr[j] = *(const bf16x8*)&Bsm[cur][(wn + j * 16 + l16) * 64 + phys];
            #pragma unroll
            for (int i = 0; i < 2; ++i)
                #pragma unroll
                for (int j = 0; j < 8; ++j)
                    acc[i][j] = __builtin_amdgcn_mfma_f32_16x16x32_bf16(
                        bfr[j], af[i], acc[i][j], 0, 0, 0);
        }
        __builtin_amdgcn_s_barrier();
    }

    #pragma unroll
    for (int i = 0; i < 2; ++i) {
        const int rl = wm + i * 16 + l16;
        const int m = m0 + rl;
        float s = 0.f, s2 = 0.f;
        #pragma unroll
        for (int j = 0; j < 8; ++j) {
            const int nb = wn + j * 16 + quad * 4;
            float4 b4 = *(const float4*)(bias + nb);
            float4 r4 = *(const float4*)(res + (size_t)m * Cc + nb);
            acc[i][j][0] += b4.x + r4.x; acc[i][j][1] += b4.y + r4.y;
            acc[i][j][2] += b4.z + r4.z; acc[i][j][3] += b4.w + r4.w;
            #pragma unroll
            for (int r = 0; r < 4; ++r) {
                s += acc[i][j][r];
                s2 += acc[i][j][r] * acc[i][j][r];
            }
        }
        s  += __shfl_xor(s, 16);  s  += __shfl_xor(s, 32);
        s2 += __shfl_xor(s2, 16); s2 += __shfl_xor(s2, 32);
        if (quad == 0) { red[rl][wnIdx][0] = s; red[rl][wnIdx][1] = s2; }
    }
    __syncthreads();

    #pragma unroll
    for (int i = 0; i < 2; ++i) {
        const int rl = wm + i * 16 + l16;
        const int m = m0 + rl;
        float s  = red[rl][0][0] + red[rl][1][0];
        float s2 = red[rl][0][1] + red[rl][1][1];
        float mean = s * (1.0f / Cc);
        float rstd = rsqrtf(s2 * (1.0f / Cc) - mean * mean + EPSc);
        #pragma unroll
        for (int j = 0; j < 8; ++j) {
            const int nb = wn + j * 16 + quad * 4;
            f32x4 v = acc[i][j];
            *(float4*)(xout + (size_t)m * Cc + nb) = (float4){v[0], v[1], v[2], v[3]};
            float4 g4 = *(const float4*)(g + nb);
            float4 bb4 = *(const float4*)(b + nb);
            union { bf16 h[4]; uint2 u; } p;
            p.h[0] = __float2bfloat16((v[0] - mean) * rstd * g4.x + bb4.x);
            p.h[1] = __float2bfloat16((v[1] - mean) * rstd * g4.y + bb4.y);
            p.h[2] = __float2bfloat16((v[2] - mean) * rstd * g4.z + bb4.z);
            p.h[3] = __float2bfloat16((v[3] - mean) * rstd * g4.w + bb4.w);
            *(uint2*)(hbout + (size_t)m * Cc + nb) = p.u;
        }
    }
}

// ------------------------------------------- fused MLP: gelu(hb@Wf+b1)@Wp
//                                             + b2 + residual + LN
// Attention-structure port (R7 k-chunk fix). Wp pre-permuted in global
// (castT_kernel<true>) so GEMM2 B-fragments are contiguous ds_read_b128.
// 512-thread / 8-wave version — verified passing 3x at ~80 us; the 16-wave
// variant (R15) NaN'd and is retired.
__global__ __launch_bounds__(512) void fused_ff_ln_kernel(
    const bf16* __restrict__ A,     // hb [M][256]
    const bf16* __restrict__ Wf,    // WfT [1024 f][256 c]
    const float* __restrict__ b1,   // [1024]
    const bf16* __restrict__ Wp,    // wpT [256 outc][1024 f], f pi-permuted
    const float* __restrict__ b2,   // [256]
    const float* __restrict__ g, const float* __restrict__ bb,
    float* __restrict__ x,          // residual in / out, fp32 [M][256]
    bf16* __restrict__ hbout)       // LN output [M][256]
{
    // 2 bufs x (Wf slice 64x256 + Wp slice 256x64) = 2 x 32768 elems = 128 KB
    __shared__ __align__(16) bf16 lds[2 * 32768];
    const int m0 = blockIdx.x * 128;
    const int tid = threadIdx.x;
    const int wave = tid >> 6, lane = tid & 63;
    const int quad = lane >> 4, l16 = lane & 15;

    // ---- prologue: stage hb tile [128][256] into lds[0..32768)
    #pragma unroll
    for (int it = 0; it < 8; ++it) {
        const int row = wave * 16 + it * 2 + (lane >> 5);
        const int clog = (lane & 31) ^ (row & 7);
        GL2LDS16(A + (size_t)(m0 + row) * Cc + clog * 8,
                 &lds[(wave * 16 + it * 2) * Cc]);
    }
    __syncthreads();
    // extract this wave's 16 rows as B-operand frags: for mfma kk, lane
    // (quad,l16) supplies hb[row = wave*16+l16][c = (kk*4+quad)*8 + e]
    bf16x8 ahb[8];
    #pragma unroll
    for (int kk = 0; kk < 8; ++kk)
        ahb[kk] = *(const bf16x8*)&lds[(wave * 16 + l16) * Cc
                                       + (((kk * 4 + quad) ^ (l16 & 7)) * 8)];
    asm volatile("s_waitcnt lgkmcnt(0)" ::: "memory");
    __builtin_amdgcn_sched_barrier(0);
    __builtin_amdgcn_s_barrier();   // all reads done before staging overwrites

    // stage one f-slice (Wf rows f0..f0+63 x 256c; Wp rows 0..255 x 64f)
    #define FF_STAGE(buf, sl) do {                                             \
        const int f0s = (sl) * 64;                                             \
        _Pragma("unroll")                                                      \
        for (int it = 0; it < 4; ++it) {                                       \
            const int row = it * 16 + wave * 2 + (lane >> 5);                  \
            const int clog = (lane & 31) ^ (row & 7);                          \
            GL2LDS16(Wf + (size_t)(f0s + row) * Cc + clog * 8,                 \
                     &lds[(buf) * 32768 + (it * 16 + wave * 2) * Cc]);         \
        }                                                                      \
        _Pragma("unroll")                                                      \
        for (int it = 0; it < 4; ++it) {                                       \
            const int row = it * 64 + wave * 8 + (lane >> 3);                  \
            const int clog = (lane & 7) ^ (row & 7);                           \
            GL2LDS16(Wp + (size_t)row * FFc + f0s + clog * 8,                  \
                     &lds[(buf) * 32768 + 16384 + (it * 64 + wave * 8) * 64]); \
        }                                                                      \
    } while (0)

    FF_STAGE(0, 0);

    f32x4 o[16];
    #pragma unroll
    for (int nt = 0; nt < 16; ++nt) o[nt] = (f32x4){0.f, 0.f, 0.f, 0.f};

    for (int kt = 0; kt < 16; ++kt) {
        const int cur = kt & 1;
        if (kt < 15) {
            FF_STAGE(cur ^ 1, kt + 1);
            asm volatile("s_waitcnt vmcnt(8)" ::: "memory");
        } else {
            asm volatile("s_waitcnt vmcnt(0)" ::: "memory");
        }
        __builtin_amdgcn_s_barrier();
        __builtin_amdgcn_sched_barrier(0);

        const bf16* Wfb = &lds[cur * 32768];
        const bf16* Wpb = &lds[cur * 32768 + 16384];

        // GEMM1 (swapped): sj[j] holds S[f=kt*64+j*16+quad*4+r][m=wave*16+l16]
        // mfma kk covers c-chunks kk*4..kk*4+3; lane supplies chunk kk*4+quad.
        f32x4 sj[4];
        #pragma unroll
        for (int j = 0; j < 4; ++j) sj[j] = (f32x4){0.f, 0.f, 0.f, 0.f};
        #pragma unroll
        for (int kk = 0; kk < 8; ++kk) {
            const int ph = ((kk * 4 + quad) ^ (l16 & 7)) * 8;
            #pragma unroll
            for (int j = 0; j < 4; ++j) {
                bf16x8 wfr = *(const bf16x8*)&Wfb[(j * 16 + l16) * Cc + ph];
                sj[j] = __builtin_amdgcn_mfma_f32_16x16x32_bf16(
                    wfr, ahb[kk], sj[j], 0, 0, 0);
            }
        }

        // bias1 + gelu
        float p[4][4];
        #pragma unroll
        for (int j = 0; j < 4; ++j) {
            float4 b4 = *(const float4*)(b1 + kt * 64 + j * 16 + quad * 4);
            p[j][0] = gelu_f(sj[j][0] + b4.x);
            p[j][1] = gelu_f(sj[j][1] + b4.y);
            p[j][2] = gelu_f(sj[j][2] + b4.z);
            p[j][3] = gelu_f(sj[j][3] + b4.w);
        }

        // pi-order PV A-frags: lane's own values, no shuffles
        U32x4 pa0, pa1;
        asm("v_cvt_pk_bf16_f32 %0, %1, %2" : "=v"(pa0.q[0]) : "v"(p[0][0]), "v"(p[0][1]));
        asm("v_cvt_pk_bf16_f32 %0, %1, %2" : "=v"(pa0.q[1]) : "v"(p[0][2]), "v"(p[0][3]));
        asm("v_cvt_pk_bf16_f32 %0, %1, %2" : "=v"(pa0.q[2]) : "v"(p[1][0]), "v"(p[1][1]));
        asm("v_cvt_pk_bf16_f32 %0, %1, %2" : "=v"(pa0.q[3]) : "v"(p[1][2]), "v"(p[1][3]));
        asm("v_cvt_pk_bf16_f32 %0, %1, %2" : "=v"(pa1.q[0]) : "v"(p[2][0]), "v"(p[2][1]));
        asm("v_cvt_pk_bf16_f32 %0, %1, %2" : "=v"(pa1.q[1]) : "v"(p[2][2]), "v"(p[2][3]));
        asm("v_cvt_pk_bf16_f32 %0, %1, %2" : "=v"(pa1.q[2]) : "v"(p[3][0]), "v"(p[3][1]));
        asm("v_cvt_pk_bf16_f32 %0, %1, %2" : "=v"(pa1.q[3]) : "v"(p[3][2]), "v"(p[3][3]));

        // GEMM2: o[nt] += P @ Wp-slice. Wp pre-permuted: frag g is one
        // contiguous b128 at chunk (g*4+quad), staged-XOR de-swizzled.
        #pragma unroll
        for (int nt = 0; nt < 16; ++nt) {
            const int d = nt * 16 + l16;
            bf16x8 w0 = *(const bf16x8*)&Wpb[d * 64 + (((0 + quad) ^ (l16 & 7)) * 8)];
            bf16x8 w1 = *(const bf16x8*)&Wpb[d * 64 + (((4 + quad) ^ (l16 & 7)) * 8)];
            o[nt] = __builtin_amdgcn_mfma_f32_16x16x32_bf16(pa0.v, w0, o[nt], 0, 0, 0);
            o[nt] = __builtin_amdgcn_mfma_f32_16x16x32_bf16(pa1.v, w1, o[nt], 0, 0, 0);
        }
        __builtin_amdgcn_s_barrier();   // buf cur reads done before overwrite
    }
    #undef FF_STAGE

    // ---- epilogue: bias2 + residual; LN stats per row (pure shfl: each
    // quad owns distinct rows, reduce across the 16 l16 lanes only)
    const int row0 = m0 + wave * 16 + quad * 4;
    float s[4] = {0.f, 0.f, 0.f, 0.f}, s2[4] = {0.f, 0.f, 0.f, 0.f};
    #pragma unroll
    for (int nt = 0; nt < 16; ++nt) {
        const int col = nt * 16 + l16;
        const float bpv = b2[col];
        #pragma unroll
        for (int r = 0; r < 4; ++r) {
            float v = o[nt][r] + bpv + x[(size_t)(row0 + r) * Cc + col];
            o[nt][r] = v;
            s[r] += v; s2[r] += v * v;
        }
    }
    #pragma unroll
    for (int r = 0; r < 4; ++r) {
        #pragma unroll
        for (int off = 1; off < 16; off <<= 1) {
            s[r]  += __shfl_xor(s[r], off);
            s2[r] += __shfl_xor(s2[r], off);
        }
    }
    float mean[4], rstd[4];
    #pragma unroll
    for (int r = 0; r < 4; ++r) {
        mean[r] = s[r] * (1.0f / Cc);
        rstd[r] = rsqrtf(s2[r] * (1.0f / Cc) - mean[r] * mean[r] + EPSc);
    }
    #pragma unroll
    for (int nt = 0; nt < 16; ++nt) {
        const int col = nt * 16 + l16;
        const float gv = g[col], bv = bb[col];
        #pragma unroll
        for (int r = 0; r < 4; ++r) {
            x[(size_t)(row0 + r) * Cc + col] = o[nt][r];
            hbout[(size_t)(row0 + r) * Cc + col] =
                __float2bfloat16((o[nt][r] - mean[r]) * rstd[r] * gv + bv);
        }
    }
}

// ---------------------------------------------------------------- attention
// MFMA flash attention, PAIRED q-tiles {pi, 7-pi} (R12-verified pairing).
// K/V triple-buffered, prefetch 2 tiles ahead, counted vmcnt (R13).
// SWAPPED QK^T + pi key-permutation: P never touches LDS.
__global__ __launch_bounds__(256) void attn_mfma_kernel(
    const bf16* __restrict__ qkv, const bf16* __restrict__ vT,
    bf16* __restrict__ y)
{
    const int id = blockIdx.x;              // 1024 = 32 g * 4 pair * 8 xcd
    const int xcd = id & 7;
    const int pi  = (id >> 3) & 3;          // pair 0 (heaviest) first
    const int bh  = ((id >> 5) << 3) + xcd;
    const int qa = pi, qb = 7 - pi;         // 128-row q-tile indices
    const int b = bh >> 3, h = bh & 7;
    const int tid = threadIdx.x;
    const int wave = tid >> 6, lane = tid & 63;
    const int quad = lane >> 4, l16 = lane & 15;

    __shared__ __align__(16) bf16 Ks[3][64 * 32];    // 12 KB, 3-buf, swizzled
    __shared__ __align__(16) bf16 Vs[3][32 * 64];    // 12 KB, 3-buf, swizzled
    __shared__ __align__(16) bf16 Qs[256 * 32];      // 16 KB Q staging

    const size_t rstride = 3 * Cc;
    const bf16* base  = qkv + (size_t)(b * Tc) * rstride + h * Dc;
    const bf16* vbase = vT + (size_t)bh * Dc * Tc;

    const int srow4  = lane >> 2;
    const int schunk = ((lane & 3) ^ ((lane >> 3) & 3)) * 8;
    const int vchunk = ((lane & 7) ^ (lane >> 3)) * 8;

    #pragma unroll
    for (int u = 0; u < 4; ++u) {
        const int qt = (u >> 1) ? qb : qa;
        const bf16* gq = base
            + (size_t)(qt * 128 + (u & 1) * 64 + wave * 16 + srow4) * rstride + schunk;
        GL2LDS16(gq, &Qs[(u * 64 + wave * 16) * 32]);
    }
    // prologue: stage K/V tiles 0 and 1 (ktmax >= 9 so tile 1 exists)
    #pragma unroll
    for (int t0 = 0; t0 < 2; ++t0) {
        const bf16* gk = base
            + (size_t)(t0 * 64 + wave * 16 + srow4) * rstride + 256 + schunk;
        GL2LDS16(gk, &Ks[t0][(wave * 16) * 32]);
        const bf16* gv = vbase + (size_t)(wave * 8 + (lane >> 3)) * Tc + t0 * 64 + vchunk;
        GL2LDS16(gv, &Vs[t0][(wave * 8) * 64]);
    }
    __syncthreads();
    const int qkphys = (quad ^ ((l16 >> 1) & 3)) * 8;
    bf16x8 afq[4];
    #pragma unroll
    for (int u = 0; u < 4; ++u)
        afq[u] = *(const bf16x8*)&Qs[(u * 64 + wave * 16 + l16) * 32 + qkphys];

    float l_acc[4] = {};
    f32x4 o[4][2];
    #pragma unroll
    for (int u = 0; u < 4; ++u)
        #pragma unroll
        for (int nt = 0; nt < 2; ++nt)
            o[u][nt] = (f32x4){0.f, 0.f, 0.f, 0.f};

    const int rloc = wave * 16 + quad * 4;     // output q rows (epilogue)
    const int qloc = wave * 16 + l16;          // this lane's P column (q row)
    const int vsw = l16 & 7;
    const int vq  = (quad >> 1);
    const int vo  = (quad & 1) * 4;

    const int ktmax = 2 * qb + 1;
    for (int kt = 0; kt <= ktmax; ++kt) {
        const int cur = kt % 3;

        if (kt + 2 <= ktmax) {
            const int nxt = (kt + 2) % 3;
            const bf16* gk = base
                + (size_t)((kt + 2) * 64 + wave * 16 + srow4) * rstride + 256 + schunk;
            GL2LDS16(gk, &Ks[nxt][(wave * 16) * 32]);
            const bf16* gv = vbase
                + (size_t)(wave * 8 + (lane >> 3)) * Tc + (kt + 2) * 64 + vchunk;
            GL2LDS16(gv, &Vs[nxt][(wave * 8) * 64]);
            asm volatile("s_waitcnt vmcnt(4)" ::: "memory");
        } else if (kt + 1 <= ktmax) {
            asm volatile("s_waitcnt vmcnt(2)" ::: "memory");
        } else {
            asm volatile("s_waitcnt vmcnt(0)" ::: "memory");
        }
        __builtin_amdgcn_s_barrier();            // tile kt ready for all waves
        __builtin_amdgcn_sched_barrier(0);

        bf16x8 bk[4];
        #pragma unroll
        for (int j = 0; j < 4; ++j)
            bk[j] = *(const bf16x8*)&Ks[cur][(j * 16 + l16) * 32 + qkphys];

        U32x4 bvx[2][2];
        #pragma unroll
        for (int g = 0; g < 2; ++g)
            #pragma unroll
            for (int nt = 0; nt < 2; ++nt) {
                const int d = nt * 16 + l16;
                uint2 lo = *(const uint2*)&Vs[cur][d * 64 + (((4 * g + 0 + vq) ^ vsw) * 8 + vo)];
                uint2 hi = *(const uint2*)&Vs[cur][d * 64 + (((4 * g + 2 + vq) ^ vsw) * 8 + vo)];
                bvx[g][nt].q[0] = lo.x; bvx[g][nt].q[1] = lo.y;
                bvx[g][nt].q[2] = hi.x; bvx[g][nt].q[3] = hi.y;
            }

        #pragma unroll
        for (int t = 1; t >= 0; --t) {
            const int qt = t ? qb : qa;
            if (kt > 2 * qt + 1) continue;      // whole tile done (uniform)

            #pragma unroll
            for (int s = 0; s < 2; ++s) {
                const int u = t * 2 + s;
                if (kt > 2 * qt + s) continue;  // subtile masked (uniform)

                f32x4 sj[4];
                #pragma unroll
                for (int j = 0; j < 4; ++j)
                    sj[j] = __builtin_amdgcn_mfma_f32_16x16x32_bf16(
                        bk[j], afq[u], (f32x4){0.f,0.f,0.f,0.f}, 0, 0, 0);
                if (kt == 2 * qt + s) {         // diagonal: causal mask
                    #pragma unroll
                    for (int j = 0; j < 4; ++j)
                        #pragma unroll
                        for (int r = 0; r < 4; ++r)
                            if (j * 16 + quad * 4 + r > qloc) sj[j][r] = -INFINITY;
                }

                float p[4][4];
                float ls = 0.f;
                #pragma unroll
                for (int j = 0; j < 4; ++j) {
                    #pragma unroll
                    for (int r = 0; r < 4; ++r) {
                        p[j][r] = __builtin_amdgcn_exp2f(sj[j][r]);
                    }
                    ls += (p[j][0] + p[j][1]) + (p[j][2] + p[j][3]);
                }
                l_acc[u] += ls;

                U32x4 pa0, pa1;
                asm("v_cvt_pk_bf16_f32 %0, %1, %2" : "=v"(pa0.q[0]) : "v"(p[0][0]), "v"(p[0][1]));
                asm("v_cvt_pk_bf16_f32 %0, %1, %2" : "=v"(pa0.q[1]) : "v"(p[0][2]), "v"(p[0][3]));
                asm("v_cvt_pk_bf16_f32 %0, %1, %2" : "=v"(pa0.q[2]) : "v"(p[1][0]), "v"(p[1][1]));
                asm("v_cvt_pk_bf16_f32 %0, %1, %2" : "=v"(pa0.q[3]) : "v"(p[1][2]), "v"(p[1][3]));
                asm("v_cvt_pk_bf16_f32 %0, %1, %2" : "=v"(pa1.q[0]) : "v"(p[2][0]), "v"(p[2][1]));
                asm("v_cvt_pk_bf16_f32 %0, %1, %2" : "=v"(pa1.q[1]) : "v"(p[2][2]), "v"(p[2][3]));
                asm("v_cvt_pk_bf16_f32 %0, %1, %2" : "=v"(pa1.q[2]) : "v"(p[3][0]), "v"(p[3][1]));
                asm("v_cvt_pk_bf16_f32 %0, %1, %2" : "=v"(pa1.q[3]) : "v"(p[3][2]), "v"(p[3][3]));

                o[u][0] = __builtin_amdgcn_mfma_f32_16x16x32_bf16(pa0.v, bvx[0][0].v, o[u][0], 0, 0, 0);
                o[u][0] = __builtin_amdgcn_mfma_f32_16x16x32_bf16(pa1.v, bvx[1][0].v, o[u][0], 0, 0, 0);
                o[u][1] = __builtin_amdgcn_mfma_f32_16x16x32_bf16(pa0.v, bvx[0][1].v, o[u][1], 0, 0, 0);
                o[u][1] = __builtin_amdgcn_mfma_f32_16x16x32_bf16(pa1.v, bvx[1][1].v, o[u][1], 0, 0, 0);
            }
        }

        __builtin_amdgcn_s_barrier();
    }

    #pragma unroll
    for (int u = 0; u < 4; ++u) {
        const int qt = (u >> 1) ? qb : qa;
        float l = l_acc[u];
        l += __shfl_xor(l, 16);
        l += __shfl_xor(l, 32);
        float linv[4];
        #pragma unroll
        for (int r = 0; r < 4; ++r)
            linv[r] = 1.0f / __shfl(l, quad * 20 + r);
        #pragma unroll
        for (int nt = 0; nt < 2; ++nt)
            #pragma unroll
            for (int r = 0; r < 4; ++r)
                y[(size_t)(b * Tc + qt * 128 + (u & 1) * 64 + rloc + r) * Cc
                  + h * Dc + nt * 16 + l16]
                    = __float2bfloat16(o[u][nt][r] * linv[r]);
    }
}

// ---------------------------------------------------------------- launch
extern "C" void kernel_launch(void* const* d_in, const int* in_sizes, int n_in,
                              void* d_out, int out_size, void* d_ws, size_t ws_size,
                              hipStream_t stream)
{
    const int*   idx     = (const int*)  d_in[0];
    const float* tok_emb = (const float*)d_in[1];
    const float* pos_emb = (const float*)d_in[2];
    const float* ln1_g   = (const float*)d_in[3];
    const float* ln1_b   = (const float*)d_in[4];
    const float* wqkv    = (const float*)d_in[5];
    const float* bqkv    = (const float*)d_in[6];
    const float* wo      = (const float*)d_in[7];
    const float* bo      = (const float*)d_in[8];
    const float* ln2_g   = (const float*)d_in[9];
    const float* ln2_b   = (const float*)d_in[10];
    const float* wfc     = (const float*)d_in[11];
    const float* bfc     = (const float*)d_in[12];
    const float* wpr     = (const float*)d_in[13];
    const float* bpr     = (const float*)d_in[14];
    const float* lnf_g   = (const float*)d_in[15];
    const float* lnf_b   = (const float*)d_in[16];
    const float* w_lm    = (const float*)d_in[17];
    float* out = (float*)d_out;

    float* ws = (float*)d_ws;
    float* x  = ws;                                        // Mc*Cc fp32
    bf16* hb  = (bf16*)(x + (size_t)Mc * Cc);              // Mc*Cc bf16
    bf16* yb  = hb + (size_t)Mc * Cc;                      // Mc*Cc bf16
    float* big = (float*)(yb + (size_t)Mc * Cc);           // scratch region
    bf16* bigb = (bf16*)big;                               // qkv bf16
    bf16* wqT = (bf16*)(big + (size_t)Mc * 3 * Cc);        // [L][3C][C]
    bf16* woT = wqT + (size_t)Lc * 3 * Cc * Cc;            // [L][C][C]
    bf16* wfT = woT + (size_t)Lc * Cc * Cc;                // [L][FF][C]
    bf16* wpT = wfT + (size_t)Lc * Cc * FFc;               // [L][C][FF] (f permuted)
    bf16* wlT = wpT + (size_t)Lc * FFc * Cc;               // [V][C]
    bf16* vT  = wlT + (size_t)Vc * Cc;                     // [B][H][D][T]

    dim3 blk(256);
    dim3 blkG(512);

    castT_kernel<false><<<dim3(3 * Cc / 32, Cc / 32, Lc), blk, 0, stream>>>(wqkv, wqT, Cc, 3 * Cc);
    castT_kernel<false><<<dim3(Cc / 32, Cc / 32, Lc),     blk, 0, stream>>>(wo,   woT, Cc, Cc);
    castT_kernel<false><<<dim3(FFc / 32, Cc / 32, Lc),    blk, 0, stream>>>(wfc,  wfT, Cc, FFc);
    castT_kernel<true><<<dim3(Cc / 32, FFc / 32, Lc),     blk, 0, stream>>>(wpr,  wpT, FFc, Cc);
    castT_kernel<false><<<dim3(Vc / 32, Cc / 32, 1),      blk, 0, stream>>>(w_lm, wlT, Cc, Vc);

    embed_ln_kernel<<<dim3(Mc), blk, 0, stream>>>(idx, tok_emb, pos_emb,
                                                  ln1_g, ln1_b, x, hb);

    for (int l = 0; l < Lc; ++l) {
        const bf16* WqT = wqT + (size_t)l * 3 * Cc * Cc;
        const bf16* WoT = woT + (size_t)l * Cc * Cc;
        const bf16* WfT = wfT + (size_t)l * Cc * FFc;
        const bf16* WpT = wpT + (size_t)l * FFc * Cc;
        const float* bq = bqkv + (size_t)l * 3 * Cc;
        const float* bo_ = bo  + (size_t)l * Cc;
        const float* bf_ = bfc + (size_t)l * FFc;
        const float* bp = bpr  + (size_t)l * Cc;
        const float* gn = (l < Lc - 1) ? ln1_g + (size_t)(l + 1) * Cc : lnf_g;
        const float* bn = (l < Lc - 1) ? ln1_b + (size_t)(l + 1) * Cc : lnf_b;

        // qkv: q,k -> bigb [M,3C]; v -> vT[B][H][D][T]   (NT=6, XCD-swizzled)
        mfma_gemm_kernel<false, true, true><<<dim3(Mc / 128 * 6), blkG, 0, stream>>>(
            hb, WqT, bq, nullptr, nullptr, bigb, vT, Mc, 3 * Cc, Cc, 6);
        attn_mfma_kernel<<<dim3(1024), blk, 0, stream>>>(bigb, vT, yb);
        // x = x + yb @ Wo + bo;  hb = LN2(x)
        mfma_gemm_ln_kernel<<<dim3(Mc / 128), blkG, 0, stream>>>(
            yb, WoT, bo_, x, ln2_g + (size_t)l * Cc, ln2_b + (size_t)l * Cc,
            x, hb, Cc);
        // fused MLP: x = x + gelu(hb@Wf+bf)@Wp + bp;  hb = LN_next(x)
        fused_ff_ln_kernel<<<dim3(Mc / 128), blkG, 0, stream>>>(
            hb, WfT, bf_, WpT, bp, gn, bn, x, hb);
    }

    // logits = hb @ w_lm   (NT=1)
    mfma_gemm_kernel<false, false, false><<<dim3(Mc / 128), blkG, 0, stream>>>(
        hb, wlT, nullptr, nullptr, out, nullptr, nullptr, Mc, Vc, Cc, 1);
}

// Round 17
// 1484.545 us; speedup vs baseline: 1.0844x; 1.0218x over previous
//
#include <hip/hip_runtime.h>
#include <hip/hip_bf16.h>
#include <cstddef>

// GPT-small: L=8 H=8 C=256 V=128 T=1024 B=32, D=32, FF=1024
static constexpr int Lc = 8, Hc = 8, Cc = 256, Vc = 128, Tc = 1024, Bc = 32;
static constexpr int Dc = Cc / Hc;       // 32
static constexpr int FFc = 4 * Cc;       // 1024
static constexpr int Mc = Bc * Tc;       // 32768 tokens
static constexpr float EPSc = 1e-5f;
// softmax scale (1/sqrt(32)) folded together with log2(e) into Q at the
// qkv-GEMM epilogue, so attention can use a bare v_exp_f32 (exp2).
static constexpr float QSCALE_LOG2E = 0.25503486f;  // 0.176776695 * 1.44269504

typedef __bf16 bf16x8 __attribute__((ext_vector_type(8)));
typedef float f32x4 __attribute__((ext_vector_type(4)));
typedef __hip_bfloat16 bf16;

union U32x4 { uint32_t q[4]; bf16x8 v; };

#define GL2LDS16(g, l) __builtin_amdgcn_global_load_lds( \
    (const __attribute__((address_space(1))) void*)(g),  \
    (__attribute__((address_space(3))) void*)(l), 16, 0, 0)

// ------------------------------------------- embedding + LN1(layer0) fused
__global__ __launch_bounds__(256) void embed_ln_kernel(
    const int* __restrict__ idx, const float* __restrict__ tok,
    const float* __restrict__ pos, const float* __restrict__ g,
    const float* __restrict__ b, float* __restrict__ x, bf16* __restrict__ hb)
{
    int row = blockIdx.x;
    int tid = threadIdx.x;
    int t = row & (Tc - 1);
    int token = idx[row];
    float v = tok[(size_t)token * Cc + tid] + pos[(size_t)t * Cc + tid];
    x[(size_t)row * Cc + tid] = v;
    __shared__ float red[4];
    float s = v;
    #pragma unroll
    for (int off = 32; off; off >>= 1) s += __shfl_xor(s, off);
    int lane = tid & 63, wave = tid >> 6;
    if (lane == 0) red[wave] = s;
    __syncthreads();
    float mean = (red[0] + red[1] + red[2] + red[3]) * (1.0f / Cc);
    float dv = v - mean;
    float s2 = dv * dv;
    #pragma unroll
    for (int off = 32; off; off >>= 1) s2 += __shfl_xor(s2, off);
    __syncthreads();
    if (lane == 0) red[wave] = s2;
    __syncthreads();
    float var = (red[0] + red[1] + red[2] + red[3]) * (1.0f / Cc);
    hb[(size_t)row * Cc + tid] = __float2bfloat16(dv * rsqrtf(var + EPSc) * g[tid] + b[tid]);
}

// ------------------------------------------------- weight cast + transpose
// PERMK: permute the K (fast) axis within each 64-block by pos(f) so the
// fused MLP's GEMM2 B-fragments are contiguous 16B reads.
// pos(f) = (f&32) | (((f>>2)&3)<<3) | (((f>>4)&1)<<2) | (f&3):
// global chunk g*4+quad holds f = 32g+16jb+4quad+r in slot order jb*4+r.
// (Weights only — permuting vT's write side regressed downstream
// dispatches; R10-R12 lessons.)
template <bool PERMK>
__global__ __launch_bounds__(256) void castT_kernel(
    const float* __restrict__ W, bf16* __restrict__ Wt, int K, int N)
{
    __shared__ float tile[32][33];
    const float* Wl = W + (size_t)blockIdx.z * K * N;
    bf16* Wtl = Wt + (size_t)blockIdx.z * K * N;
    int k0 = blockIdx.y * 32, n0 = blockIdx.x * 32;
    int tid = threadIdx.x;
    for (int e = tid; e < 1024; e += 256) {
        int r = e >> 5, c = e & 31;
        tile[r][c] = Wl[(size_t)(k0 + r) * N + n0 + c];
    }
    __syncthreads();
    for (int e = tid; e < 1024; e += 256) {
        int r = e >> 5, c = e & 31;
        int kk = k0 + c;
        if (PERMK) {
            int f = kk & 63;
            kk = (kk & ~63) | (f & 32) | (((f >> 2) & 3) << 3)
                 | (((f >> 4) & 1) << 2) | (f & 3);
        }
        Wtl[(size_t)(n0 + r) * K + kk] = __float2bfloat16(tile[c][r]);
    }
}

__device__ __forceinline__ float gelu_f(float x) {
    const float k2 = 2.0f * 0.7978845608028654f;
    float u2 = k2 * (x + 0.044715f * x * x * x);
    return x / (1.0f + __expf(-u2));
}

// ---------------------------------------------------------------- MFMA GEMM
// 128x128 tile, BK=64, XOR-swizzled LDS, swapped operands, XCD-aware flat
// grid. 512 threads / 8 waves (4m x 2n, 32x64 per wave).
// K-tiles double-buffered with counted s_waitcnt vmcnt(4) + raw s_barriers.
template <bool GELU, bool OUT_BF16, bool VSPLIT>
__global__ __launch_bounds__(512) void mfma_gemm_kernel(
    const bf16* __restrict__ A,    // [M][K]
    const bf16* __restrict__ Bt,   // [N][K]
    const float* __restrict__ bias,
    const float* __restrict__ res, // fp32 [M][N] or null
    float* __restrict__ Cf,        // fp32 out (used if !OUT_BF16)
    bf16* __restrict__ Cb,         // bf16 out (used if OUT_BF16)
    bf16* __restrict__ vTout,      // V^T out (used if VSPLIT)
    int M, int N, int K, int NT)
{
    __shared__ __align__(16) bf16 Asm[2][128 * 64];   // 32 KB dbuf
    __shared__ __align__(16) bf16 Bsm[2][128 * 64];   // 32 KB dbuf
    const int id = blockIdx.x;
    const int xcd = id & 7, q = id >> 3;
    const int m0 = ((q / NT) * 8 + xcd) * 128, n0 = (q % NT) * 128;
    const int tid = threadIdx.x;
    const int wave = tid >> 6, lane = tid & 63;
    const int quad = lane >> 4, l16 = lane & 15;
    const int wm = (wave >> 1) * 32, wn = (wave & 1) * 64;
    const int srow = lane >> 3;                    // 0..7
    const int scol = ((lane & 7) ^ srow) * 8;      // swizzled source k-chunk

    f32x4 acc[2][4];
    #pragma unroll
    for (int i = 0; i < 2; ++i)
        #pragma unroll
        for (int j = 0; j < 4; ++j)
            acc[i][j] = (f32x4){0.f, 0.f, 0.f, 0.f};

    // prologue: stage K-tile 0 into buffer 0 (8 waves x 2 bands each)
    #pragma unroll
    for (int i = 0; i < 2; ++i) {
        int rband = wave * 16 + i * 8;                       // wave-uniform
        GL2LDS16(A  + (size_t)(m0 + rband + srow) * K + scol, &Asm[0][rband * 64]);
        GL2LDS16(Bt + (size_t)(n0 + rband + srow) * K + scol, &Bsm[0][rband * 64]);
    }

    const int nk = K >> 6;
    for (int kt = 0; kt < nk; ++kt) {
        const int cur = kt & 1;
        if (kt + 1 < nk) {
            const int k0 = (kt + 1) << 6;
            #pragma unroll
            for (int i = 0; i < 2; ++i) {
                int rband = wave * 16 + i * 8;
                GL2LDS16(A  + (size_t)(m0 + rband + srow) * K + k0 + scol,
                         &Asm[cur ^ 1][rband * 64]);
                GL2LDS16(Bt + (size_t)(n0 + rband + srow) * K + k0 + scol,
                         &Bsm[cur ^ 1][rband * 64]);
            }
            asm volatile("s_waitcnt vmcnt(4)" ::: "memory");
        } else {
            asm volatile("s_waitcnt vmcnt(0)" ::: "memory");
        }
        __builtin_amdgcn_s_barrier();            // tile kt ready for all waves
        __builtin_amdgcn_sched_barrier(0);

        #pragma unroll
        for (int ks = 0; ks < 2; ++ks) {
            const int phys = ((ks * 4 + quad) ^ (l16 & 7)) * 8;  // de-swizzle
            bf16x8 af[2], bfr[4];
            #pragma unroll
            for (int i = 0; i < 2; ++i)
                af[i] = *(const bf16x8*)&Asm[cur][(wm + i * 16 + l16) * 64 + phys];
            #pragma unroll
            for (int j = 0; j < 4; ++j)
                bfr[j] = *(const bf16x8*)&Bsm[cur][(wn + j * 16 + l16) * 64 + phys];
            #pragma unroll
            for (int i = 0; i < 2; ++i)
                #pragma unroll
                for (int j = 0; j < 4; ++j)
                    acc[i][j] = __builtin_amdgcn_mfma_f32_16x16x32_bf16(
                        bfr[j], af[i], acc[i][j], 0, 0, 0);
        }
        __builtin_amdgcn_s_barrier();
    }

    #pragma unroll
    for (int i = 0; i < 2; ++i) {
        const int m = m0 + wm + i * 16 + l16;
        #pragma unroll
        for (int j = 0; j < 4; ++j) {
            const int nb = n0 + wn + j * 16 + quad * 4;
            f32x4 v = acc[i][j];
            if (bias) {
                float4 b4 = *(const float4*)(bias + nb);
                v[0] += b4.x; v[1] += b4.y; v[2] += b4.z; v[3] += b4.w;
            }
            if (GELU) {
                #pragma unroll
                for (int r = 0; r < 4; ++r) v[r] = gelu_f(v[r]);
            }
            if (res) {
                float4 r4 = *(const float4*)(res + (size_t)m * N + nb);
                v[0] += r4.x; v[1] += r4.y; v[2] += r4.z; v[3] += r4.w;
            }
            if (VSPLIT && nb < Cc) {
                #pragma unroll
                for (int r = 0; r < 4; ++r) v[r] *= QSCALE_LOG2E;
            }
            if (VSPLIT && nb >= 2 * Cc) {
                int hv = (nb - 2 * Cc) >> 5, dv = (nb - 2 * Cc) & 31;
                int bq = m >> 10, t = m & 1023;
                bf16* vp = vTout + ((size_t)(bq * Hc + hv) * Dc + dv) * Tc + t;
                #pragma unroll
                for (int r = 0; r < 4; ++r)
                    vp[(size_t)r * Tc] = __float2bfloat16(v[r]);
            } else if (OUT_BF16) {
                union { bf16 h[4]; uint2 u; } p;
                #pragma unroll
                for (int r = 0; r < 4; ++r) p.h[r] = __float2bfloat16(v[r]);
                *(uint2*)(Cb + (size_t)m * N + nb) = p.u;
            } else {
                *(float4*)(Cf + (size_t)m * N + nb) = (float4){v[0], v[1], v[2], v[3]};
            }
        }
    }
}

// --------------------------------------------- MFMA GEMM + residual + LN
// 512 threads / 8 waves (4m x 2n). K-tiles double-buffered, counted vmcnt(6).
__global__ __launch_bounds__(512) void mfma_gemm_ln_kernel(
    const bf16* __restrict__ A,    // [M][K]
    const bf16* __restrict__ Bt,   // [256][K]
    const float* __restrict__ bias,
    const float* __restrict__ res, // fp32 [M][256]
    const float* __restrict__ g, const float* __restrict__ b,
    float* __restrict__ xout, bf16* __restrict__ hbout, int K)
{
    __shared__ __align__(16) bf16 Asm[2][128 * 64];   // 32 KB dbuf
    __shared__ __align__(16) bf16 Bsm[2][256 * 64];   // 64 KB dbuf
    __shared__ float red[128][2][2];                  // 2 KB
    const int m0 = blockIdx.x * 128;
    const int tid = threadIdx.x;
    const int wave = tid >> 6, lane = tid & 63;
    const int quad = lane >> 4, l16 = lane & 15;
    const int wm = (wave >> 1) * 32, wn = (wave & 1) * 128;
    const int wnIdx = wave & 1;
    const int srow = lane >> 3;
    const int scol = ((lane & 7) ^ srow) * 8;

    f32x4 acc[2][8];
    #pragma unroll
    for (int i = 0; i < 2; ++i)
        #pragma unroll
        for (int j = 0; j < 8; ++j)
            acc[i][j] = (f32x4){0.f, 0.f, 0.f, 0.f};

    #pragma unroll
    for (int i = 0; i < 2; ++i) {
        int rband = wave * 16 + i * 8;
        GL2LDS16(A + (size_t)(m0 + rband + srow) * K + scol, &Asm[0][rband * 64]);
    }
    #pragma unroll
    for (int i = 0; i < 4; ++i) {
        int rband = wave * 32 + i * 8;
        GL2LDS16(Bt + (size_t)(rband + srow) * K + scol, &Bsm[0][rband * 64]);
    }

    const int nk = K >> 6;
    for (int kt = 0; kt < nk; ++kt) {
        const int cur = kt & 1;
        if (kt + 1 < nk) {
            const int k0 = (kt + 1) << 6;
            #pragma unroll
            for (int i = 0; i < 2; ++i) {
                int rband = wave * 16 + i * 8;
                GL2LDS16(A + (size_t)(m0 + rband + srow) * K + k0 + scol,
                         &Asm[cur ^ 1][rband * 64]);
            }
            #pragma unroll
            for (int i = 0; i < 4; ++i) {
                int rband = wave * 32 + i * 8;
                GL2LDS16(Bt + (size_t)(rband + srow) * K + k0 + scol,
                         &Bsm[cur ^ 1][rband * 64]);
            }
            asm volatile("s_waitcnt vmcnt(6)" ::: "memory");
        } else {
            asm volatile("s_waitcnt vmcnt(0)" ::: "memory");
        }
        __builtin_amdgcn_s_barrier();
        __builtin_amdgcn_sched_barrier(0);

        #pragma unroll
        for (int ks = 0; ks < 2; ++ks) {
            const int phys = ((ks * 4 + quad) ^ (l16 & 7)) * 8;
            bf16x8 af[2], bfr[8];
            #pragma unroll
            for (int i = 0; i < 2; ++i)
                af[i] = *(const bf16x8*)&Asm[cur][(wm + i * 16 + l16) * 64 + phys];
            #pragma unroll
            for (int j = 0; j < 8; ++j)
                bfr[j] = *(const bf16x8*)&Bsm[cur][(wn + j * 16 + l16) * 64 + phys];
            #pragma unroll
            for (int i = 0; i < 2; ++i)
                #pragma unroll
                for (int j = 0; j < 8; ++j)
                    acc[i][j] = __builtin_amdgcn_mfma_f32_16x16x32_bf16(
                        bfr[j], af[i], acc[i][j], 0, 0, 0);
        }
        __builtin_amdgcn_s_barrier();
    }

    #pragma unroll
    for (int i = 0; i < 2; ++i) {
        const int rl = wm + i * 16 + l16;
        const int m = m0 + rl;
        float s = 0.f, s2 = 0.f;
        #pragma unroll
        for (int j = 0; j < 8; ++j) {
            const int nb = wn + j * 16 + quad * 4;
            float4 b4 = *(const float4*)(bias + nb);
            float4 r4 = *(const float4*)(res + (size_t)m * Cc + nb);
            acc[i][j][0] += b4.x + r4.x; acc[i][j][1] += b4.y + r4.y;
            acc[i][j][2] += b4.z + r4.z; acc[i][j][3] += b4.w + r4.w;
            #pragma unroll
            for (int r = 0; r < 4; ++r) {
                s += acc[i][j][r];
                s2 += acc[i][j][r] * acc[i][j][r];
            }
        }
        s  += __shfl_xor(s, 16);  s  += __shfl_xor(s, 32);
        s2 += __shfl_xor(s2, 16); s2 += __shfl_xor(s2, 32);
        if (quad == 0) { red[rl][wnIdx][0] = s; red[rl][wnIdx][1] = s2; }
    }
    __syncthreads();

    #pragma unroll
    for (int i = 0; i < 2; ++i) {
        const int rl = wm + i * 16 + l16;
        const int m = m0 + rl;
        float s  = red[rl][0][0] + red[rl][1][0];
        float s2 = red[rl][0][1] + red[rl][1][1];
        float mean = s * (1.0f / Cc);
        float rstd = rsqrtf(s2 * (1.0f / Cc) - mean * mean + EPSc);
        #pragma unroll
        for (int j = 0; j < 8; ++j) {
            const int nb = wn + j * 16 + quad * 4;
            f32x4 v = acc[i][j];
            *(float4*)(xout + (size_t)m * Cc + nb) = (float4){v[0], v[1], v[2], v[3]};
            float4 g4 = *(const float4*)(g + nb);
            float4 bb4 = *(const float4*)(b + nb);
            union { bf16 h[4]; uint2 u; } p;
            p.h[0] = __float2bfloat16((v[0] - mean) * rstd * g4.x + bb4.x);
            p.h[1] = __float2bfloat16((v[1] - mean) * rstd * g4.y + bb4.y);
            p.h[2] = __float2bfloat16((v[2] - mean) * rstd * g4.z + bb4.z);
            p.h[3] = __float2bfloat16((v[3] - mean) * rstd * g4.w + bb4.w);
            *(uint2*)(hbout + (size_t)m * Cc + nb) = p.u;
        }
    }
}

// ------------------------------------------- fused MLP: gelu(hb@Wf+b1)@Wp
//                                             + b2 + residual + LN
// Attention-structure port (R7 k-chunk fix). Wp pre-permuted in global
// (castT_kernel<true>) so GEMM2 B-fragments are contiguous ds_read_b128.
// 512-thread / 8-wave version — verified passing 4x at ~80-83 us.
__global__ __launch_bounds__(512) void fused_ff_ln_kernel(
    const bf16* __restrict__ A,     // hb [M][256]
    const bf16* __restrict__ Wf,    // WfT [1024 f][256 c]
    const float* __restrict__ b1,   // [1024]
    const bf16* __restrict__ Wp,    // wpT [256 outc][1024 f], f pi-permuted
    const float* __restrict__ b2,   // [256]
    const float* __restrict__ g, const float* __restrict__ bb,
    float* __restrict__ x,          // residual in / out, fp32 [M][256]
    bf16* __restrict__ hbout)       // LN output [M][256]
{
    // 2 bufs x (Wf slice 64x256 + Wp slice 256x64) = 2 x 32768 elems = 128 KB
    __shared__ __align__(16) bf16 lds[2 * 32768];
    const int m0 = blockIdx.x * 128;
    const int tid = threadIdx.x;
    const int wave = tid >> 6, lane = tid & 63;
    const int quad = lane >> 4, l16 = lane & 15;

    // ---- prologue: stage hb tile [128][256] into lds[0..32768)
    #pragma unroll
    for (int it = 0; it < 8; ++it) {
        const int row = wave * 16 + it * 2 + (lane >> 5);
        const int clog = (lane & 31) ^ (row & 7);
        GL2LDS16(A + (size_t)(m0 + row) * Cc + clog * 8,
                 &lds[(wave * 16 + it * 2) * Cc]);
    }
    __syncthreads();
    // extract this wave's 16 rows as B-operand frags: for mfma kk, lane
    // (quad,l16) supplies hb[row = wave*16+l16][c = (kk*4+quad)*8 + e]
    bf16x8 ahb[8];
    #pragma unroll
    for (int kk = 0; kk < 8; ++kk)
        ahb[kk] = *(const bf16x8*)&lds[(wave * 16 + l16) * Cc
                                       + (((kk * 4 + quad) ^ (l16 & 7)) * 8)];
    asm volatile("s_waitcnt lgkmcnt(0)" ::: "memory");
    __builtin_amdgcn_sched_barrier(0);
    __builtin_amdgcn_s_barrier();   // all reads done before staging overwrites

    // stage one f-slice (Wf rows f0..f0+63 x 256c; Wp rows 0..255 x 64f)
    #define FF_STAGE(buf, sl) do {                                             \
        const int f0s = (sl) * 64;                                             \
        _Pragma("unroll")                                                      \
        for (int it = 0; it < 4; ++it) {                                       \
            const int row = it * 16 + wave * 2 + (lane >> 5);                  \
            const int clog = (lane & 31) ^ (row & 7);                          \
            GL2LDS16(Wf + (size_t)(f0s + row) * Cc + clog * 8,                 \
                     &lds[(buf) * 32768 + (it * 16 + wave * 2) * Cc]);         \
        }                                                                      \
        _Pragma("unroll")                                                      \
        for (int it = 0; it < 4; ++it) {                                       \
            const int row = it * 64 + wave * 8 + (lane >> 3);                  \
            const int clog = (lane & 7) ^ (row & 7);                           \
            GL2LDS16(Wp + (size_t)row * FFc + f0s + clog * 8,                  \
                     &lds[(buf) * 32768 + 16384 + (it * 64 + wave * 8) * 64]); \
        }                                                                      \
    } while (0)

    FF_STAGE(0, 0);

    f32x4 o[16];
    #pragma unroll
    for (int nt = 0; nt < 16; ++nt) o[nt] = (f32x4){0.f, 0.f, 0.f, 0.f};

    for (int kt = 0; kt < 16; ++kt) {
        const int cur = kt & 1;
        if (kt < 15) {
            FF_STAGE(cur ^ 1, kt + 1);
            asm volatile("s_waitcnt vmcnt(8)" ::: "memory");
        } else {
            asm volatile("s_waitcnt vmcnt(0)" ::: "memory");
        }
        __builtin_amdgcn_s_barrier();
        __builtin_amdgcn_sched_barrier(0);

        const bf16* Wfb = &lds[cur * 32768];
        const bf16* Wpb = &lds[cur * 32768 + 16384];

        // GEMM1 (swapped): sj[j] holds S[f=kt*64+j*16+quad*4+r][m=wave*16+l16]
        // mfma kk covers c-chunks kk*4..kk*4+3; lane supplies chunk kk*4+quad.
        f32x4 sj[4];
        #pragma unroll
        for (int j = 0; j < 4; ++j) sj[j] = (f32x4){0.f, 0.f, 0.f, 0.f};
        #pragma unroll
        for (int kk = 0; kk < 8; ++kk) {
            const int ph = ((kk * 4 + quad) ^ (l16 & 7)) * 8;
            #pragma unroll
            for (int j = 0; j < 4; ++j) {
                bf16x8 wfr = *(const bf16x8*)&Wfb[(j * 16 + l16) * Cc + ph];
                sj[j] = __builtin_amdgcn_mfma_f32_16x16x32_bf16(
                    wfr, ahb[kk], sj[j], 0, 0, 0);
            }
        }

        // bias1 + gelu
        float p[4][4];
        #pragma unroll
        for (int j = 0; j < 4; ++j) {
            float4 b4 = *(const float4*)(b1 + kt * 64 + j * 16 + quad * 4);
            p[j][0] = gelu_f(sj[j][0] + b4.x);
            p[j][1] = gelu_f(sj[j][1] + b4.y);
            p[j][2] = gelu_f(sj[j][2] + b4.z);
            p[j][3] = gelu_f(sj[j][3] + b4.w);
        }

        // pi-order PV A-frags: lane's own values, no shuffles
        U32x4 pa0, pa1;
        asm("v_cvt_pk_bf16_f32 %0, %1, %2" : "=v"(pa0.q[0]) : "v"(p[0][0]), "v"(p[0][1]));
        asm("v_cvt_pk_bf16_f32 %0, %1, %2" : "=v"(pa0.q[1]) : "v"(p[0][2]), "v"(p[0][3]));
        asm("v_cvt_pk_bf16_f32 %0, %1, %2" : "=v"(pa0.q[2]) : "v"(p[1][0]), "v"(p[1][1]));
        asm("v_cvt_pk_bf16_f32 %0, %1, %2" : "=v"(pa0.q[3]) : "v"(p[1][2]), "v"(p[1][3]));
        asm("v_cvt_pk_bf16_f32 %0, %1, %2" : "=v"(pa1.q[0]) : "v"(p[2][0]), "v"(p[2][1]));
        asm("v_cvt_pk_bf16_f32 %0, %1, %2" : "=v"(pa1.q[1]) : "v"(p[2][2]), "v"(p[2][3]));
        asm("v_cvt_pk_bf16_f32 %0, %1, %2" : "=v"(pa1.q[2]) : "v"(p[3][0]), "v"(p[3][1]));
        asm("v_cvt_pk_bf16_f32 %0, %1, %2" : "=v"(pa1.q[3]) : "v"(p[3][2]), "v"(p[3][3]));

        // GEMM2: o[nt] += P @ Wp-slice. Wp pre-permuted: frag g is one
        // contiguous b128 at chunk (g*4+quad), staged-XOR de-swizzled.
        #pragma unroll
        for (int nt = 0; nt < 16; ++nt) {
            const int d = nt * 16 + l16;
            bf16x8 w0 = *(const bf16x8*)&Wpb[d * 64 + (((0 + quad) ^ (l16 & 7)) * 8)];
            bf16x8 w1 = *(const bf16x8*)&Wpb[d * 64 + (((4 + quad) ^ (l16 & 7)) * 8)];
            o[nt] = __builtin_amdgcn_mfma_f32_16x16x32_bf16(pa0.v, w0, o[nt], 0, 0, 0);
            o[nt] = __builtin_amdgcn_mfma_f32_16x16x32_bf16(pa1.v, w1, o[nt], 0, 0, 0);
        }
        __builtin_amdgcn_s_barrier();   // buf cur reads done before overwrite
    }
    #undef FF_STAGE

    // ---- epilogue: bias2 + residual; LN stats per row (pure shfl: each
    // quad owns distinct rows, reduce across the 16 l16 lanes only)
    const int row0 = m0 + wave * 16 + quad * 4;
    float s[4] = {0.f, 0.f, 0.f, 0.f}, s2[4] = {0.f, 0.f, 0.f, 0.f};
    #pragma unroll
    for (int nt = 0; nt < 16; ++nt) {
        const int col = nt * 16 + l16;
        const float bpv = b2[col];
        #pragma unroll
        for (int r = 0; r < 4; ++r) {
            float v = o[nt][r] + bpv + x[(size_t)(row0 + r) * Cc + col];
            o[nt][r] = v;
            s[r] += v; s2[r] += v * v;
        }
    }
    #pragma unroll
    for (int r = 0; r < 4; ++r) {
        #pragma unroll
        for (int off = 1; off < 16; off <<= 1) {
            s[r]  += __shfl_xor(s[r], off);
            s2[r] += __shfl_xor(s2[r], off);
        }
    }
    float mean[4], rstd[4];
    #pragma unroll
    for (int r = 0; r < 4; ++r) {
        mean[r] = s[r] * (1.0f / Cc);
        rstd[r] = rsqrtf(s2[r] * (1.0f / Cc) - mean[r] * mean[r] + EPSc);
    }
    #pragma unroll
    for (int nt = 0; nt < 16; ++nt) {
        const int col = nt * 16 + l16;
        const float gv = g[col], bv = bb[col];
        #pragma unroll
        for (int r = 0; r < 4; ++r) {
            x[(size_t)(row0 + r) * Cc + col] = o[nt][r];
            hbout[(size_t)(row0 + r) * Cc + col] =
                __float2bfloat16((o[nt][r] - mean[r]) * rstd[r] * gv + bv);
        }
    }
}

// ---------------------------------------------------------------- attention
// MFMA flash attention, PAIRED q-tiles {pi, 7-pi}. K/V triple-buffered,
// prefetch 2 tiles ahead, counted vmcnt (R13). SWAPPED QK^T + pi key-
// permutation: P never touches LDS.
// R17: pi moved to the HIGH bits of blockIdx. Dispatch round-robins ids
// over 8 XCDs, then CU slots every 256 ids; with pi at bits 3..4 every
// CU received 4 blocks of the SAME pair class (4x16 vs 4x10 rounds ->
// ~19% structural idle). With pi = id>>8, each CU gets pairs {0,1,2,3}
// of the same bh: uniform 52 rounds/CU + shared K/V stream in L1/L2.
__global__ __launch_bounds__(256) void attn_mfma_kernel(
    const bf16* __restrict__ qkv, const bf16* __restrict__ vT,
    bf16* __restrict__ y)
{
    const int id = blockIdx.x;              // 1024 = 4 pair * 32 g * 8 xcd
    const int xcd = id & 7;
    const int g5  = (id >> 3) & 31;
    const int pi  = id >> 8;                // pair 0 (heaviest) still first
    const int bh  = g5 * 8 + xcd;
    const int qa = pi, qb = 7 - pi;         // 128-row q-tile indices
    const int b = bh >> 3, h = bh & 7;
    const int tid = threadIdx.x;
    const int wave = tid >> 6, lane = tid & 63;
    const int quad = lane >> 4, l16 = lane & 15;

    __shared__ __align__(16) bf16 Ks[3][64 * 32];    // 12 KB, 3-buf, swizzled
    __shared__ __align__(16) bf16 Vs[3][32 * 64];    // 12 KB, 3-buf, swizzled
    __shared__ __align__(16) bf16 Qs[256 * 32];      // 16 KB Q staging

    const size_t rstride = 3 * Cc;
    const bf16* base  = qkv + (size_t)(b * Tc) * rstride + h * Dc;
    const bf16* vbase = vT + (size_t)bh * Dc * Tc;

    const int srow4  = lane >> 2;
    const int schunk = ((lane & 3) ^ ((lane >> 3) & 3)) * 8;
    const int vchunk = ((lane & 7) ^ (lane >> 3)) * 8;

    #pragma unroll
    for (int u = 0; u < 4; ++u) {
        const int qt = (u >> 1) ? qb : qa;
        const bf16* gq = base
            + (size_t)(qt * 128 + (u & 1) * 64 + wave * 16 + srow4) * rstride + schunk;
        GL2LDS16(gq, &Qs[(u * 64 + wave * 16) * 32]);
    }
    // prologue: stage K/V tiles 0 and 1 (ktmax >= 9 so tile 1 exists)
    #pragma unroll
    for (int t0 = 0; t0 < 2; ++t0) {
        const bf16* gk = base
            + (size_t)(t0 * 64 + wave * 16 + srow4) * rstride + 256 + schunk;
        GL2LDS16(gk, &Ks[t0][(wave * 16) * 32]);
        const bf16* gv = vbase + (size_t)(wave * 8 + (lane >> 3)) * Tc + t0 * 64 + vchunk;
        GL2LDS16(gv, &Vs[t0][(wave * 8) * 64]);
    }
    __syncthreads();
    const int qkphys = (quad ^ ((l16 >> 1) & 3)) * 8;
    bf16x8 afq[4];
    #pragma unroll
    for (int u = 0; u < 4; ++u)
        afq[u] = *(const bf16x8*)&Qs[(u * 64 + wave * 16 + l16) * 32 + qkphys];

    float l_acc[4] = {};
    f32x4 o[4][2];
    #pragma unroll
    for (int u = 0; u < 4; ++u)
        #pragma unroll
        for (int nt = 0; nt < 2; ++nt)
            o[u][nt] = (f32x4){0.f, 0.f, 0.f, 0.f};

    const int rloc = wave * 16 + quad * 4;     // output q rows (epilogue)
    const int qloc = wave * 16 + l16;          // this lane's P column (q row)
    const int vsw = l16 & 7;
    const int vq  = (quad >> 1);
    const int vo  = (quad & 1) * 4;

    const int ktmax = 2 * qb + 1;
    for (int kt = 0; kt <= ktmax; ++kt) {
        const int cur = kt % 3;

        if (kt + 2 <= ktmax) {
            const int nxt = (kt + 2) % 3;
            const bf16* gk = base
                + (size_t)((kt + 2) * 64 + wave * 16 + srow4) * rstride + 256 + schunk;
            GL2LDS16(gk, &Ks[nxt][(wave * 16) * 32]);
            const bf16* gv = vbase
                + (size_t)(wave * 8 + (lane >> 3)) * Tc + (kt + 2) * 64 + vchunk;
            GL2LDS16(gv, &Vs[nxt][(wave * 8) * 64]);
            asm volatile("s_waitcnt vmcnt(4)" ::: "memory");
        } else if (kt + 1 <= ktmax) {
            asm volatile("s_waitcnt vmcnt(2)" ::: "memory");
        } else {
            asm volatile("s_waitcnt vmcnt(0)" ::: "memory");
        }
        __builtin_amdgcn_s_barrier();            // tile kt ready for all waves
        __builtin_amdgcn_sched_barrier(0);

        bf16x8 bk[4];
        #pragma unroll
        for (int j = 0; j < 4; ++j)
            bk[j] = *(const bf16x8*)&Ks[cur][(j * 16 + l16) * 32 + qkphys];

        U32x4 bvx[2][2];
        #pragma unroll
        for (int g = 0; g < 2; ++g)
            #pragma unroll
            for (int nt = 0; nt < 2; ++nt) {
                const int d = nt * 16 + l16;
                uint2 lo = *(const uint2*)&Vs[cur][d * 64 + (((4 * g + 0 + vq) ^ vsw) * 8 + vo)];
                uint2 hi = *(const uint2*)&Vs[cur][d * 64 + (((4 * g + 2 + vq) ^ vsw) * 8 + vo)];
                bvx[g][nt].q[0] = lo.x; bvx[g][nt].q[1] = lo.y;
                bvx[g][nt].q[2] = hi.x; bvx[g][nt].q[3] = hi.y;
            }

        #pragma unroll
        for (int t = 1; t >= 0; --t) {
            const int qt = t ? qb : qa;
            if (kt > 2 * qt + 1) continue;      // whole tile done (uniform)

            #pragma unroll
            for (int s = 0; s < 2; ++s) {
                const int u = t * 2 + s;
                if (kt > 2 * qt + s) continue;  // subtile masked (uniform)

                f32x4 sj[4];
                #pragma unroll
                for (int j = 0; j < 4; ++j)
                    sj[j] = __builtin_amdgcn_mfma_f32_16x16x32_bf16(
                        bk[j], afq[u], (f32x4){0.f,0.f,0.f,0.f}, 0, 0, 0);
                if (kt == 2 * qt + s) {         // diagonal: causal mask
                    #pragma unroll
                    for (int j = 0; j < 4; ++j)
                        #pragma unroll
                        for (int r = 0; r < 4; ++r)
                            if (j * 16 + quad * 4 + r > qloc) sj[j][r] = -INFINITY;
                }

                float p[4][4];
                float ls = 0.f;
                #pragma unroll
                for (int j = 0; j < 4; ++j) {
                    #pragma unroll
                    for (int r = 0; r < 4; ++r) {
                        p[j][r] = __builtin_amdgcn_exp2f(sj[j][r]);
                    }
                    ls += (p[j][0] + p[j][1]) + (p[j][2] + p[j][3]);
                }
                l_acc[u] += ls;

                U32x4 pa0, pa1;
                asm("v_cvt_pk_bf16_f32 %0, %1, %2" : "=v"(pa0.q[0]) : "v"(p[0][0]), "v"(p[0][1]));
                asm("v_cvt_pk_bf16_f32 %0, %1, %2" : "=v"(pa0.q[1]) : "v"(p[0][2]), "v"(p[0][3]));
                asm("v_cvt_pk_bf16_f32 %0, %1, %2" : "=v"(pa0.q[2]) : "v"(p[1][0]), "v"(p[1][1]));
                asm("v_cvt_pk_bf16_f32 %0, %1, %2" : "=v"(pa0.q[3]) : "v"(p[1][2]), "v"(p[1][3]));
                asm("v_cvt_pk_bf16_f32 %0, %1, %2" : "=v"(pa1.q[0]) : "v"(p[2][0]), "v"(p[2][1]));
                asm("v_cvt_pk_bf16_f32 %0, %1, %2" : "=v"(pa1.q[1]) : "v"(p[2][2]), "v"(p[2][3]));
                asm("v_cvt_pk_bf16_f32 %0, %1, %2" : "=v"(pa1.q[2]) : "v"(p[3][0]), "v"(p[3][1]));
                asm("v_cvt_pk_bf16_f32 %0, %1, %2" : "=v"(pa1.q[3]) : "v"(p[3][2]), "v"(p[3][3]));

                o[u][0] = __builtin_amdgcn_mfma_f32_16x16x32_bf16(pa0.v, bvx[0][0].v, o[u][0], 0, 0, 0);
                o[u][0] = __builtin_amdgcn_mfma_f32_16x16x32_bf16(pa1.v, bvx[1][0].v, o[u][0], 0, 0, 0);
                o[u][1] = __builtin_amdgcn_mfma_f32_16x16x32_bf16(pa0.v, bvx[0][1].v, o[u][1], 0, 0, 0);
                o[u][1] = __builtin_amdgcn_mfma_f32_16x16x32_bf16(pa1.v, bvx[1][1].v, o[u][1], 0, 0, 0);
            }
        }

        __builtin_amdgcn_s_barrier();
    }

    #pragma unroll
    for (int u = 0; u < 4; ++u) {
        const int qt = (u >> 1) ? qb : qa;
        float l = l_acc[u];
        l += __shfl_xor(l, 16);
        l += __shfl_xor(l, 32);
        float linv[4];
        #pragma unroll
        for (int r = 0; r < 4; ++r)
            linv[r] = 1.0f / __shfl(l, quad * 20 + r);
        #pragma unroll
        for (int nt = 0; nt < 2; ++nt)
            #pragma unroll
            for (int r = 0; r < 4; ++r)
                y[(size_t)(b * Tc + qt * 128 + (u & 1) * 64 + rloc + r) * Cc
                  + h * Dc + nt * 16 + l16]
                    = __float2bfloat16(o[u][nt][r] * linv[r]);
    }
}

// ---------------------------------------------------------------- launch
extern "C" void kernel_launch(void* const* d_in, const int* in_sizes, int n_in,
                              void* d_out, int out_size, void* d_ws, size_t ws_size,
                              hipStream_t stream)
{
    const int*   idx     = (const int*)  d_in[0];
    const float* tok_emb = (const float*)d_in[1];
    const float* pos_emb = (const float*)d_in[2];
    const float* ln1_g   = (const float*)d_in[3];
    const float* ln1_b   = (const float*)d_in[4];
    const float* wqkv    = (const float*)d_in[5];
    const float* bqkv    = (const float*)d_in[6];
    const float* wo      = (const float*)d_in[7];
    const float* bo      = (const float*)d_in[8];
    const float* ln2_g   = (const float*)d_in[9];
    const float* ln2_b   = (const float*)d_in[10];
    const float* wfc     = (const float*)d_in[11];
    const float* bfc     = (const float*)d_in[12];
    const float* wpr     = (const float*)d_in[13];
    const float* bpr     = (const float*)d_in[14];
    const float* lnf_g   = (const float*)d_in[15];
    const float* lnf_b   = (const float*)d_in[16];
    const float* w_lm    = (const float*)d_in[17];
    float* out = (float*)d_out;

    float* ws = (float*)d_ws;
    float* x  = ws;                                        // Mc*Cc fp32
    bf16* hb  = (bf16*)(x + (size_t)Mc * Cc);              // Mc*Cc bf16
    bf16* yb  = hb + (size_t)Mc * Cc;                      // Mc*Cc bf16
    float* big = (float*)(yb + (size_t)Mc * Cc);           // scratch region
    bf16* bigb = (bf16*)big;                               // qkv bf16
    bf16* wqT = (bf16*)(big + (size_t)Mc * 3 * Cc);        // [L][3C][C]
    bf16* woT = wqT + (size_t)Lc * 3 * Cc * Cc;            // [L][C][C]
    bf16* wfT = woT + (size_t)Lc * Cc * Cc;                // [L][FF][C]
    bf16* wpT = wfT + (size_t)Lc * Cc * FFc;               // [L][C][FF] (f permuted)
    bf16* wlT = wpT + (size_t)Lc * FFc * Cc;               // [V][C]
    bf16* vT  = wlT + (size_t)Vc * Cc;                     // [B][H][D][T]

    dim3 blk(256);
    dim3 blkG(512);

    castT_kernel<false><<<dim3(3 * Cc / 32, Cc / 32, Lc), blk, 0, stream>>>(wqkv, wqT, Cc, 3 * Cc);
    castT_kernel<false><<<dim3(Cc / 32, Cc / 32, Lc),     blk, 0, stream>>>(wo,   woT, Cc, Cc);
    castT_kernel<false><<<dim3(FFc / 32, Cc / 32, Lc),    blk, 0, stream>>>(wfc,  wfT, Cc, FFc);
    castT_kernel<true><<<dim3(Cc / 32, FFc / 32, Lc),     blk, 0, stream>>>(wpr,  wpT, FFc, Cc);
    castT_kernel<false><<<dim3(Vc / 32, Cc / 32, 1),      blk, 0, stream>>>(w_lm, wlT, Cc, Vc);

    embed_ln_kernel<<<dim3(Mc), blk, 0, stream>>>(idx, tok_emb, pos_emb,
                                                  ln1_g, ln1_b, x, hb);

    for (int l = 0; l < Lc; ++l) {
        const bf16* WqT = wqT + (size_t)l * 3 * Cc * Cc;
        const bf16* WoT = woT + (size_t)l * Cc * Cc;
        const bf16* WfT = wfT + (size_t)l * Cc * FFc;
        const bf16* WpT = wpT + (size_t)l * FFc * Cc;
        const float* bq = bqkv + (size_t)l * 3 * Cc;
        const float* bo_ = bo  + (size_t)l * Cc;
        const float* bf_ = bfc + (size_t)l * FFc;
        const float* bp = bpr  + (size_t)l * Cc;
        const float* gn = (l < Lc - 1) ? ln1_g + (size_t)(l + 1) * Cc : lnf_g;
        const float* bn = (l < Lc - 1) ? ln1_b + (size_t)(l + 1) * Cc : lnf_b;

        // qkv: q,k -> bigb [M,3C]; v -> vT[B][H][D][T]   (NT=6, XCD-swizzled)
        mfma_gemm_kernel<false, true, true><<<dim3(Mc / 128 * 6), blkG, 0, stream>>>(
            hb, WqT, bq, nullptr, nullptr, bigb, vT, Mc, 3 * Cc, Cc, 6);
        attn_mfma_kernel<<<dim3(1024), blk, 0, stream>>>(bigb, vT, yb);
        // x = x + yb @ Wo + bo;  hb = LN2(x)
        mfma_gemm_ln_kernel<<<dim3(Mc / 128), blkG, 0, stream>>>(
            yb, WoT, bo_, x, ln2_g + (size_t)l * Cc, ln2_b + (size_t)l * Cc,
            x, hb, Cc);
        // fused MLP: x = x + gelu(hb@Wf+bf)@Wp + bp;  hb = LN_next(x)
        fused_ff_ln_kernel<<<dim3(Mc / 128), blkG, 0, stream>>>(
            hb, WfT, bf_, WpT, bp, gn, bn, x, hb);
    }

    // logits = hb @ w_lm   (NT=1)
    mfma_gemm_kernel<false, false, false><<<dim3(Mc / 128), blkG, 0, stream>>>(
        hb, wlT, nullptr, nullptr, out, nullptr, nullptr, Mc, Vc, Cc, 1);
}